// Round 2
// baseline (46766.364 us; speedup 1.0000x reference)
//
#include <hip/hip_runtime.h>
#include <cstdint>

// ---------------- problem constants ----------------
#define NB 64        // batch
#define TT 8         // timesteps
#define NN 2000      // nodes
#define NF 16        // in features
#define NCH 64       // channels
#define NPAD 2048    // padded node dim
#define BCD 4096     // NB*NCH
#define ITEMS 128000 // NB*NN

// ws offsets (floats)
#define OFF_ADP   0                        // 2048*2048   = 4194304
#define OFF_S     4194304                  // 2048*4096   = 8388608
#define OFF_X1    (OFF_S + 8388608)
#define OFF_X2    (OFF_X1 + 8388608)
#define OFF_C01   (OFF_X2 + 8388608)       // 128
#define OFF_WGCNT (OFF_C01 + 128)          // 192*64 = 12288 (gcn_w transposed)
#define OFF_W1TT  (OFF_WGCNT + 12288)      // 2*64*64 = 8192 (head w1 gx-part transposed)
#define OFF_PART  (OFF_W1TT + 8192)        // 2048*132 partials

// ---------------- K0: tiny precompute (transposes + task-dot) ----------------
__global__ void prep_kernel(const float* __restrict__ gcn_w,
                            const float* __restrict__ h0_w1, const float* __restrict__ h0_b1,
                            const float* __restrict__ h1_w1, const float* __restrict__ h1_b1,
                            const float* __restrict__ task_emb,
                            float* __restrict__ c01, float* __restrict__ wgcnT,
                            float* __restrict__ w1tT)
{
    int tid = threadIdx.x;
    for (int idx = tid; idx < 64 * 192; idx += 256) {
        int o = idx / 192, j = idx % 192;
        wgcnT[j * 64 + o] = gcn_w[idx];
    }
    for (int idx = tid; idx < 4096; idx += 256) {
        int o = idx >> 6, c = idx & 63;
        w1tT[c * 64 + o]        = h0_w1[o * 128 + 64 + c];
        w1tT[4096 + c * 64 + o] = h1_w1[o * 128 + 64 + c];
    }
    if (tid < 128) {
        int head = tid >> 6, o = tid & 63;
        const float* w1 = head ? h1_w1 : h0_w1;
        const float* b1 = head ? h1_b1 : h0_b1;
        float a = b1[o];
        for (int k = 0; k < 64; ++k) a = fmaf(w1[o * 128 + k], task_emb[k], a);
        c01[tid] = a;
    }
}

// ---------------- K1: adp = softmax(relu(nv1@nv2), axis=1), padded to 2048 cols ----------------
__global__ __launch_bounds__(256) void adp_kernel(const float* __restrict__ nv1,
                                                  const float* __restrict__ nv2,
                                                  float* __restrict__ adp)
{
    __shared__ float nv1s[10];
    __shared__ float rbuf[4];
    int tid = threadIdx.x;
    int r = blockIdx.x;
    if (tid < 10) nv1s[tid] = nv1[r * 10 + tid];
    __syncthreads();

    float val[8];
    float vmax = -3.4e38f;
    #pragma unroll
    for (int s = 0; s < 8; ++s) {
        int j = tid + s * 256;
        if (j < NN) {
            float v = 0.f;
            #pragma unroll
            for (int k = 0; k < 10; ++k) v = fmaf(nv1s[k], nv2[k * NN + j], v);
            v = fmaxf(v, 0.f);
            val[s] = v;
            vmax = fmaxf(vmax, v);
        } else val[s] = -3.4e38f;
    }
    for (int off = 32; off; off >>= 1) vmax = fmaxf(vmax, __shfl_down(vmax, off, 64));
    if ((tid & 63) == 0) rbuf[tid >> 6] = vmax;
    __syncthreads();
    vmax = fmaxf(fmaxf(rbuf[0], rbuf[1]), fmaxf(rbuf[2], rbuf[3]));
    __syncthreads();
    float sum = 0.f;
    #pragma unroll
    for (int s = 0; s < 8; ++s) {
        int j = tid + s * 256;
        if (j < NN) { val[s] = expf(val[s] - vmax); sum += val[s]; }
    }
    for (int off = 32; off; off >>= 1) sum += __shfl_down(sum, off, 64);
    if ((tid & 63) == 0) rbuf[tid >> 6] = sum;
    __syncthreads();
    sum = rbuf[0] + rbuf[1] + rbuf[2] + rbuf[3];
    float inv = 1.f / sum;
    #pragma unroll
    for (int s = 0; s < 8; ++s) {
        int j = tid + s * 256;
        if (j < NN) adp[r * NPAD + j] = val[s] * inv;
    }
}

// ---------------- K2: fused temporal stack (v2: conflict-free layout, 16 waves) ----------------
// Block = 1024 threads = 16 waves; 32 items/block; each wave owns 2 items (lane = channel).
// LDS layout:
//   xstate[32 items][8 t][64 ch]  (64 KB)  - lane-stride-1 writes, b128 broadcast reads
//   gbuf  [32 items][64 ch]       (8 KB)   - gated[P] exchange for skip conv
//   flds/glds [c][k][o] (32 KB each), slds [c][o] (16 KB)
// Own-channel state additionally lives in registers (xreg) across layers.
#define TK_GI 2

template<int LAYER, int D, int WIN, int WOUT>
__device__ __forceinline__ void do_layer(
    float* __restrict__ xstate, float* __restrict__ gbuf,
    float* __restrict__ flds, float* __restrict__ glds, float* __restrict__ slds,
    const float* __restrict__ filt_w, const float* __restrict__ filt_b,
    const float* __restrict__ gate_w, const float* __restrict__ gate_b,
    const float* __restrict__ skip_w, const float* __restrict__ skip_b,
    const float* __restrict__ bn_g, const float* __restrict__ bn_b,
    float xreg[TK_GI][8], float* __restrict__ sacc)
{
    int tid = threadIdx.x;
    int wave = tid >> 6, o = tid & 63;
    // stage weights: global read coalesced, LDS write lane-transposed
    for (int idx = tid; idx < 8192; idx += 1024) {
        int oo = idx >> 7, rem = idx & 127;
        int c = rem >> 1, k = rem & 1;
        flds[c * 128 + k * 64 + oo] = filt_w[LAYER * 8192 + idx];
        glds[c * 128 + k * 64 + oo] = gate_w[LAYER * 8192 + idx];
    }
    for (int idx = tid; idx < 4096; idx += 1024) {
        int oo = idx >> 6, c = idx & 63;
        slds[c * 64 + oo] = skip_w[LAYER * 4096 + idx];
    }
    __syncthreads();

    float fb = filt_b[LAYER * 64 + o], gb = gate_b[LAYER * 64 + o];
    float skb = skip_b[LAYER * 64 + o];
    float bscale = bn_g[LAYER * 64 + o] * rsqrtf(1.0f + 1e-5f);
    float bshift = bn_b[LAYER * 64 + o];

    #pragma unroll
    for (int gi = 0; gi < TK_GI; ++gi) {
        int g = wave * TK_GI + gi;
        const float4* xs4 = (const float4*)&xstate[g * 512];   // [t][c] as float4
        float facc[WOUT], gacc[WOUT];
        #pragma unroll
        for (int t = 0; t < WOUT; ++t) { facc[t] = fb; gacc[t] = gb; }

        #pragma unroll
        for (int c0 = 0; c0 < 16; ++c0) {
            float4 xq[WIN];
            #pragma unroll
            for (int t = 0; t < WIN; ++t) xq[t] = xs4[t * 16 + c0];  // broadcast b128
            #pragma unroll
            for (int j = 0; j < 4; ++j) {
                int c = c0 * 4 + j;
                float wf0 = flds[c * 128 + o];        // lane-stride-1
                float wf1 = flds[c * 128 + 64 + o];
                float wg0 = glds[c * 128 + o];
                float wg1 = glds[c * 128 + 64 + o];
                #pragma unroll
                for (int t = 0; t < WOUT; ++t) {
                    float xt  = ((const float*)&xq[t])[j];
                    float xtd = ((const float*)&xq[t + D])[j];
                    facc[t] = fmaf(wf0, xt, facc[t]);
                    facc[t] = fmaf(wf1, xtd, facc[t]);
                    gacc[t] = fmaf(wg0, xt, gacc[t]);
                    gacc[t] = fmaf(wg1, xtd, gacc[t]);
                }
            }
        }
        float gated[WOUT];
        #pragma unroll
        for (int t = 0; t < WOUT; ++t)
            gated[t] = tanhf(facc[t]) * (1.0f / (1.0f + expf(-gacc[t])));

        // publish gated[last] for skip conv (wave-lockstep; same-wave LDS order)
        gbuf[g * 64 + o] = gated[WOUT - 1];
        asm volatile("" ::: "memory");
        float s = skb;
        const float4* gb4 = (const float4*)&gbuf[g * 64];
        #pragma unroll
        for (int c0 = 0; c0 < 16; ++c0) {
            float4 gq = gb4[c0];                       // broadcast b128
            #pragma unroll
            for (int j = 0; j < 4; ++j)
                s = fmaf(slds[(c0 * 4 + j) * 64 + o], ((const float*)&gq)[j], s);
        }
        sacc[gi] += s;

        // residual + eval-mode BN -> next layer input (regs + LDS copy)
        #pragma unroll
        for (int t = 0; t < WOUT; ++t) {
            float nx = fmaf(gated[t] + xreg[gi][t + D], bscale, bshift);
            xreg[gi][t] = nx;
            xstate[g * 512 + t * 64 + o] = nx;         // lane-stride-1
        }
        asm volatile("" ::: "memory");
    }
    __syncthreads();  // all waves done with this layer's weights before restage
}

__global__ __launch_bounds__(1024, 4) void temporal_kernel(
    const float* __restrict__ X,
    const float* __restrict__ start_w, const float* __restrict__ start_b,
    const float* __restrict__ filt_w, const float* __restrict__ filt_b,
    const float* __restrict__ gate_w, const float* __restrict__ gate_b,
    const float* __restrict__ skip_w, const float* __restrict__ skip_b,
    const float* __restrict__ bn_g, const float* __restrict__ bn_b,
    float* __restrict__ S)
{
    extern __shared__ float smem[];
    float* xstate = smem;           // 16384 floats [32][8][64]
    float* gbuf   = smem + 16384;   // 2048 floats  [32][64]
    float* flds   = smem + 18432;   // 8192
    float* glds   = smem + 26624;   // 8192
    float* slds   = smem + 34816;   // 4096
    float* xstage = flds;           // overlap: X staging (4096 floats) before weights

    int tid = threadIdx.x;
    int wave = tid >> 6, o = tid & 63;
    int item0 = blockIdx.x * 32;

    // stage X for 32 items: xstage[g][t*16+f]
    for (int idx = tid; idx < 32 * 128; idx += 1024) {
        int g = idx >> 7, rem = idx & 127;
        int ig = item0 + g;
        int b = ig / NN, n = ig - b * NN;
        int t = rem >> 4, f = rem & 15;
        xstage[idx] = X[((b * TT + t) * NN + n) * NF + f];
    }
    __syncthreads();

    float xreg[TK_GI][8];
    // start 1x1 conv (F=16 -> CH=64)
    {
        float wst[16];
        #pragma unroll
        for (int f4 = 0; f4 < 16; f4 += 4) {
            float4 v = *(const float4*)&start_w[o * 16 + f4];
            wst[f4] = v.x; wst[f4+1] = v.y; wst[f4+2] = v.z; wst[f4+3] = v.w;
        }
        float sb = start_b[o];
        #pragma unroll
        for (int gi = 0; gi < TK_GI; ++gi) {
            int g = wave * TK_GI + gi;
            const float4* xr4 = (const float4*)&xstage[g * 128];
            #pragma unroll
            for (int t = 0; t < 8; ++t) {
                float acc = sb;
                #pragma unroll
                for (int f4 = 0; f4 < 4; ++f4) {
                    float4 xv = xr4[t * 4 + f4];       // broadcast b128
                    acc = fmaf(wst[f4*4],   xv.x, acc);
                    acc = fmaf(wst[f4*4+1], xv.y, acc);
                    acc = fmaf(wst[f4*4+2], xv.z, acc);
                    acc = fmaf(wst[f4*4+3], xv.w, acc);
                }
                xreg[gi][t] = acc;
                xstate[g * 512 + t * 64 + o] = acc;    // lane-stride-1
            }
        }
    }
    __syncthreads();  // xstage (aliases flds) free; xstate visible

    float sacc[TK_GI] = {0, 0};
    do_layer<0, 1, 8, 7>(xstate, gbuf, flds, glds, slds, filt_w, filt_b, gate_w, gate_b,
                         skip_w, skip_b, bn_g, bn_b, xreg, sacc);
    do_layer<1, 2, 7, 5>(xstate, gbuf, flds, glds, slds, filt_w, filt_b, gate_w, gate_b,
                         skip_w, skip_b, bn_g, bn_b, xreg, sacc);
    do_layer<2, 4, 5, 1>(xstate, gbuf, flds, glds, slds, filt_w, filt_b, gate_w, gate_b,
                         skip_w, skip_b, bn_g, bn_b, xreg, sacc);

    // write skip_final: S[n][b*64+o] (K-major for GEMM)
    #pragma unroll
    for (int gi = 0; gi < TK_GI; ++gi) {
        int ig = item0 + wave * TK_GI + gi;
        int b = ig / NN, n = ig - b * NN;
        S[n * BCD + b * 64 + o] = sacc[gi];
    }
}

// ---------------- K3: TN GEMM, C[m][n] = sum_k A[k][m]*B[k][n] ----------------
__global__ __launch_bounds__(256) void gemm_tn(const float* __restrict__ A,
                                               const float* __restrict__ B,
                                               float* __restrict__ Cm)
{
    __shared__ float As[16][132];
    __shared__ float Bs[16][132];
    int tid = threadIdx.x;
    int tx = tid & 15, ty = tid >> 4;
    int m0 = blockIdx.y * 128, n0 = blockIdx.x * 128;
    float acc[8][8] = {};
    for (int k0 = 0; k0 < NPAD; k0 += 16) {
        #pragma unroll
        for (int l = 0; l < 2; ++l) {
            int fi = tid * 4 + l * 1024;
            int r = fi >> 7, c = fi & 127;
            *(float4*)&As[r][c] = *(const float4*)&A[(k0 + r) * NPAD + m0 + c];
            *(float4*)&Bs[r][c] = *(const float4*)&B[(k0 + r) * BCD + n0 + c];
        }
        __syncthreads();
        #pragma unroll
        for (int kk = 0; kk < 16; ++kk) {
            float a[8], b[8];
            *(float4*)&a[0] = *(float4*)&As[kk][ty * 8];
            *(float4*)&a[4] = *(float4*)&As[kk][ty * 8 + 4];
            *(float4*)&b[0] = *(float4*)&Bs[kk][tx * 8];
            *(float4*)&b[4] = *(float4*)&Bs[kk][tx * 8 + 4];
            #pragma unroll
            for (int i = 0; i < 8; ++i)
                #pragma unroll
                for (int j = 0; j < 8; ++j)
                    acc[i][j] = fmaf(a[i], b[j], acc[i][j]);
        }
        __syncthreads();
    }
    #pragma unroll
    for (int i = 0; i < 8; ++i) {
        int m = m0 + ty * 8 + i;
        *(float4*)&Cm[m * BCD + n0 + tx * 8]     = make_float4(acc[i][0], acc[i][1], acc[i][2], acc[i][3]);
        *(float4*)&Cm[m * BCD + n0 + tx * 8 + 4] = make_float4(acc[i][4], acc[i][5], acc[i][6], acc[i][7]);
    }
}

// ---------------- K4: gcn 1x1 + heads + outputs + partial reductions ----------------
__global__ __launch_bounds__(256) void head_kernel(
    const float* __restrict__ S, const float* __restrict__ x1, const float* __restrict__ x2,
    const float* __restrict__ wgcnT, const float* __restrict__ gcn_b,
    const float* __restrict__ c01, const float* __restrict__ w1tT,
    const float* __restrict__ h0_w2, const float* __restrict__ h0_b2,
    const float* __restrict__ h1_w2, const float* __restrict__ h1_b2,
    const int* __restrict__ Ct, const float* __restrict__ Yf,
    float* __restrict__ out, float* __restrict__ partials)
{
    __shared__ float hl[4][4][192];
    __shared__ float gxl[4][4][64];
    int tid = threadIdx.x;
    int wave = tid >> 6, o = tid & 63;
    int wid = blockIdx.x * 4 + wave;  // 0..2047
    float w2a = h0_w2[o], w2b = h1_w2[o];
    float b20 = h0_b2[0], b21 = h1_b2[0];
    float cb = gcn_b[o], c0a = c01[o], c0b = c01[64 + o];

    float accT = 0.f, accC = 0.f, bce = 0.f, cT = 0.f, cC = 0.f;

    for (int base = wid * 4; base < ITEMS; base += 2048 * 4) {
        #pragma unroll
        for (int it = 0; it < 4; ++it) {
            int item = base + it;
            int b = item / NN, n = item - b * NN;
            int off = n * BCD + b * 64 + o;
            hl[wave][it][o]       = S[off];
            hl[wave][it][64 + o]  = x1[off];
            hl[wave][it][128 + o] = x2[off];
        }
        float a0 = cb, a1 = cb, a2 = cb, a3 = cb;
        for (int j = 0; j < 192; ++j) {
            float w = wgcnT[j * 64 + o];
            a0 = fmaf(w, hl[wave][0][j], a0);
            a1 = fmaf(w, hl[wave][1][j], a1);
            a2 = fmaf(w, hl[wave][2][j], a2);
            a3 = fmaf(w, hl[wave][3][j], a3);
        }
        float gxv[4] = {fmaxf(a0, 0.f), fmaxf(a1, 0.f), fmaxf(a2, 0.f), fmaxf(a3, 0.f)};
        #pragma unroll
        for (int it = 0; it < 4; ++it) gxl[wave][it][o] = gxv[it];

        float p0[4], p1[4];
        #pragma unroll
        for (int it = 0; it < 4; ++it) { p0[it] = c0a; p1[it] = c0b; }
        for (int c = 0; c < 64; ++c) {
            float w0 = w1tT[c * 64 + o];
            float w1 = w1tT[4096 + c * 64 + o];
            float g0 = gxl[wave][0][c], g1 = gxl[wave][1][c];
            float g2 = gxl[wave][2][c], g3 = gxl[wave][3][c];
            p0[0] = fmaf(w0, g0, p0[0]); p0[1] = fmaf(w0, g1, p0[1]);
            p0[2] = fmaf(w0, g2, p0[2]); p0[3] = fmaf(w0, g3, p0[3]);
            p1[0] = fmaf(w1, g0, p1[0]); p1[1] = fmaf(w1, g1, p1[1]);
            p1[2] = fmaf(w1, g2, p1[2]); p1[3] = fmaf(w1, g3, p1[3]);
        }
        #pragma unroll
        for (int it = 0; it < 4; ++it) {
            float r0 = w2a * fmaxf(p0[it], 0.f);
            float r1 = w2b * fmaxf(p1[it], 0.f);
            #pragma unroll
            for (int off = 32; off; off >>= 1) {
                r0 += __shfl_down(r0, off, 64);
                r1 += __shfl_down(r1, off, 64);
            }
            int item = base + it;
            int tt = Ct[item];
            if (o == 0) {
                float y0 = 1.f / (1.f + expf(-(r0 + b20)));
                float y1 = 1.f / (1.f + expf(-(r1 + b21)));
                float y = (tt > 0) ? y1 : y0;
                out[1 + item] = y;
                out[1 + ITEMS + item] = y0;
                out[1 + 2 * ITEMS + item] = y1;
                float yc = fminf(fmaxf(y, 1e-7f), 1.f - 1e-7f);
                float Yv = Yf[item];
                bce -= Yv * logf(yc) + (1.f - Yv) * logf(1.f - yc);
                if (tt > 0) cT += 1.f; else cC += 1.f;
            }
            if (tt > 0) accT += gxv[it]; else accC += gxv[it];
        }
    }
    partials[wid * 132 + o] = accT;
    partials[wid * 132 + 64 + o] = accC;
    if (o == 0) {
        partials[wid * 132 + 128] = bce;
        partials[wid * 132 + 129] = cT;
        partials[wid * 132 + 130] = cC;
    }
}

// ---------------- K5: final loss ----------------
__global__ void finalize_kernel(const float* __restrict__ partials,
                                const float* __restrict__ task_emb,
                                float* __restrict__ out)
{
    __shared__ float red[131];
    int tid = threadIdx.x; // 128
    for (int slot = tid; slot < 131; slot += 128) {
        float s = 0.f;
        for (int w = 0; w < 2048; ++w) s += partials[w * 132 + slot];
        red[slot] = s;
    }
    __syncthreads();
    if (tid < 64) {
        float cT = red[129], cC = red[130];
        float iT = 1.f / fmaxf(cT, 1.f), iC = 1.f / fmaxf(cC, 1.f);
        float d1 = task_emb[tid] * (cT * iT) - task_emb[tid] * (cC * iC);
        float d2 = red[tid] * iT - red[64 + tid] * iC;
        float p = d1 * d1 + d2 * d2;
        #pragma unroll
        for (int off = 32; off; off >>= 1) p += __shfl_down(p, off, 64);
        if (tid == 0) out[0] = red[128] * (1.f / (float)ITEMS) + p;
    }
}

// ---------------- launch ----------------
extern "C" void kernel_launch(void* const* d_in, const int* in_sizes, int n_in,
                              void* d_out, int out_size, void* d_ws, size_t ws_size,
                              hipStream_t stream)
{
    const float* X       = (const float*)d_in[0];
    const int*   Ct      = (const int*)d_in[2];
    const float* Yf      = (const float*)d_in[3];
    const float* start_w = (const float*)d_in[5];
    const float* start_b = (const float*)d_in[6];
    const float* filt_w  = (const float*)d_in[7];
    const float* filt_b  = (const float*)d_in[8];
    const float* gate_w  = (const float*)d_in[9];
    const float* gate_b  = (const float*)d_in[10];
    const float* skip_w  = (const float*)d_in[11];
    const float* skip_b  = (const float*)d_in[12];
    const float* bn_g    = (const float*)d_in[13];
    const float* bn_b    = (const float*)d_in[14];
    const float* nv1     = (const float*)d_in[15];
    const float* nv2     = (const float*)d_in[16];
    const float* task    = (const float*)d_in[17];
    const float* gcn_w   = (const float*)d_in[18];
    const float* gcn_b   = (const float*)d_in[19];
    const float* h0_w1   = (const float*)d_in[20];
    const float* h0_b1   = (const float*)d_in[21];
    const float* h0_w2   = (const float*)d_in[22];
    const float* h0_b2   = (const float*)d_in[23];
    const float* h1_w1   = (const float*)d_in[24];
    const float* h1_b1   = (const float*)d_in[25];
    const float* h1_w2   = (const float*)d_in[26];
    const float* h1_b2   = (const float*)d_in[27];

    float* ws    = (float*)d_ws;
    float* adp   = ws + OFF_ADP;
    float* S     = ws + OFF_S;
    float* x1    = ws + OFF_X1;
    float* x2    = ws + OFF_X2;
    float* c01   = ws + OFF_C01;
    float* wgcnT = ws + OFF_WGCNT;
    float* w1tT  = ws + OFF_W1TT;
    float* part  = ws + OFF_PART;
    float* outp  = (float*)d_out;

    hipMemsetAsync(adp, 0, (size_t)NPAD * NPAD * sizeof(float), stream);
    hipMemsetAsync(S + (size_t)NN * BCD, 0, (size_t)(NPAD - NN) * BCD * sizeof(float), stream);

    prep_kernel<<<1, 256, 0, stream>>>(gcn_w, h0_w1, h0_b1, h1_w1, h1_b1, task,
                                       c01, wgcnT, w1tT);
    adp_kernel<<<NN, 256, 0, stream>>>(nv1, nv2, adp);

    const int K2_LDS = 38912 * 4; // 152 KiB dynamic LDS
    hipFuncSetAttribute(reinterpret_cast<const void*>(temporal_kernel),
                        hipFuncAttributeMaxDynamicSharedMemorySize, K2_LDS);
    temporal_kernel<<<ITEMS / 32, 1024, K2_LDS, stream>>>(
        X, start_w, start_b, filt_w, filt_b, gate_w, gate_b,
        skip_w, skip_b, bn_g, bn_b, S);

    dim3 gg(BCD / 128, NPAD / 128);
    gemm_tn<<<gg, 256, 0, stream>>>(adp, S, x1);   // x1 = skip · adp
    gemm_tn<<<gg, 256, 0, stream>>>(adp, x1, x2);  // x2 = x1 · adp

    head_kernel<<<512, 256, 0, stream>>>(S, x1, x2, wgcnT, gcn_b, c01, w1tT,
                                         h0_w2, h0_b2, h1_w2, h1_b2,
                                         Ct, Yf, outp, part);
    finalize_kernel<<<1, 128, 0, stream>>>(part, task, outp);
}

// Round 3
// 40521.414 us; speedup vs baseline: 1.1541x; 1.1541x over previous
//
#include <hip/hip_runtime.h>
#include <cstdint>

// ---------------- problem constants ----------------
#define NB 64        // batch
#define TT 8         // timesteps
#define NN 2000      // nodes
#define NF 16        // in features
#define NCH 64       // channels
#define NPAD 2048    // padded node dim
#define BCD 4096     // NB*NCH
#define ITEMS 128000 // NB*NN

// ws offsets (floats)
#define OFF_ADP   0                        // 2048*2048   = 4194304
#define OFF_S     4194304                  // 2048*4096   = 8388608
#define OFF_X1    (OFF_S + 8388608)
#define OFF_X2    (OFF_X1 + 8388608)
#define OFF_C01   (OFF_X2 + 8388608)       // 128
#define OFF_WGCNT (OFF_C01 + 128)          // 192*64 = 12288
#define OFF_W1TT  (OFF_WGCNT + 12288)      // 2*64*64 = 8192
#define OFF_PART  (OFF_W1TT + 8192)        // 2048*132 = 270336
#define OFF_PW    (OFF_PART + 270336)      // 3*4096*4 = 49152 packed conv weights
#define OFF_SKT   (OFF_PW + 49152)         // 3*4096 skip weights transposed

// ---------------- K0: tiny precompute (transposes + packing + task-dot) ----------------
__global__ void prep_kernel(const float* __restrict__ gcn_w,
                            const float* __restrict__ h0_w1, const float* __restrict__ h0_b1,
                            const float* __restrict__ h1_w1, const float* __restrict__ h1_b1,
                            const float* __restrict__ task_emb,
                            const float* __restrict__ filt_w, const float* __restrict__ gate_w,
                            const float* __restrict__ skip_w,
                            float* __restrict__ c01, float* __restrict__ wgcnT,
                            float* __restrict__ w1tT, float* __restrict__ pw,
                            float* __restrict__ skT)
{
    int tid = threadIdx.x;
    for (int idx = tid; idx < 64 * 192; idx += 256) {
        int o = idx / 192, j = idx % 192;
        wgcnT[j * 64 + o] = gcn_w[idx];
    }
    for (int idx = tid; idx < 4096; idx += 256) {
        int o = idx >> 6, c = idx & 63;
        w1tT[c * 64 + o]        = h0_w1[o * 128 + 64 + c];
        w1tT[4096 + c * 64 + o] = h1_w1[o * 128 + 64 + c];
    }
    // pack conv weights: pw4[L][c*64+o] = {f[o][c][0], f[o][c][1], g[o][c][0], g[o][c][1]}
    // skT[L][c*64+o] = skip_w[L][o][c]
    for (int idx = tid; idx < 3 * 4096; idx += 256) {
        int L = idx >> 12, rem = idx & 4095;
        int c = rem >> 6, o = rem & 63;
        float f0 = filt_w[L * 8192 + o * 128 + c * 2];
        float f1 = filt_w[L * 8192 + o * 128 + c * 2 + 1];
        float g0 = gate_w[L * 8192 + o * 128 + c * 2];
        float g1 = gate_w[L * 8192 + o * 128 + c * 2 + 1];
        ((float4*)pw)[idx] = make_float4(f0, f1, g0, g1);
        skT[idx] = skip_w[L * 4096 + o * 64 + c];
    }
    if (tid < 128) {
        int head = tid >> 6, o = tid & 63;
        const float* w1 = head ? h1_w1 : h0_w1;
        const float* b1 = head ? h1_b1 : h0_b1;
        float a = b1[o];
        for (int k = 0; k < 64; ++k) a = fmaf(w1[o * 128 + k], task_emb[k], a);
        c01[tid] = a;
    }
}

// ---------------- K1: adp = softmax(relu(nv1@nv2), axis=1), padded to 2048 cols ----------------
__global__ __launch_bounds__(256) void adp_kernel(const float* __restrict__ nv1,
                                                  const float* __restrict__ nv2,
                                                  float* __restrict__ adp)
{
    __shared__ float nv1s[10];
    __shared__ float rbuf[4];
    int tid = threadIdx.x;
    int r = blockIdx.x;
    if (tid < 10) nv1s[tid] = nv1[r * 10 + tid];
    __syncthreads();

    float val[8];
    float vmax = -3.4e38f;
    #pragma unroll
    for (int s = 0; s < 8; ++s) {
        int j = tid + s * 256;
        if (j < NN) {
            float v = 0.f;
            #pragma unroll
            for (int k = 0; k < 10; ++k) v = fmaf(nv1s[k], nv2[k * NN + j], v);
            v = fmaxf(v, 0.f);
            val[s] = v;
            vmax = fmaxf(vmax, v);
        } else val[s] = -3.4e38f;
    }
    for (int off = 32; off; off >>= 1) vmax = fmaxf(vmax, __shfl_down(vmax, off, 64));
    if ((tid & 63) == 0) rbuf[tid >> 6] = vmax;
    __syncthreads();
    vmax = fmaxf(fmaxf(rbuf[0], rbuf[1]), fmaxf(rbuf[2], rbuf[3]));
    __syncthreads();
    float sum = 0.f;
    #pragma unroll
    for (int s = 0; s < 8; ++s) {
        int j = tid + s * 256;
        if (j < NN) { val[s] = expf(val[s] - vmax); sum += val[s]; }
    }
    for (int off = 32; off; off >>= 1) sum += __shfl_down(sum, off, 64);
    if ((tid & 63) == 0) rbuf[tid >> 6] = sum;
    __syncthreads();
    sum = rbuf[0] + rbuf[1] + rbuf[2] + rbuf[3];
    float inv = 1.f / sum;
    #pragma unroll
    for (int s = 0; s < 8; ++s) {
        int j = tid + s * 256;
        if (j < NN) adp[r * NPAD + j] = val[s] * inv;
    }
}

// ---------------- K2: fused temporal stack (v3) ----------------
// 1024 threads = 16 waves; 32 items/block; wave owns 2 items (lane = out channel).
// LDS: xstate[32][8t][64c] (64KB, lane-stride-1 / b128 broadcast)
//      gbuf[32][64] (8KB), pwlds float4[c][o] (64KB), slds[c][o] (16KB) = 152KB
// No persistent per-thread state arrays -> no spills (VGPR cap 128 at 4 waves/SIMD).
#define TK_GI 2

template<int LAYER, int D, int WIN, int WOUT>
__device__ __forceinline__ void do_layer(
    float* __restrict__ xstate, float* __restrict__ gbuf,
    float* __restrict__ pwlds, float* __restrict__ slds,
    const float* __restrict__ pw, const float* __restrict__ skT,
    const float* __restrict__ filt_b, const float* __restrict__ gate_b,
    const float* __restrict__ skip_b,
    const float* __restrict__ bn_g, const float* __restrict__ bn_b,
    float* __restrict__ sacc)
{
    int tid = threadIdx.x;
    int wave = tid >> 6, o = tid & 63;
    // stage packed weights: fully coalesced float4 copies
    for (int idx = tid; idx < 4096; idx += 1024) {
        ((float4*)pwlds)[idx] = ((const float4*)pw)[LAYER * 4096 + idx];
        slds[idx] = skT[LAYER * 4096 + idx];
    }
    __syncthreads();

    float fb = filt_b[LAYER * 64 + o], gb = gate_b[LAYER * 64 + o];
    float skb = skip_b[LAYER * 64 + o];
    float bscale = bn_g[LAYER * 64 + o] * rsqrtf(1.0f + 1e-5f);
    float bshift = bn_b[LAYER * 64 + o];

    #pragma unroll
    for (int gi = 0; gi < TK_GI; ++gi) {
        int g = wave * TK_GI + gi;
        const float4* xs4 = (const float4*)&xstate[g * 512];   // [t][c] rows as float4
        float facc[WOUT], gacc[WOUT];
        #pragma unroll
        for (int t = 0; t < WOUT; ++t) { facc[t] = fb; gacc[t] = gb; }

        #pragma unroll
        for (int c0 = 0; c0 < 16; ++c0) {
            float4 xq[WIN];
            #pragma unroll
            for (int t = 0; t < WIN; ++t) xq[t] = xs4[t * 16 + c0];  // b128 broadcast
            #pragma unroll
            for (int j = 0; j < 4; ++j) {
                float4 w = ((const float4*)pwlds)[(c0 * 4 + j) * 64 + o];  // one b128/lane
                #pragma unroll
                for (int t = 0; t < WOUT; ++t) {
                    float xt  = ((const float*)&xq[t])[j];
                    float xtd = ((const float*)&xq[t + D])[j];
                    facc[t] = fmaf(w.x, xt, fmaf(w.y, xtd, facc[t]));
                    gacc[t] = fmaf(w.z, xt, fmaf(w.w, xtd, gacc[t]));
                }
            }
        }
        float gated[WOUT];
        #pragma unroll
        for (int t = 0; t < WOUT; ++t)
            gated[t] = tanhf(facc[t]) * (1.0f / (1.0f + expf(-gacc[t])));

        // publish gated[last] for skip conv (same-wave lockstep exchange)
        gbuf[g * 64 + o] = gated[WOUT - 1];
        asm volatile("" ::: "memory");
        float s = skb;
        const float4* gb4 = (const float4*)&gbuf[g * 64];
        #pragma unroll
        for (int c0 = 0; c0 < 16; ++c0) {
            float4 gq = gb4[c0];                       // b128 broadcast
            #pragma unroll
            for (int j = 0; j < 4; ++j)
                s = fmaf(slds[(c0 * 4 + j) * 64 + o], ((const float*)&gq)[j], s);
        }
        sacc[gi] += s;

        // residual + eval-mode BN: read own-channel xold (lane-stride-1), then update
        float xo[WOUT];
        #pragma unroll
        for (int t = 0; t < WOUT; ++t) xo[t] = xstate[g * 512 + (t + D) * 64 + o];
        #pragma unroll
        for (int t = 0; t < WOUT; ++t)
            xstate[g * 512 + t * 64 + o] = fmaf(gated[t] + xo[t], bscale, bshift);
        asm volatile("" ::: "memory");
    }
    __syncthreads();  // all waves done reading weights before next layer restage
}

__global__ __launch_bounds__(1024) void temporal_kernel(
    const float* __restrict__ X,
    const float* __restrict__ start_w, const float* __restrict__ start_b,
    const float* __restrict__ pw, const float* __restrict__ skT,
    const float* __restrict__ filt_b, const float* __restrict__ gate_b,
    const float* __restrict__ skip_b,
    const float* __restrict__ bn_g, const float* __restrict__ bn_b,
    float* __restrict__ S)
{
    extern __shared__ float smem[];
    float* xstate = smem;           // 16384 floats [32][8][64]
    float* gbuf   = smem + 16384;   // 2048
    float* pwlds  = smem + 18432;   // 16384 (float4[4096])
    float* slds   = smem + 34816;   // 4096
    float* xstage = pwlds;          // overlap: X staging (4096 floats) before weights

    int tid = threadIdx.x;
    int wave = tid >> 6, o = tid & 63;
    int item0 = blockIdx.x * 32;

    for (int idx = tid; idx < 32 * 128; idx += 1024) {
        int g = idx >> 7, rem = idx & 127;
        int ig = item0 + g;
        int b = ig / NN, n = ig - b * NN;
        int t = rem >> 4, f = rem & 15;
        xstage[idx] = X[((b * TT + t) * NN + n) * NF + f];
    }
    __syncthreads();

    // start 1x1 conv (F=16 -> CH=64)
    {
        float wst[16];
        #pragma unroll
        for (int f4 = 0; f4 < 16; f4 += 4) {
            float4 v = *(const float4*)&start_w[o * 16 + f4];
            wst[f4] = v.x; wst[f4+1] = v.y; wst[f4+2] = v.z; wst[f4+3] = v.w;
        }
        float sb = start_b[o];
        #pragma unroll
        for (int gi = 0; gi < TK_GI; ++gi) {
            int g = wave * TK_GI + gi;
            const float4* xr4 = (const float4*)&xstage[g * 128];
            #pragma unroll
            for (int t = 0; t < 8; ++t) {
                float acc = sb;
                #pragma unroll
                for (int f4 = 0; f4 < 4; ++f4) {
                    float4 xv = xr4[t * 4 + f4];       // b128 broadcast
                    acc = fmaf(wst[f4*4],   xv.x, acc);
                    acc = fmaf(wst[f4*4+1], xv.y, acc);
                    acc = fmaf(wst[f4*4+2], xv.z, acc);
                    acc = fmaf(wst[f4*4+3], xv.w, acc);
                }
                xstate[g * 512 + t * 64 + o] = acc;    // lane-stride-1
            }
        }
    }
    __syncthreads();  // xstage (aliases pwlds) free; xstate visible

    float sacc[TK_GI] = {0, 0};
    do_layer<0, 1, 8, 7>(xstate, gbuf, pwlds, slds, pw, skT, filt_b, gate_b,
                         skip_b, bn_g, bn_b, sacc);
    do_layer<1, 2, 7, 5>(xstate, gbuf, pwlds, slds, pw, skT, filt_b, gate_b,
                         skip_b, bn_g, bn_b, sacc);
    do_layer<2, 4, 5, 1>(xstate, gbuf, pwlds, slds, pw, skT, filt_b, gate_b,
                         skip_b, bn_g, bn_b, sacc);

    // write skip_final: S[n][b*64+o] (K-major for GEMM)
    #pragma unroll
    for (int gi = 0; gi < TK_GI; ++gi) {
        int ig = item0 + wave * TK_GI + gi;
        int b = ig / NN, n = ig - b * NN;
        S[n * BCD + b * 64 + o] = sacc[gi];
    }
}

// ---------------- K3: TN GEMM, C[m][n] = sum_k A[k][m]*B[k][n] ----------------
__global__ __launch_bounds__(256) void gemm_tn(const float* __restrict__ A,
                                               const float* __restrict__ B,
                                               float* __restrict__ Cm)
{
    __shared__ float As[16][132];
    __shared__ float Bs[16][132];
    int tid = threadIdx.x;
    int tx = tid & 15, ty = tid >> 4;
    int m0 = blockIdx.y * 128, n0 = blockIdx.x * 128;
    float acc[8][8] = {};
    for (int k0 = 0; k0 < NPAD; k0 += 16) {
        #pragma unroll
        for (int l = 0; l < 2; ++l) {
            int fi = tid * 4 + l * 1024;
            int r = fi >> 7, c = fi & 127;
            *(float4*)&As[r][c] = *(const float4*)&A[(k0 + r) * NPAD + m0 + c];
            *(float4*)&Bs[r][c] = *(const float4*)&B[(k0 + r) * BCD + n0 + c];
        }
        __syncthreads();
        #pragma unroll
        for (int kk = 0; kk < 16; ++kk) {
            float a[8], b[8];
            *(float4*)&a[0] = *(float4*)&As[kk][ty * 8];
            *(float4*)&a[4] = *(float4*)&As[kk][ty * 8 + 4];
            *(float4*)&b[0] = *(float4*)&Bs[kk][tx * 8];
            *(float4*)&b[4] = *(float4*)&Bs[kk][tx * 8 + 4];
            #pragma unroll
            for (int i = 0; i < 8; ++i)
                #pragma unroll
                for (int j = 0; j < 8; ++j)
                    acc[i][j] = fmaf(a[i], b[j], acc[i][j]);
        }
        __syncthreads();
    }
    #pragma unroll
    for (int i = 0; i < 8; ++i) {
        int m = m0 + ty * 8 + i;
        *(float4*)&Cm[m * BCD + n0 + tx * 8]     = make_float4(acc[i][0], acc[i][1], acc[i][2], acc[i][3]);
        *(float4*)&Cm[m * BCD + n0 + tx * 8 + 4] = make_float4(acc[i][4], acc[i][5], acc[i][6], acc[i][7]);
    }
}

// ---------------- K4: gcn 1x1 + heads + outputs + partial reductions ----------------
__global__ __launch_bounds__(256) void head_kernel(
    const float* __restrict__ S, const float* __restrict__ x1, const float* __restrict__ x2,
    const float* __restrict__ wgcnT, const float* __restrict__ gcn_b,
    const float* __restrict__ c01, const float* __restrict__ w1tT,
    const float* __restrict__ h0_w2, const float* __restrict__ h0_b2,
    const float* __restrict__ h1_w2, const float* __restrict__ h1_b2,
    const int* __restrict__ Ct, const float* __restrict__ Yf,
    float* __restrict__ out, float* __restrict__ partials)
{
    __shared__ float hl[4][4][192];
    __shared__ float gxl[4][4][64];
    int tid = threadIdx.x;
    int wave = tid >> 6, o = tid & 63;
    int wid = blockIdx.x * 4 + wave;  // 0..2047
    float w2a = h0_w2[o], w2b = h1_w2[o];
    float b20 = h0_b2[0], b21 = h1_b2[0];
    float cb = gcn_b[o], c0a = c01[o], c0b = c01[64 + o];

    float accT = 0.f, accC = 0.f, bce = 0.f, cT = 0.f, cC = 0.f;

    for (int base = wid * 4; base < ITEMS; base += 2048 * 4) {
        #pragma unroll
        for (int it = 0; it < 4; ++it) {
            int item = base + it;
            int b = item / NN, n = item - b * NN;
            int off = n * BCD + b * 64 + o;
            hl[wave][it][o]       = S[off];
            hl[wave][it][64 + o]  = x1[off];
            hl[wave][it][128 + o] = x2[off];
        }
        float a0 = cb, a1 = cb, a2 = cb, a3 = cb;
        for (int j = 0; j < 192; ++j) {
            float w = wgcnT[j * 64 + o];
            a0 = fmaf(w, hl[wave][0][j], a0);
            a1 = fmaf(w, hl[wave][1][j], a1);
            a2 = fmaf(w, hl[wave][2][j], a2);
            a3 = fmaf(w, hl[wave][3][j], a3);
        }
        float gxv[4] = {fmaxf(a0, 0.f), fmaxf(a1, 0.f), fmaxf(a2, 0.f), fmaxf(a3, 0.f)};
        #pragma unroll
        for (int it = 0; it < 4; ++it) gxl[wave][it][o] = gxv[it];

        float p0[4], p1[4];
        #pragma unroll
        for (int it = 0; it < 4; ++it) { p0[it] = c0a; p1[it] = c0b; }
        for (int c = 0; c < 64; ++c) {
            float w0 = w1tT[c * 64 + o];
            float w1 = w1tT[4096 + c * 64 + o];
            float g0 = gxl[wave][0][c], g1 = gxl[wave][1][c];
            float g2 = gxl[wave][2][c], g3 = gxl[wave][3][c];
            p0[0] = fmaf(w0, g0, p0[0]); p0[1] = fmaf(w0, g1, p0[1]);
            p0[2] = fmaf(w0, g2, p0[2]); p0[3] = fmaf(w0, g3, p0[3]);
            p1[0] = fmaf(w1, g0, p1[0]); p1[1] = fmaf(w1, g1, p1[1]);
            p1[2] = fmaf(w1, g2, p1[2]); p1[3] = fmaf(w1, g3, p1[3]);
        }
        #pragma unroll
        for (int it = 0; it < 4; ++it) {
            float r0 = w2a * fmaxf(p0[it], 0.f);
            float r1 = w2b * fmaxf(p1[it], 0.f);
            #pragma unroll
            for (int off = 32; off; off >>= 1) {
                r0 += __shfl_down(r0, off, 64);
                r1 += __shfl_down(r1, off, 64);
            }
            int item = base + it;
            int tt = Ct[item];
            if (o == 0) {
                float y0 = 1.f / (1.f + expf(-(r0 + b20)));
                float y1 = 1.f / (1.f + expf(-(r1 + b21)));
                float y = (tt > 0) ? y1 : y0;
                out[1 + item] = y;
                out[1 + ITEMS + item] = y0;
                out[1 + 2 * ITEMS + item] = y1;
                float yc = fminf(fmaxf(y, 1e-7f), 1.f - 1e-7f);
                float Yv = Yf[item];
                bce -= Yv * logf(yc) + (1.f - Yv) * logf(1.f - yc);
                if (tt > 0) cT += 1.f; else cC += 1.f;
            }
            if (tt > 0) accT += gxv[it]; else accC += gxv[it];
        }
    }
    partials[wid * 132 + o] = accT;
    partials[wid * 132 + 64 + o] = accC;
    if (o == 0) {
        partials[wid * 132 + 128] = bce;
        partials[wid * 132 + 129] = cT;
        partials[wid * 132 + 130] = cC;
    }
}

// ---------------- K5: final loss ----------------
__global__ void finalize_kernel(const float* __restrict__ partials,
                                const float* __restrict__ task_emb,
                                float* __restrict__ out)
{
    __shared__ float red[131];
    int tid = threadIdx.x; // 128
    for (int slot = tid; slot < 131; slot += 128) {
        float s = 0.f;
        for (int w = 0; w < 2048; ++w) s += partials[w * 132 + slot];
        red[slot] = s;
    }
    __syncthreads();
    if (tid < 64) {
        float cT = red[129], cC = red[130];
        float iT = 1.f / fmaxf(cT, 1.f), iC = 1.f / fmaxf(cC, 1.f);
        float d1 = task_emb[tid] * (cT * iT) - task_emb[tid] * (cC * iC);
        float d2 = red[tid] * iT - red[64 + tid] * iC;
        float p = d1 * d1 + d2 * d2;
        #pragma unroll
        for (int off = 32; off; off >>= 1) p += __shfl_down(p, off, 64);
        if (tid == 0) out[0] = red[128] * (1.f / (float)ITEMS) + p;
    }
}

// ---------------- launch ----------------
extern "C" void kernel_launch(void* const* d_in, const int* in_sizes, int n_in,
                              void* d_out, int out_size, void* d_ws, size_t ws_size,
                              hipStream_t stream)
{
    const float* X       = (const float*)d_in[0];
    const int*   Ct      = (const int*)d_in[2];
    const float* Yf      = (const float*)d_in[3];
    const float* start_w = (const float*)d_in[5];
    const float* start_b = (const float*)d_in[6];
    const float* filt_w  = (const float*)d_in[7];
    const float* filt_b  = (const float*)d_in[8];
    const float* gate_w  = (const float*)d_in[9];
    const float* gate_b  = (const float*)d_in[10];
    const float* skip_w  = (const float*)d_in[11];
    const float* skip_b  = (const float*)d_in[12];
    const float* bn_g    = (const float*)d_in[13];
    const float* bn_b    = (const float*)d_in[14];
    const float* nv1     = (const float*)d_in[15];
    const float* nv2     = (const float*)d_in[16];
    const float* task    = (const float*)d_in[17];
    const float* gcn_w   = (const float*)d_in[18];
    const float* gcn_b   = (const float*)d_in[19];
    const float* h0_w1   = (const float*)d_in[20];
    const float* h0_b1   = (const float*)d_in[21];
    const float* h0_w2   = (const float*)d_in[22];
    const float* h0_b2   = (const float*)d_in[23];
    const float* h1_w1   = (const float*)d_in[24];
    const float* h1_b1   = (const float*)d_in[25];
    const float* h1_w2   = (const float*)d_in[26];
    const float* h1_b2   = (const float*)d_in[27];

    float* ws    = (float*)d_ws;
    float* adp   = ws + OFF_ADP;
    float* S     = ws + OFF_S;
    float* x1    = ws + OFF_X1;
    float* x2    = ws + OFF_X2;
    float* c01   = ws + OFF_C01;
    float* wgcnT = ws + OFF_WGCNT;
    float* w1tT  = ws + OFF_W1TT;
    float* part  = ws + OFF_PART;
    float* pw    = ws + OFF_PW;
    float* skT   = ws + OFF_SKT;
    float* outp  = (float*)d_out;

    hipMemsetAsync(adp, 0, (size_t)NPAD * NPAD * sizeof(float), stream);
    hipMemsetAsync(S + (size_t)NN * BCD, 0, (size_t)(NPAD - NN) * BCD * sizeof(float), stream);

    prep_kernel<<<1, 256, 0, stream>>>(gcn_w, h0_w1, h0_b1, h1_w1, h1_b1, task,
                                       filt_w, gate_w, skip_w,
                                       c01, wgcnT, w1tT, pw, skT);
    adp_kernel<<<NN, 256, 0, stream>>>(nv1, nv2, adp);

    const int K2_LDS = 38912 * 4; // 152 KiB dynamic LDS
    hipFuncSetAttribute(reinterpret_cast<const void*>(temporal_kernel),
                        hipFuncAttributeMaxDynamicSharedMemorySize, K2_LDS);
    temporal_kernel<<<ITEMS / 32, 1024, K2_LDS, stream>>>(
        X, start_w, start_b, pw, skT, filt_b, gate_b,
        skip_b, bn_g, bn_b, S);

    dim3 gg(BCD / 128, NPAD / 128);
    gemm_tn<<<gg, 256, 0, stream>>>(adp, S, x1);   // x1 = skip · adp
    gemm_tn<<<gg, 256, 0, stream>>>(adp, x1, x2);  // x2 = x1 · adp

    head_kernel<<<512, 256, 0, stream>>>(S, x1, x2, wgcnT, gcn_b, c01, w1tT,
                                         h0_w2, h0_b2, h1_w2, h1_b2,
                                         Ct, Yf, outp, part);
    finalize_kernel<<<1, 128, 0, stream>>>(part, task, outp);
}

// Round 4
// 4451.266 us; speedup vs baseline: 10.5063x; 9.1033x over previous
//
#include <hip/hip_runtime.h>
#include <cstdint>

// ---------------- problem constants ----------------
#define NB 64        // batch
#define TT 8         // timesteps
#define NN 2000      // nodes
#define NF 16        // in features
#define NCH 64       // channels
#define NPAD 2048    // padded node dim
#define BCD 4096     // NB*NCH
#define ITEMS 128000 // NB*NN

// ws offsets (floats)
#define OFF_ADP   0                        // 2048*2048   = 4194304
#define OFF_S     4194304                  // 2048*4096   = 8388608
#define OFF_X1    (OFF_S + 8388608)
#define OFF_X2    (OFF_X1 + 8388608)
#define OFF_C01   (OFF_X2 + 8388608)       // 128
#define OFF_WGCNT (OFF_C01 + 128)          // 192*64 = 12288
#define OFF_W1TT  (OFF_WGCNT + 12288)      // 2*64*64 = 8192
#define OFF_PART  (OFF_W1TT + 8192)        // 2048*132 = 270336
#define OFF_PW    (OFF_PART + 270336)      // 3*4096*4 = 49152 packed conv weights
#define OFF_SKT   (OFF_PW + 49152)         // 3*4096 skip weights transposed

__device__ __forceinline__ float fast_rcp(float x) { return __builtin_amdgcn_rcpf(x); }
__device__ __forceinline__ float fast_tanh(float x) {
    x = fminf(fmaxf(x, -10.f), 10.f);
    float e = __expf(2.f * x);
    return (e - 1.f) * fast_rcp(e + 1.f);
}
__device__ __forceinline__ float fast_sigmoid(float x) {
    return fast_rcp(1.f + __expf(-x));
}

// ---------------- K0: tiny precompute (transposes + packing + task-dot) ----------------
__global__ void prep_kernel(const float* __restrict__ gcn_w,
                            const float* __restrict__ h0_w1, const float* __restrict__ h0_b1,
                            const float* __restrict__ h1_w1, const float* __restrict__ h1_b1,
                            const float* __restrict__ task_emb,
                            const float* __restrict__ filt_w, const float* __restrict__ gate_w,
                            const float* __restrict__ skip_w,
                            float* __restrict__ c01, float* __restrict__ wgcnT,
                            float* __restrict__ w1tT, float* __restrict__ pw,
                            float* __restrict__ skT)
{
    int tid = threadIdx.x;
    for (int idx = tid; idx < 64 * 192; idx += 256) {
        int o = idx / 192, j = idx % 192;
        wgcnT[j * 64 + o] = gcn_w[idx];
    }
    for (int idx = tid; idx < 4096; idx += 256) {
        int o = idx >> 6, c = idx & 63;
        w1tT[c * 64 + o]        = h0_w1[o * 128 + 64 + c];
        w1tT[4096 + c * 64 + o] = h1_w1[o * 128 + 64 + c];
    }
    // pw4[L][c*64+o] = {f[o][c][0], f[o][c][1], g[o][c][0], g[o][c][1]}; skT[L][c*64+o] = skip_w[L][o][c]
    for (int idx = tid; idx < 3 * 4096; idx += 256) {
        int L = idx >> 12, rem = idx & 4095;
        int c = rem >> 6, o = rem & 63;
        float f0 = filt_w[L * 8192 + o * 128 + c * 2];
        float f1 = filt_w[L * 8192 + o * 128 + c * 2 + 1];
        float g0 = gate_w[L * 8192 + o * 128 + c * 2];
        float g1 = gate_w[L * 8192 + o * 128 + c * 2 + 1];
        ((float4*)pw)[idx] = make_float4(f0, f1, g0, g1);
        skT[idx] = skip_w[L * 4096 + o * 64 + c];
    }
    if (tid < 128) {
        int head = tid >> 6, o = tid & 63;
        const float* w1 = head ? h1_w1 : h0_w1;
        const float* b1 = head ? h1_b1 : h0_b1;
        float a = b1[o];
        for (int k = 0; k < 64; ++k) a = fmaf(w1[o * 128 + k], task_emb[k], a);
        c01[tid] = a;
    }
}

// ---------------- K1: adp = softmax(relu(nv1@nv2), axis=1), padded to 2048 cols ----------------
__global__ __launch_bounds__(256) void adp_kernel(const float* __restrict__ nv1,
                                                  const float* __restrict__ nv2,
                                                  float* __restrict__ adp)
{
    __shared__ float nv1s[10];
    __shared__ float rbuf[4];
    int tid = threadIdx.x;
    int r = blockIdx.x;
    if (tid < 10) nv1s[tid] = nv1[r * 10 + tid];
    __syncthreads();

    float val[8];
    float vmax = -3.4e38f;
    #pragma unroll
    for (int s = 0; s < 8; ++s) {
        int j = tid + s * 256;
        if (j < NN) {
            float v = 0.f;
            #pragma unroll
            for (int k = 0; k < 10; ++k) v = fmaf(nv1s[k], nv2[k * NN + j], v);
            v = fmaxf(v, 0.f);
            val[s] = v;
            vmax = fmaxf(vmax, v);
        } else val[s] = -3.4e38f;
    }
    for (int off = 32; off; off >>= 1) vmax = fmaxf(vmax, __shfl_down(vmax, off, 64));
    if ((tid & 63) == 0) rbuf[tid >> 6] = vmax;
    __syncthreads();
    vmax = fmaxf(fmaxf(rbuf[0], rbuf[1]), fmaxf(rbuf[2], rbuf[3]));
    __syncthreads();
    float sum = 0.f;
    #pragma unroll
    for (int s = 0; s < 8; ++s) {
        int j = tid + s * 256;
        if (j < NN) { val[s] = expf(val[s] - vmax); sum += val[s]; }
    }
    for (int off = 32; off; off >>= 1) sum += __shfl_down(sum, off, 64);
    if ((tid & 63) == 0) rbuf[tid >> 6] = sum;
    __syncthreads();
    sum = rbuf[0] + rbuf[1] + rbuf[2] + rbuf[3];
    float inv = 1.f / sum;
    #pragma unroll
    for (int s = 0; s < 8; ++s) {
        int j = tid + s * 256;
        if (j < NN) adp[r * NPAD + j] = val[s] * inv;
    }
}

// ---------------- K2: fused temporal stack (v4: no address-escaping locals) ----------------
// 1024 threads = 16 waves; 32 items/block; wave owns 2 items (lane = out channel).
// LDS: xstate[32][8t][64c] (64KB), gbuf[32][64] (8KB), pwlds float4[c][o] (64KB),
//      slds[c][o] (16KB) = 152KB. All per-thread arrays statically indexed, no casts.
#define TK_GI 2

template<int LAYER, int D, int WIN, int WOUT>
__device__ __forceinline__ void do_layer(
    float* __restrict__ xstate, float* __restrict__ gbuf,
    float* __restrict__ pwlds, float* __restrict__ slds,
    const float* __restrict__ pw, const float* __restrict__ skT,
    const float* __restrict__ filt_b, const float* __restrict__ gate_b,
    const float* __restrict__ skip_b,
    const float* __restrict__ bn_g, const float* __restrict__ bn_b,
    float* __restrict__ sacc)
{
    int tid = threadIdx.x;
    int wave = tid >> 6, o = tid & 63;
    for (int idx = tid; idx < 4096; idx += 1024) {
        ((float4*)pwlds)[idx] = ((const float4*)pw)[LAYER * 4096 + idx];
        slds[idx] = skT[LAYER * 4096 + idx];
    }
    __syncthreads();

    float fb = filt_b[LAYER * 64 + o], gb = gate_b[LAYER * 64 + o];
    float skb = skip_b[LAYER * 64 + o];
    float bscale = bn_g[LAYER * 64 + o] * rsqrtf(1.0f + 1e-5f);
    float bshift = bn_b[LAYER * 64 + o];
    const float4* pw4 = (const float4*)pwlds;

    #pragma unroll
    for (int gi = 0; gi < TK_GI; ++gi) {
        int g = wave * TK_GI + gi;
        const float4* xs4 = (const float4*)&xstate[g * 512];   // [t][c] rows as float4
        float facc[WOUT], gacc[WOUT];
        #pragma unroll
        for (int t = 0; t < WOUT; ++t) { facc[t] = fb; gacc[t] = gb; }

        #pragma unroll
        for (int c0 = 0; c0 < 16; ++c0) {
            float4 xq[WIN];
            #pragma unroll
            for (int t = 0; t < WIN; ++t) xq[t] = xs4[t * 16 + c0];  // b128 broadcast
            float4 w0 = pw4[(c0 * 4 + 0) * 64 + o];
            float4 w1 = pw4[(c0 * 4 + 1) * 64 + o];
            float4 w2 = pw4[(c0 * 4 + 2) * 64 + o];
            float4 w3 = pw4[(c0 * 4 + 3) * 64 + o];
            #pragma unroll
            for (int t = 0; t < WOUT; ++t) {
                facc[t] = fmaf(w0.x, xq[t].x, fmaf(w0.y, xq[t + D].x, facc[t]));
                gacc[t] = fmaf(w0.z, xq[t].x, fmaf(w0.w, xq[t + D].x, gacc[t]));
                facc[t] = fmaf(w1.x, xq[t].y, fmaf(w1.y, xq[t + D].y, facc[t]));
                gacc[t] = fmaf(w1.z, xq[t].y, fmaf(w1.w, xq[t + D].y, gacc[t]));
                facc[t] = fmaf(w2.x, xq[t].z, fmaf(w2.y, xq[t + D].z, facc[t]));
                gacc[t] = fmaf(w2.z, xq[t].z, fmaf(w2.w, xq[t + D].z, gacc[t]));
                facc[t] = fmaf(w3.x, xq[t].w, fmaf(w3.y, xq[t + D].w, facc[t]));
                gacc[t] = fmaf(w3.z, xq[t].w, fmaf(w3.w, xq[t + D].w, gacc[t]));
            }
        }
        float gated[WOUT];
        #pragma unroll
        for (int t = 0; t < WOUT; ++t)
            gated[t] = fast_tanh(facc[t]) * fast_sigmoid(gacc[t]);

        // publish gated[last] for skip conv (same-wave lockstep exchange)
        gbuf[g * 64 + o] = gated[WOUT - 1];
        asm volatile("" ::: "memory");
        float s = skb;
        const float4* gb4 = (const float4*)&gbuf[g * 64];
        #pragma unroll
        for (int c0 = 0; c0 < 16; ++c0) {
            float4 gq = gb4[c0];                       // b128 broadcast
            s = fmaf(slds[(c0 * 4 + 0) * 64 + o], gq.x, s);
            s = fmaf(slds[(c0 * 4 + 1) * 64 + o], gq.y, s);
            s = fmaf(slds[(c0 * 4 + 2) * 64 + o], gq.z, s);
            s = fmaf(slds[(c0 * 4 + 3) * 64 + o], gq.w, s);
        }
        sacc[gi] += s;

        // residual + eval-mode BN: read own-channel xold (lane-stride-1), then update
        float xo[WOUT];
        #pragma unroll
        for (int t = 0; t < WOUT; ++t) xo[t] = xstate[g * 512 + (t + D) * 64 + o];
        #pragma unroll
        for (int t = 0; t < WOUT; ++t)
            xstate[g * 512 + t * 64 + o] = fmaf(gated[t] + xo[t], bscale, bshift);
        asm volatile("" ::: "memory");
    }
    __syncthreads();
}

__global__ __launch_bounds__(1024) void temporal_kernel(
    const float* __restrict__ X,
    const float* __restrict__ start_w, const float* __restrict__ start_b,
    const float* __restrict__ pw, const float* __restrict__ skT,
    const float* __restrict__ filt_b, const float* __restrict__ gate_b,
    const float* __restrict__ skip_b,
    const float* __restrict__ bn_g, const float* __restrict__ bn_b,
    float* __restrict__ S)
{
    extern __shared__ float smem[];
    float* xstate = smem;           // 16384 floats [32][8][64]
    float* gbuf   = smem + 16384;   // 2048
    float* pwlds  = smem + 18432;   // 16384 (float4[4096])
    float* slds   = smem + 34816;   // 4096
    float* xstage = pwlds;          // overlap: X staging (4096 floats) before weights

    int tid = threadIdx.x;
    int wave = tid >> 6, o = tid & 63;
    int item0 = blockIdx.x * 32;

    for (int idx = tid; idx < 32 * 128; idx += 1024) {
        int g = idx >> 7, rem = idx & 127;
        int ig = item0 + g;
        int b = ig / NN, n = ig - b * NN;
        int t = rem >> 4, f = rem & 15;
        xstage[idx] = X[((b * TT + t) * NN + n) * NF + f];
    }
    __syncthreads();

    // start 1x1 conv (F=16 -> CH=64)
    {
        float4 wv0 = *(const float4*)&start_w[o * 16];
        float4 wv1 = *(const float4*)&start_w[o * 16 + 4];
        float4 wv2 = *(const float4*)&start_w[o * 16 + 8];
        float4 wv3 = *(const float4*)&start_w[o * 16 + 12];
        float sb = start_b[o];
        #pragma unroll
        for (int gi = 0; gi < TK_GI; ++gi) {
            int g = wave * TK_GI + gi;
            const float4* xr4 = (const float4*)&xstage[g * 128];
            #pragma unroll
            for (int t = 0; t < 8; ++t) {
                float acc = sb;
                float4 xa = xr4[t * 4 + 0];
                float4 xb = xr4[t * 4 + 1];
                float4 xc = xr4[t * 4 + 2];
                float4 xd = xr4[t * 4 + 3];
                acc = fmaf(wv0.x, xa.x, acc); acc = fmaf(wv0.y, xa.y, acc);
                acc = fmaf(wv0.z, xa.z, acc); acc = fmaf(wv0.w, xa.w, acc);
                acc = fmaf(wv1.x, xb.x, acc); acc = fmaf(wv1.y, xb.y, acc);
                acc = fmaf(wv1.z, xb.z, acc); acc = fmaf(wv1.w, xb.w, acc);
                acc = fmaf(wv2.x, xc.x, acc); acc = fmaf(wv2.y, xc.y, acc);
                acc = fmaf(wv2.z, xc.z, acc); acc = fmaf(wv2.w, xc.w, acc);
                acc = fmaf(wv3.x, xd.x, acc); acc = fmaf(wv3.y, xd.y, acc);
                acc = fmaf(wv3.z, xd.z, acc); acc = fmaf(wv3.w, xd.w, acc);
                xstate[g * 512 + t * 64 + o] = acc;    // lane-stride-1
            }
        }
    }
    __syncthreads();  // xstage (aliases pwlds) free; xstate visible

    float sacc[TK_GI] = {0, 0};
    do_layer<0, 1, 8, 7>(xstate, gbuf, pwlds, slds, pw, skT, filt_b, gate_b,
                         skip_b, bn_g, bn_b, sacc);
    do_layer<1, 2, 7, 5>(xstate, gbuf, pwlds, slds, pw, skT, filt_b, gate_b,
                         skip_b, bn_g, bn_b, sacc);
    do_layer<2, 4, 5, 1>(xstate, gbuf, pwlds, slds, pw, skT, filt_b, gate_b,
                         skip_b, bn_g, bn_b, sacc);

    // write skip_final: S[n][b*64+o] (K-major for GEMM)
    #pragma unroll
    for (int gi = 0; gi < TK_GI; ++gi) {
        int ig = item0 + wave * TK_GI + gi;
        int b = ig / NN, n = ig - b * NN;
        S[n * BCD + b * 64 + o] = sacc[gi];
    }
}

// ---------------- K3: TN GEMM, C[m][n] = sum_k A[k][m]*B[k][n] ----------------
__global__ __launch_bounds__(256) void gemm_tn(const float* __restrict__ A,
                                               const float* __restrict__ B,
                                               float* __restrict__ Cm)
{
    __shared__ float As[16][132];
    __shared__ float Bs[16][132];
    int tid = threadIdx.x;
    int tx = tid & 15, ty = tid >> 4;
    int m0 = blockIdx.y * 128, n0 = blockIdx.x * 128;
    float acc[8][8] = {};
    for (int k0 = 0; k0 < NPAD; k0 += 16) {
        #pragma unroll
        for (int l = 0; l < 2; ++l) {
            int fi = tid * 4 + l * 1024;
            int r = fi >> 7, c = fi & 127;
            *(float4*)&As[r][c] = *(const float4*)&A[(k0 + r) * NPAD + m0 + c];
            *(float4*)&Bs[r][c] = *(const float4*)&B[(k0 + r) * BCD + n0 + c];
        }
        __syncthreads();
        #pragma unroll
        for (int kk = 0; kk < 16; ++kk) {
            float a[8], b[8];
            *(float4*)&a[0] = *(float4*)&As[kk][ty * 8];
            *(float4*)&a[4] = *(float4*)&As[kk][ty * 8 + 4];
            *(float4*)&b[0] = *(float4*)&Bs[kk][tx * 8];
            *(float4*)&b[4] = *(float4*)&Bs[kk][tx * 8 + 4];
            #pragma unroll
            for (int i = 0; i < 8; ++i)
                #pragma unroll
                for (int j = 0; j < 8; ++j)
                    acc[i][j] = fmaf(a[i], b[j], acc[i][j]);
        }
        __syncthreads();
    }
    #pragma unroll
    for (int i = 0; i < 8; ++i) {
        int m = m0 + ty * 8 + i;
        *(float4*)&Cm[m * BCD + n0 + tx * 8]     = make_float4(acc[i][0], acc[i][1], acc[i][2], acc[i][3]);
        *(float4*)&Cm[m * BCD + n0 + tx * 8 + 4] = make_float4(acc[i][4], acc[i][5], acc[i][6], acc[i][7]);
    }
}

// ---------------- K4: gcn 1x1 + heads + outputs + partial reductions ----------------
__global__ __launch_bounds__(256) void head_kernel(
    const float* __restrict__ S, const float* __restrict__ x1, const float* __restrict__ x2,
    const float* __restrict__ wgcnT, const float* __restrict__ gcn_b,
    const float* __restrict__ c01, const float* __restrict__ w1tT,
    const float* __restrict__ h0_w2, const float* __restrict__ h0_b2,
    const float* __restrict__ h1_w2, const float* __restrict__ h1_b2,
    const int* __restrict__ Ct, const float* __restrict__ Yf,
    float* __restrict__ out, float* __restrict__ partials)
{
    __shared__ float hl[4][4][192];
    __shared__ float gxl[4][4][64];
    int tid = threadIdx.x;
    int wave = tid >> 6, o = tid & 63;
    int wid = blockIdx.x * 4 + wave;  // 0..2047
    float w2a = h0_w2[o], w2b = h1_w2[o];
    float b20 = h0_b2[0], b21 = h1_b2[0];
    float cb = gcn_b[o], c0a = c01[o], c0b = c01[64 + o];

    float accT = 0.f, accC = 0.f, bce = 0.f, cT = 0.f, cC = 0.f;

    for (int base = wid * 4; base < ITEMS; base += 2048 * 4) {
        #pragma unroll
        for (int it = 0; it < 4; ++it) {
            int item = base + it;
            int b = item / NN, n = item - b * NN;
            int off = n * BCD + b * 64 + o;
            hl[wave][it][o]       = S[off];
            hl[wave][it][64 + o]  = x1[off];
            hl[wave][it][128 + o] = x2[off];
        }
        float a0 = cb, a1 = cb, a2 = cb, a3 = cb;
        for (int j = 0; j < 192; ++j) {
            float w = wgcnT[j * 64 + o];
            a0 = fmaf(w, hl[wave][0][j], a0);
            a1 = fmaf(w, hl[wave][1][j], a1);
            a2 = fmaf(w, hl[wave][2][j], a2);
            a3 = fmaf(w, hl[wave][3][j], a3);
        }
        float gxv[4] = {fmaxf(a0, 0.f), fmaxf(a1, 0.f), fmaxf(a2, 0.f), fmaxf(a3, 0.f)};
        #pragma unroll
        for (int it = 0; it < 4; ++it) gxl[wave][it][o] = gxv[it];

        float p0[4], p1[4];
        #pragma unroll
        for (int it = 0; it < 4; ++it) { p0[it] = c0a; p1[it] = c0b; }
        for (int c = 0; c < 64; ++c) {
            float w0 = w1tT[c * 64 + o];
            float w1 = w1tT[4096 + c * 64 + o];
            float g0 = gxl[wave][0][c], g1 = gxl[wave][1][c];
            float g2 = gxl[wave][2][c], g3 = gxl[wave][3][c];
            p0[0] = fmaf(w0, g0, p0[0]); p0[1] = fmaf(w0, g1, p0[1]);
            p0[2] = fmaf(w0, g2, p0[2]); p0[3] = fmaf(w0, g3, p0[3]);
            p1[0] = fmaf(w1, g0, p1[0]); p1[1] = fmaf(w1, g1, p1[1]);
            p1[2] = fmaf(w1, g2, p1[2]); p1[3] = fmaf(w1, g3, p1[3]);
        }
        #pragma unroll
        for (int it = 0; it < 4; ++it) {
            float r0 = w2a * fmaxf(p0[it], 0.f);
            float r1 = w2b * fmaxf(p1[it], 0.f);
            #pragma unroll
            for (int off = 32; off; off >>= 1) {
                r0 += __shfl_down(r0, off, 64);
                r1 += __shfl_down(r1, off, 64);
            }
            int item = base + it;
            int tt = Ct[item];
            if (o == 0) {
                float y0 = 1.f / (1.f + expf(-(r0 + b20)));
                float y1 = 1.f / (1.f + expf(-(r1 + b21)));
                float y = (tt > 0) ? y1 : y0;
                out[1 + item] = y;
                out[1 + ITEMS + item] = y0;
                out[1 + 2 * ITEMS + item] = y1;
                float yc = fminf(fmaxf(y, 1e-7f), 1.f - 1e-7f);
                float Yv = Yf[item];
                bce -= Yv * logf(yc) + (1.f - Yv) * logf(1.f - yc);
                if (tt > 0) cT += 1.f; else cC += 1.f;
            }
            if (tt > 0) accT += gxv[it]; else accC += gxv[it];
        }
    }
    partials[wid * 132 + o] = accT;
    partials[wid * 132 + 64 + o] = accC;
    if (o == 0) {
        partials[wid * 132 + 128] = bce;
        partials[wid * 132 + 129] = cT;
        partials[wid * 132 + 130] = cC;
    }
}

// ---------------- K5: final loss ----------------
__global__ void finalize_kernel(const float* __restrict__ partials,
                                const float* __restrict__ task_emb,
                                float* __restrict__ out)
{
    __shared__ float red[131];
    int tid = threadIdx.x; // 128
    for (int slot = tid; slot < 131; slot += 128) {
        float s = 0.f;
        for (int w = 0; w < 2048; ++w) s += partials[w * 132 + slot];
        red[slot] = s;
    }
    __syncthreads();
    if (tid < 64) {
        float cT = red[129], cC = red[130];
        float iT = 1.f / fmaxf(cT, 1.f), iC = 1.f / fmaxf(cC, 1.f);
        float d1 = task_emb[tid] * (cT * iT) - task_emb[tid] * (cC * iC);
        float d2 = red[tid] * iT - red[64 + tid] * iC;
        float p = d1 * d1 + d2 * d2;
        #pragma unroll
        for (int off = 32; off; off >>= 1) p += __shfl_down(p, off, 64);
        if (tid == 0) out[0] = red[128] * (1.f / (float)ITEMS) + p;
    }
}

// ---------------- launch ----------------
extern "C" void kernel_launch(void* const* d_in, const int* in_sizes, int n_in,
                              void* d_out, int out_size, void* d_ws, size_t ws_size,
                              hipStream_t stream)
{
    const float* X       = (const float*)d_in[0];
    const int*   Ct      = (const int*)d_in[2];
    const float* Yf      = (const float*)d_in[3];
    const float* start_w = (const float*)d_in[5];
    const float* start_b = (const float*)d_in[6];
    const float* filt_w  = (const float*)d_in[7];
    const float* filt_b  = (const float*)d_in[8];
    const float* gate_w  = (const float*)d_in[9];
    const float* gate_b  = (const float*)d_in[10];
    const float* skip_w  = (const float*)d_in[11];
    const float* skip_b  = (const float*)d_in[12];
    const float* bn_g    = (const float*)d_in[13];
    const float* bn_b    = (const float*)d_in[14];
    const float* nv1     = (const float*)d_in[15];
    const float* nv2     = (const float*)d_in[16];
    const float* task    = (const float*)d_in[17];
    const float* gcn_w   = (const float*)d_in[18];
    const float* gcn_b   = (const float*)d_in[19];
    const float* h0_w1   = (const float*)d_in[20];
    const float* h0_b1   = (const float*)d_in[21];
    const float* h0_w2   = (const float*)d_in[22];
    const float* h0_b2   = (const float*)d_in[23];
    const float* h1_w1   = (const float*)d_in[24];
    const float* h1_b1   = (const float*)d_in[25];
    const float* h1_w2   = (const float*)d_in[26];
    const float* h1_b2   = (const float*)d_in[27];

    float* ws    = (float*)d_ws;
    float* adp   = ws + OFF_ADP;
    float* S     = ws + OFF_S;
    float* x1    = ws + OFF_X1;
    float* x2    = ws + OFF_X2;
    float* c01   = ws + OFF_C01;
    float* wgcnT = ws + OFF_WGCNT;
    float* w1tT  = ws + OFF_W1TT;
    float* part  = ws + OFF_PART;
    float* pw    = ws + OFF_PW;
    float* skT   = ws + OFF_SKT;
    float* outp  = (float*)d_out;

    hipMemsetAsync(adp, 0, (size_t)NPAD * NPAD * sizeof(float), stream);
    hipMemsetAsync(S + (size_t)NN * BCD, 0, (size_t)(NPAD - NN) * BCD * sizeof(float), stream);

    prep_kernel<<<1, 256, 0, stream>>>(gcn_w, h0_w1, h0_b1, h1_w1, h1_b1, task,
                                       filt_w, gate_w, skip_w,
                                       c01, wgcnT, w1tT, pw, skT);
    adp_kernel<<<NN, 256, 0, stream>>>(nv1, nv2, adp);

    const int K2_LDS = 38912 * 4; // 152 KiB dynamic LDS
    hipFuncSetAttribute(reinterpret_cast<const void*>(temporal_kernel),
                        hipFuncAttributeMaxDynamicSharedMemorySize, K2_LDS);
    temporal_kernel<<<ITEMS / 32, 1024, K2_LDS, stream>>>(
        X, start_w, start_b, pw, skT, filt_b, gate_b,
        skip_b, bn_g, bn_b, S);

    dim3 gg(BCD / 128, NPAD / 128);
    gemm_tn<<<gg, 256, 0, stream>>>(adp, S, x1);   // x1 = skip · adp
    gemm_tn<<<gg, 256, 0, stream>>>(adp, x1, x2);  // x2 = x1 · adp

    head_kernel<<<512, 256, 0, stream>>>(S, x1, x2, wgcnT, gcn_b, c01, w1tT,
                                         h0_w2, h0_b2, h1_w2, h1_b2,
                                         Ct, Yf, outp, part);
    finalize_kernel<<<1, 128, 0, stream>>>(part, task, outp);
}

// Round 5
// 2919.874 us; speedup vs baseline: 16.0166x; 1.5245x over previous
//
#include <hip/hip_runtime.h>
#include <cstdint>

// ---------------- problem constants ----------------
#define NB 64        // batch
#define TT 8         // timesteps
#define NN 2000      // nodes
#define NF 16        // in features
#define NCH 64       // channels
#define NPAD 2048    // padded node dim
#define BCD 4096     // NB*NCH
#define ITEMS 128000 // NB*NN

// ws offsets (floats)
#define OFF_ADP   0                        // 2048*2048   = 4194304
#define OFF_S     4194304                  // 2048*4096   = 8388608
#define OFF_X1    (OFF_S + 8388608)
#define OFF_X2    (OFF_X1 + 8388608)
#define OFF_C01   (OFF_X2 + 8388608)       // 128
#define OFF_WGCNT (OFF_C01 + 128)          // 192*64 = 12288
#define OFF_W1TT  (OFF_WGCNT + 12288)      // 2*64*64 = 8192
#define OFF_PART  (OFF_W1TT + 8192)        // 2048*132 = 270336
#define OFF_PW    (OFF_PART + 270336)      // 3*4096*4 = 49152 packed conv weights
#define OFF_SKT   (OFF_PW + 49152)         // 3*4096 skip weights transposed

__device__ __forceinline__ float fast_rcp(float x) { return __builtin_amdgcn_rcpf(x); }
__device__ __forceinline__ float fast_tanh(float x) {
    x = fminf(fmaxf(x, -10.f), 10.f);
    float e = __expf(2.f * x);
    return (e - 1.f) * fast_rcp(e + 1.f);
}
__device__ __forceinline__ float fast_sigmoid(float x) {
    return fast_rcp(1.f + __expf(-x));
}

// ---------------- K0: tiny precompute (transposes + packing + task-dot) ----------------
__global__ void prep_kernel(const float* __restrict__ gcn_w,
                            const float* __restrict__ h0_w1, const float* __restrict__ h0_b1,
                            const float* __restrict__ h1_w1, const float* __restrict__ h1_b1,
                            const float* __restrict__ task_emb,
                            const float* __restrict__ filt_w, const float* __restrict__ gate_w,
                            const float* __restrict__ skip_w,
                            float* __restrict__ c01, float* __restrict__ wgcnT,
                            float* __restrict__ w1tT, float* __restrict__ pw,
                            float* __restrict__ skT)
{
    int tid = threadIdx.x;
    for (int idx = tid; idx < 64 * 192; idx += 256) {
        int o = idx / 192, j = idx % 192;
        wgcnT[j * 64 + o] = gcn_w[idx];
    }
    for (int idx = tid; idx < 4096; idx += 256) {
        int o = idx >> 6, c = idx & 63;
        w1tT[c * 64 + o]        = h0_w1[o * 128 + 64 + c];
        w1tT[4096 + c * 64 + o] = h1_w1[o * 128 + 64 + c];
    }
    // pw4[L][c*64+o] = {f[o][c][0], f[o][c][1], g[o][c][0], g[o][c][1]}; skT[L][c*64+o] = skip_w[L][o][c]
    for (int idx = tid; idx < 3 * 4096; idx += 256) {
        int L = idx >> 12, rem = idx & 4095;
        int c = rem >> 6, o = rem & 63;
        float f0 = filt_w[L * 8192 + o * 128 + c * 2];
        float f1 = filt_w[L * 8192 + o * 128 + c * 2 + 1];
        float g0 = gate_w[L * 8192 + o * 128 + c * 2];
        float g1 = gate_w[L * 8192 + o * 128 + c * 2 + 1];
        ((float4*)pw)[idx] = make_float4(f0, f1, g0, g1);
        skT[idx] = skip_w[L * 4096 + o * 64 + c];
    }
    if (tid < 128) {
        int head = tid >> 6, o = tid & 63;
        const float* w1 = head ? h1_w1 : h0_w1;
        const float* b1 = head ? h1_b1 : h0_b1;
        float a = b1[o];
        for (int k = 0; k < 64; ++k) a = fmaf(w1[o * 128 + k], task_emb[k], a);
        c01[tid] = a;
    }
}

// ---------------- K1: adp = softmax(relu(nv1@nv2), axis=1), padded to 2048 cols ----------------
__global__ __launch_bounds__(256) void adp_kernel(const float* __restrict__ nv1,
                                                  const float* __restrict__ nv2,
                                                  float* __restrict__ adp)
{
    __shared__ float nv1s[10];
    __shared__ float rbuf[4];
    int tid = threadIdx.x;
    int r = blockIdx.x;
    if (tid < 10) nv1s[tid] = nv1[r * 10 + tid];
    __syncthreads();

    float val[8];
    float vmax = -3.4e38f;
    #pragma unroll
    for (int s = 0; s < 8; ++s) {
        int j = tid + s * 256;
        if (j < NN) {
            float v = 0.f;
            #pragma unroll
            for (int k = 0; k < 10; ++k) v = fmaf(nv1s[k], nv2[k * NN + j], v);
            v = fmaxf(v, 0.f);
            val[s] = v;
            vmax = fmaxf(vmax, v);
        } else val[s] = -3.4e38f;
    }
    for (int off = 32; off; off >>= 1) vmax = fmaxf(vmax, __shfl_down(vmax, off, 64));
    if ((tid & 63) == 0) rbuf[tid >> 6] = vmax;
    __syncthreads();
    vmax = fmaxf(fmaxf(rbuf[0], rbuf[1]), fmaxf(rbuf[2], rbuf[3]));
    __syncthreads();
    float sum = 0.f;
    #pragma unroll
    for (int s = 0; s < 8; ++s) {
        int j = tid + s * 256;
        if (j < NN) { val[s] = expf(val[s] - vmax); sum += val[s]; }
    }
    for (int off = 32; off; off >>= 1) sum += __shfl_down(sum, off, 64);
    if ((tid & 63) == 0) rbuf[tid >> 6] = sum;
    __syncthreads();
    sum = rbuf[0] + rbuf[1] + rbuf[2] + rbuf[3];
    float inv = 1.f / sum;
    #pragma unroll
    for (int s = 0; s < 8; ++s) {
        int j = tid + s * 256;
        if (j < NN) adp[r * NPAD + j] = val[s] * inv;
    }
}

// ---------------- K2: fused temporal stack (v5: small live set, no spills) ----------------
// 1024 threads = 16 waves; 32 items/block; wave owns 2 items (lane = out channel).
// LDS: xstate[32][8t][64c] (64KB), gbuf[32][64] (8KB), pwlds float4[c][o] (64KB),
//      slds[c][o] (16KB) = 152KB.
// Inner conv loop: per-channel scalar form — WIN b32 LDS broadcasts + 1 b128 weight
// read per c; live set ~35 VGPRs so even a 64-VGPR cap produces zero scratch.
#define TK_GI 2

template<int LAYER, int D, int WIN, int WOUT>
__device__ __forceinline__ void do_layer(
    float* __restrict__ xstate, float* __restrict__ gbuf,
    float* __restrict__ pwlds, float* __restrict__ slds,
    const float* __restrict__ pw, const float* __restrict__ skT,
    const float* __restrict__ filt_b, const float* __restrict__ gate_b,
    const float* __restrict__ skip_b,
    const float* __restrict__ bn_g, const float* __restrict__ bn_b,
    float* __restrict__ sacc)
{
    int tid = threadIdx.x;
    int wave = tid >> 6, o = tid & 63;
    for (int idx = tid; idx < 4096; idx += 1024) {
        ((float4*)pwlds)[idx] = ((const float4*)pw)[LAYER * 4096 + idx];
        slds[idx] = skT[LAYER * 4096 + idx];
    }
    __syncthreads();

    float fb = filt_b[LAYER * 64 + o], gb = gate_b[LAYER * 64 + o];
    float skb = skip_b[LAYER * 64 + o];
    float bscale = bn_g[LAYER * 64 + o] * rsqrtf(1.0f + 1e-5f);
    float bshift = bn_b[LAYER * 64 + o];
    const float4* pw4 = (const float4*)pwlds;

    #pragma unroll
    for (int gi = 0; gi < TK_GI; ++gi) {
        int g = wave * TK_GI + gi;
        const float* xs = &xstate[g * 512];        // [t][c]
        float facc[WOUT], gacc[WOUT];
        #pragma unroll
        for (int t = 0; t < WOUT; ++t) { facc[t] = fb; gacc[t] = gb; }

        #pragma unroll 2
        for (int c = 0; c < 64; ++c) {
            float xv[WIN];
            #pragma unroll
            for (int t = 0; t < WIN; ++t) xv[t] = xs[t * 64 + c];   // b32 broadcast
            float4 w = pw4[c * 64 + o];                             // b128 lane-stride-1
            #pragma unroll
            for (int t = 0; t < WOUT; ++t) {
                facc[t] = fmaf(w.x, xv[t], fmaf(w.y, xv[t + D], facc[t]));
                gacc[t] = fmaf(w.z, xv[t], fmaf(w.w, xv[t + D], gacc[t]));
            }
        }
        float gated[WOUT];
        #pragma unroll
        for (int t = 0; t < WOUT; ++t)
            gated[t] = fast_tanh(facc[t]) * fast_sigmoid(gacc[t]);

        // publish gated[last] for skip conv (same-wave lockstep exchange)
        gbuf[g * 64 + o] = gated[WOUT - 1];
        asm volatile("" ::: "memory");
        float s = skb;
        #pragma unroll 8
        for (int c = 0; c < 64; ++c)
            s = fmaf(slds[c * 64 + o], gbuf[g * 64 + c], s);        // b32 bcast + b32
        sacc[gi] += s;

        // residual + eval-mode BN: read own-channel xold (lane-stride-1), then update
        float xo[WOUT];
        #pragma unroll
        for (int t = 0; t < WOUT; ++t) xo[t] = xstate[g * 512 + (t + D) * 64 + o];
        #pragma unroll
        for (int t = 0; t < WOUT; ++t)
            xstate[g * 512 + t * 64 + o] = fmaf(gated[t] + xo[t], bscale, bshift);
        asm volatile("" ::: "memory");
    }
    __syncthreads();
}

__global__ __launch_bounds__(1024) void temporal_kernel(
    const float* __restrict__ X,
    const float* __restrict__ start_w, const float* __restrict__ start_b,
    const float* __restrict__ pw, const float* __restrict__ skT,
    const float* __restrict__ filt_b, const float* __restrict__ gate_b,
    const float* __restrict__ skip_b,
    const float* __restrict__ bn_g, const float* __restrict__ bn_b,
    float* __restrict__ S)
{
    extern __shared__ float smem[];
    float* xstate = smem;           // 16384 floats [32][8][64]
    float* gbuf   = smem + 16384;   // 2048
    float* pwlds  = smem + 18432;   // 16384 (float4[4096])
    float* slds   = smem + 34816;   // 4096
    float* xstage = pwlds;          // overlap: X staging (4096 floats) before weights

    int tid = threadIdx.x;
    int wave = tid >> 6, o = tid & 63;
    int item0 = blockIdx.x * 32;

    for (int idx = tid; idx < 32 * 128; idx += 1024) {
        int g = idx >> 7, rem = idx & 127;
        int ig = item0 + g;
        int b = ig / NN, n = ig - b * NN;
        int t = rem >> 4, f = rem & 15;
        xstage[idx] = X[((b * TT + t) * NN + n) * NF + f];
    }
    __syncthreads();

    // start 1x1 conv (F=16 -> CH=64): per-f scalar broadcasts, small live set
    {
        float sb = start_b[o];
        #pragma unroll
        for (int gi = 0; gi < TK_GI; ++gi) {
            int g = wave * TK_GI + gi;
            const float* xr = &xstage[g * 128];
            #pragma unroll
            for (int t = 0; t < 8; ++t) {
                float acc = sb;
                #pragma unroll
                for (int f = 0; f < 16; ++f)
                    acc = fmaf(start_w[o * 16 + f], xr[t * 16 + f], acc);
                xstate[g * 512 + t * 64 + o] = acc;    // lane-stride-1
            }
        }
    }
    __syncthreads();  // xstage (aliases pwlds) free; xstate visible

    float sacc[TK_GI] = {0, 0};
    do_layer<0, 1, 8, 7>(xstate, gbuf, pwlds, slds, pw, skT, filt_b, gate_b,
                         skip_b, bn_g, bn_b, sacc);
    do_layer<1, 2, 7, 5>(xstate, gbuf, pwlds, slds, pw, skT, filt_b, gate_b,
                         skip_b, bn_g, bn_b, sacc);
    do_layer<2, 4, 5, 1>(xstate, gbuf, pwlds, slds, pw, skT, filt_b, gate_b,
                         skip_b, bn_g, bn_b, sacc);

    // write skip_final: S[n][b*64+o] (K-major for GEMM)
    #pragma unroll
    for (int gi = 0; gi < TK_GI; ++gi) {
        int ig = item0 + wave * TK_GI + gi;
        int b = ig / NN, n = ig - b * NN;
        S[n * BCD + b * 64 + o] = sacc[gi];
    }
}

// ---------------- K3: TN GEMM, C[m][n] = sum_k A[k][m]*B[k][n] ----------------
__global__ __launch_bounds__(256) void gemm_tn(const float* __restrict__ A,
                                               const float* __restrict__ B,
                                               float* __restrict__ Cm)
{
    __shared__ float As[16][132];
    __shared__ float Bs[16][132];
    int tid = threadIdx.x;
    int tx = tid & 15, ty = tid >> 4;
    int m0 = blockIdx.y * 128, n0 = blockIdx.x * 128;
    float acc[8][8] = {};
    for (int k0 = 0; k0 < NPAD; k0 += 16) {
        #pragma unroll
        for (int l = 0; l < 2; ++l) {
            int fi = tid * 4 + l * 1024;
            int r = fi >> 7, c = fi & 127;
            *(float4*)&As[r][c] = *(const float4*)&A[(k0 + r) * NPAD + m0 + c];
            *(float4*)&Bs[r][c] = *(const float4*)&B[(k0 + r) * BCD + n0 + c];
        }
        __syncthreads();
        #pragma unroll
        for (int kk = 0; kk < 16; ++kk) {
            float a[8], b[8];
            *(float4*)&a[0] = *(float4*)&As[kk][ty * 8];
            *(float4*)&a[4] = *(float4*)&As[kk][ty * 8 + 4];
            *(float4*)&b[0] = *(float4*)&Bs[kk][tx * 8];
            *(float4*)&b[4] = *(float4*)&Bs[kk][tx * 8 + 4];
            #pragma unroll
            for (int i = 0; i < 8; ++i)
                #pragma unroll
                for (int j = 0; j < 8; ++j)
                    acc[i][j] = fmaf(a[i], b[j], acc[i][j]);
        }
        __syncthreads();
    }
    #pragma unroll
    for (int i = 0; i < 8; ++i) {
        int m = m0 + ty * 8 + i;
        *(float4*)&Cm[m * BCD + n0 + tx * 8]     = make_float4(acc[i][0], acc[i][1], acc[i][2], acc[i][3]);
        *(float4*)&Cm[m * BCD + n0 + tx * 8 + 4] = make_float4(acc[i][4], acc[i][5], acc[i][6], acc[i][7]);
    }
}

// ---------------- K4: gcn 1x1 + heads + outputs + partial reductions ----------------
__global__ __launch_bounds__(256) void head_kernel(
    const float* __restrict__ S, const float* __restrict__ x1, const float* __restrict__ x2,
    const float* __restrict__ wgcnT, const float* __restrict__ gcn_b,
    const float* __restrict__ c01, const float* __restrict__ w1tT,
    const float* __restrict__ h0_w2, const float* __restrict__ h0_b2,
    const float* __restrict__ h1_w2, const float* __restrict__ h1_b2,
    const int* __restrict__ Ct, const float* __restrict__ Yf,
    float* __restrict__ out, float* __restrict__ partials)
{
    __shared__ float hl[4][4][192];
    __shared__ float gxl[4][4][64];
    int tid = threadIdx.x;
    int wave = tid >> 6, o = tid & 63;
    int wid = blockIdx.x * 4 + wave;  // 0..2047
    float w2a = h0_w2[o], w2b = h1_w2[o];
    float b20 = h0_b2[0], b21 = h1_b2[0];
    float cb = gcn_b[o], c0a = c01[o], c0b = c01[64 + o];

    float accT = 0.f, accC = 0.f, bce = 0.f, cT = 0.f, cC = 0.f;

    for (int base = wid * 4; base < ITEMS; base += 2048 * 4) {
        #pragma unroll
        for (int it = 0; it < 4; ++it) {
            int item = base + it;
            int b = item / NN, n = item - b * NN;
            int off = n * BCD + b * 64 + o;
            hl[wave][it][o]       = S[off];
            hl[wave][it][64 + o]  = x1[off];
            hl[wave][it][128 + o] = x2[off];
        }
        float a0 = cb, a1 = cb, a2 = cb, a3 = cb;
        for (int j = 0; j < 192; ++j) {
            float w = wgcnT[j * 64 + o];
            a0 = fmaf(w, hl[wave][0][j], a0);
            a1 = fmaf(w, hl[wave][1][j], a1);
            a2 = fmaf(w, hl[wave][2][j], a2);
            a3 = fmaf(w, hl[wave][3][j], a3);
        }
        float gxv[4] = {fmaxf(a0, 0.f), fmaxf(a1, 0.f), fmaxf(a2, 0.f), fmaxf(a3, 0.f)};
        #pragma unroll
        for (int it = 0; it < 4; ++it) gxl[wave][it][o] = gxv[it];

        float p0[4], p1[4];
        #pragma unroll
        for (int it = 0; it < 4; ++it) { p0[it] = c0a; p1[it] = c0b; }
        for (int c = 0; c < 64; ++c) {
            float w0 = w1tT[c * 64 + o];
            float w1 = w1tT[4096 + c * 64 + o];
            float g0 = gxl[wave][0][c], g1 = gxl[wave][1][c];
            float g2 = gxl[wave][2][c], g3 = gxl[wave][3][c];
            p0[0] = fmaf(w0, g0, p0[0]); p0[1] = fmaf(w0, g1, p0[1]);
            p0[2] = fmaf(w0, g2, p0[2]); p0[3] = fmaf(w0, g3, p0[3]);
            p1[0] = fmaf(w1, g0, p1[0]); p1[1] = fmaf(w1, g1, p1[1]);
            p1[2] = fmaf(w1, g2, p1[2]); p1[3] = fmaf(w1, g3, p1[3]);
        }
        #pragma unroll
        for (int it = 0; it < 4; ++it) {
            float r0 = w2a * fmaxf(p0[it], 0.f);
            float r1 = w2b * fmaxf(p1[it], 0.f);
            #pragma unroll
            for (int off = 32; off; off >>= 1) {
                r0 += __shfl_down(r0, off, 64);
                r1 += __shfl_down(r1, off, 64);
            }
            int item = base + it;
            int tt = Ct[item];
            if (o == 0) {
                float y0 = 1.f / (1.f + expf(-(r0 + b20)));
                float y1 = 1.f / (1.f + expf(-(r1 + b21)));
                float y = (tt > 0) ? y1 : y0;
                out[1 + item] = y;
                out[1 + ITEMS + item] = y0;
                out[1 + 2 * ITEMS + item] = y1;
                float yc = fminf(fmaxf(y, 1e-7f), 1.f - 1e-7f);
                float Yv = Yf[item];
                bce -= Yv * logf(yc) + (1.f - Yv) * logf(1.f - yc);
                if (tt > 0) cT += 1.f; else cC += 1.f;
            }
            if (tt > 0) accT += gxv[it]; else accC += gxv[it];
        }
    }
    partials[wid * 132 + o] = accT;
    partials[wid * 132 + 64 + o] = accC;
    if (o == 0) {
        partials[wid * 132 + 128] = bce;
        partials[wid * 132 + 129] = cT;
        partials[wid * 132 + 130] = cC;
    }
}

// ---------------- K5: final loss ----------------
__global__ void finalize_kernel(const float* __restrict__ partials,
                                const float* __restrict__ task_emb,
                                float* __restrict__ out)
{
    __shared__ float red[131];
    int tid = threadIdx.x; // 128
    for (int slot = tid; slot < 131; slot += 128) {
        float s = 0.f;
        for (int w = 0; w < 2048; ++w) s += partials[w * 132 + slot];
        red[slot] = s;
    }
    __syncthreads();
    if (tid < 64) {
        float cT = red[129], cC = red[130];
        float iT = 1.f / fmaxf(cT, 1.f), iC = 1.f / fmaxf(cC, 1.f);
        float d1 = task_emb[tid] * (cT * iT) - task_emb[tid] * (cC * iC);
        float d2 = red[tid] * iT - red[64 + tid] * iC;
        float p = d1 * d1 + d2 * d2;
        #pragma unroll
        for (int off = 32; off; off >>= 1) p += __shfl_down(p, off, 64);
        if (tid == 0) out[0] = red[128] * (1.f / (float)ITEMS) + p;
    }
}

// ---------------- launch ----------------
extern "C" void kernel_launch(void* const* d_in, const int* in_sizes, int n_in,
                              void* d_out, int out_size, void* d_ws, size_t ws_size,
                              hipStream_t stream)
{
    const float* X       = (const float*)d_in[0];
    const int*   Ct      = (const int*)d_in[2];
    const float* Yf      = (const float*)d_in[3];
    const float* start_w = (const float*)d_in[5];
    const float* start_b = (const float*)d_in[6];
    const float* filt_w  = (const float*)d_in[7];
    const float* filt_b  = (const float*)d_in[8];
    const float* gate_w  = (const float*)d_in[9];
    const float* gate_b  = (const float*)d_in[10];
    const float* skip_w  = (const float*)d_in[11];
    const float* skip_b  = (const float*)d_in[12];
    const float* bn_g    = (const float*)d_in[13];
    const float* bn_b    = (const float*)d_in[14];
    const float* nv1     = (const float*)d_in[15];
    const float* nv2     = (const float*)d_in[16];
    const float* task    = (const float*)d_in[17];
    const float* gcn_w   = (const float*)d_in[18];
    const float* gcn_b   = (const float*)d_in[19];
    const float* h0_w1   = (const float*)d_in[20];
    const float* h0_b1   = (const float*)d_in[21];
    const float* h0_w2   = (const float*)d_in[22];
    const float* h0_b2   = (const float*)d_in[23];
    const float* h1_w1   = (const float*)d_in[24];
    const float* h1_b1   = (const float*)d_in[25];
    const float* h1_w2   = (const float*)d_in[26];
    const float* h1_b2   = (const float*)d_in[27];

    float* ws    = (float*)d_ws;
    float* adp   = ws + OFF_ADP;
    float* S     = ws + OFF_S;
    float* x1    = ws + OFF_X1;
    float* x2    = ws + OFF_X2;
    float* c01   = ws + OFF_C01;
    float* wgcnT = ws + OFF_WGCNT;
    float* w1tT  = ws + OFF_W1TT;
    float* part  = ws + OFF_PART;
    float* pw    = ws + OFF_PW;
    float* skT   = ws + OFF_SKT;
    float* outp  = (float*)d_out;

    hipMemsetAsync(adp, 0, (size_t)NPAD * NPAD * sizeof(float), stream);
    hipMemsetAsync(S + (size_t)NN * BCD, 0, (size_t)(NPAD - NN) * BCD * sizeof(float), stream);

    prep_kernel<<<1, 256, 0, stream>>>(gcn_w, h0_w1, h0_b1, h1_w1, h1_b1, task,
                                       filt_w, gate_w, skip_w,
                                       c01, wgcnT, w1tT, pw, skT);
    adp_kernel<<<NN, 256, 0, stream>>>(nv1, nv2, adp);

    const int K2_LDS = 38912 * 4; // 152 KiB dynamic LDS
    hipFuncSetAttribute(reinterpret_cast<const void*>(temporal_kernel),
                        hipFuncAttributeMaxDynamicSharedMemorySize, K2_LDS);
    temporal_kernel<<<ITEMS / 32, 1024, K2_LDS, stream>>>(
        X, start_w, start_b, pw, skT, filt_b, gate_b,
        skip_b, bn_g, bn_b, S);

    dim3 gg(BCD / 128, NPAD / 128);
    gemm_tn<<<gg, 256, 0, stream>>>(adp, S, x1);   // x1 = skip · adp
    gemm_tn<<<gg, 256, 0, stream>>>(adp, x1, x2);  // x2 = x1 · adp

    head_kernel<<<512, 256, 0, stream>>>(S, x1, x2, wgcnT, gcn_b, c01, w1tT,
                                         h0_w2, h0_b2, h1_w2, h1_b2,
                                         Ct, Yf, outp, part);
    finalize_kernel<<<1, 128, 0, stream>>>(part, task, outp);
}

// Round 6
// 2208.536 us; speedup vs baseline: 21.1753x; 1.3221x over previous
//
#include <hip/hip_runtime.h>
#include <cstdint>

// ---------------- problem constants ----------------
#define NB 64        // batch
#define TT 8         // timesteps
#define NN 2000      // nodes
#define NF 16        // in features
#define NCH 64       // channels
#define NPAD 2048    // padded node dim
#define BCD 4096     // NB*NCH
#define ITEMS 128000 // NB*NN

// ws offsets (floats)
#define OFF_ADPT  0                         // adpT bf16 [2048][2048] = 2097152 floats
#define OFF_S     2097152                   // S fp32 [2048][4096] = 8388608
#define OFF_ST    (OFF_S + 8388608)         // St bf16 [4096][2048] = 4194304 floats
#define OFF_X1T   (OFF_ST + 4194304)        // x1t bf16 [4096][2048] = 4194304 floats
#define OFF_X2    (OFF_X1T + 4194304)       // x2 fp32 [2048][4096] = 8388608
#define OFF_C01   (OFF_X2 + 8388608)        // 128
#define OFF_WGCNT (OFF_C01 + 128)           // 12288
#define OFF_W1TT  (OFF_WGCNT + 12288)       // 8192
#define OFF_PART  (OFF_W1TT + 8192)         // 270336
#define OFF_PW    (OFF_PART + 270336)       // 49152 packed conv weights (float4)
#define OFF_SK2   (OFF_PW + 49152)          // 12288 packed skip weights (float2)

// chunk-XOR swizzle on the k dimension (8-bf16 chunks within 64-k tiles)
#define SWZK(k, x) (((k) & ~63) | (((((k) >> 3) & 7) ^ ((x) & 7)) << 3) | ((k) & 7))

typedef __attribute__((ext_vector_type(8))) short short8;
typedef __attribute__((ext_vector_type(4))) float f32x4;
typedef const __attribute__((address_space(1))) uint32_t* gas_t;
typedef __attribute__((address_space(3))) uint32_t* las_t;

__device__ __forceinline__ float fast_rcp(float x) { return __builtin_amdgcn_rcpf(x); }
__device__ __forceinline__ float fast_tanh(float x) {
    x = fminf(fmaxf(x, -10.f), 10.f);
    float e = __expf(2.f * x);
    return (e - 1.f) * fast_rcp(e + 1.f);
}
__device__ __forceinline__ float fast_sigmoid(float x) {
    return fast_rcp(1.f + __expf(-x));
}
__device__ __forceinline__ unsigned short f2bf(float f) {
    uint32_t u = __float_as_uint(f);
    u += 0x7fff + ((u >> 16) & 1);       // RNE
    return (unsigned short)(u >> 16);
}
__device__ __forceinline__ float bf2f(unsigned short b) {
    return __uint_as_float(((uint32_t)b) << 16);
}

// ---------------- K0: tiny precompute (transposes + packing + task-dot) ----------------
__global__ void prep_kernel(const float* __restrict__ gcn_w,
                            const float* __restrict__ h0_w1, const float* __restrict__ h0_b1,
                            const float* __restrict__ h1_w1, const float* __restrict__ h1_b1,
                            const float* __restrict__ task_emb,
                            const float* __restrict__ filt_w, const float* __restrict__ gate_w,
                            const float* __restrict__ skip_w,
                            float* __restrict__ c01, float* __restrict__ wgcnT,
                            float* __restrict__ w1tT, float* __restrict__ pw,
                            float* __restrict__ sk2)
{
    int tid = threadIdx.x;
    for (int idx = tid; idx < 64 * 192; idx += 256) {
        int o = idx / 192, j = idx % 192;
        wgcnT[j * 64 + o] = gcn_w[idx];
    }
    for (int idx = tid; idx < 4096; idx += 256) {
        int o = idx >> 6, c = idx & 63;
        w1tT[c * 64 + o]        = h0_w1[o * 128 + 64 + c];
        w1tT[4096 + c * 64 + o] = h1_w1[o * 128 + 64 + c];
    }
    // pw4[L][c*64+o] = {f[o][c][0], f[o][c][1], g[o][c][0], g[o][c][1]}
    for (int idx = tid; idx < 3 * 4096; idx += 256) {
        int L = idx >> 12, rem = idx & 4095;
        int c = rem >> 6, o = rem & 63;
        float f0 = filt_w[L * 8192 + o * 128 + c * 2];
        float f1 = filt_w[L * 8192 + o * 128 + c * 2 + 1];
        float g0 = gate_w[L * 8192 + o * 128 + c * 2];
        float g1 = gate_w[L * 8192 + o * 128 + c * 2 + 1];
        ((float4*)pw)[idx] = make_float4(f0, f1, g0, g1);
    }
    // sk2[L][cp*64+o] = {skip_w[L][o][2cp], skip_w[L][o][2cp+1]}
    for (int idx = tid; idx < 3 * 2048; idx += 256) {
        int L = idx / 2048, rem = idx % 2048;
        int cp = rem >> 6, o = rem & 63;
        ((float2*)sk2)[idx] = make_float2(skip_w[L * 4096 + o * 64 + 2 * cp],
                                          skip_w[L * 4096 + o * 64 + 2 * cp + 1]);
    }
    if (tid < 128) {
        int head = tid >> 6, o = tid & 63;
        const float* w1 = head ? h1_w1 : h0_w1;
        const float* b1 = head ? h1_b1 : h0_b1;
        float a = b1[o];
        for (int k = 0; k < 64; ++k) a = fmaf(w1[o * 128 + k], task_emb[k], a);
        c01[tid] = a;
    }
}

// ---------------- K1: adpT = softmax(relu(nv1@nv2),axis=1)^T, bf16, k-swizzled ----------------
__global__ __launch_bounds__(256) void adp_kernel(const float* __restrict__ nv1,
                                                  const float* __restrict__ nv2,
                                                  unsigned short* __restrict__ adpT)
{
    __shared__ float nv1s[10];
    __shared__ float rbuf[4];
    int tid = threadIdx.x;
    int r = blockIdx.x;     // source row v = r; destination column k = r
    if (tid < 10) nv1s[tid] = nv1[r * 10 + tid];
    __syncthreads();

    float val[8];
    float vmax = -3.4e38f;
    #pragma unroll
    for (int s = 0; s < 8; ++s) {
        int j = tid + s * 256;
        if (j < NN) {
            float v = 0.f;
            #pragma unroll
            for (int k = 0; k < 10; ++k) v = fmaf(nv1s[k], nv2[k * NN + j], v);
            v = fmaxf(v, 0.f);
            val[s] = v;
            vmax = fmaxf(vmax, v);
        } else val[s] = -3.4e38f;
    }
    for (int off = 32; off; off >>= 1) vmax = fmaxf(vmax, __shfl_down(vmax, off, 64));
    if ((tid & 63) == 0) rbuf[tid >> 6] = vmax;
    __syncthreads();
    vmax = fmaxf(fmaxf(rbuf[0], rbuf[1]), fmaxf(rbuf[2], rbuf[3]));
    __syncthreads();
    float sum = 0.f;
    #pragma unroll
    for (int s = 0; s < 8; ++s) {
        int j = tid + s * 256;
        if (j < NN) { val[s] = expf(val[s] - vmax); sum += val[s]; }
    }
    for (int off = 32; off; off >>= 1) sum += __shfl_down(sum, off, 64);
    if ((tid & 63) == 0) rbuf[tid >> 6] = sum;
    __syncthreads();
    sum = rbuf[0] + rbuf[1] + rbuf[2] + rbuf[3];
    float inv = 1.f / sum;
    #pragma unroll
    for (int s = 0; s < 8; ++s) {
        int j = tid + s * 256;
        if (j < NN)
            adpT[(size_t)j * NPAD + SWZK(r, j)] = f2bf(val[s] * inv);
    }
}

// ---------------- K2: fused temporal stack (v6: b64 LDS reads) ----------------
#define TK_GI 2

template<int LAYER, int D, int WIN, int WOUT>
__device__ __forceinline__ void do_layer(
    float* __restrict__ xstate, float* __restrict__ gbuf,
    float* __restrict__ pwlds, float* __restrict__ slds,
    const float* __restrict__ pw, const float* __restrict__ sk2,
    const float* __restrict__ filt_b, const float* __restrict__ gate_b,
    const float* __restrict__ skip_b,
    const float* __restrict__ bn_g, const float* __restrict__ bn_b,
    float* __restrict__ sacc)
{
    int tid = threadIdx.x;
    int wave = tid >> 6, o = tid & 63;
    for (int idx = tid; idx < 4096; idx += 1024)
        ((float4*)pwlds)[idx] = ((const float4*)pw)[LAYER * 4096 + idx];
    for (int idx = tid; idx < 2048; idx += 1024)
        ((float2*)slds)[idx] = ((const float2*)sk2)[LAYER * 2048 + idx];
    __syncthreads();

    float fb = filt_b[LAYER * 64 + o], gb = gate_b[LAYER * 64 + o];
    float skb = skip_b[LAYER * 64 + o];
    float bscale = bn_g[LAYER * 64 + o] * rsqrtf(1.0f + 1e-5f);
    float bshift = bn_b[LAYER * 64 + o];
    const float4* pw4 = (const float4*)pwlds;
    const float2* sl2 = (const float2*)slds;

    #pragma unroll
    for (int gi = 0; gi < TK_GI; ++gi) {
        int g = wave * TK_GI + gi;
        const float2* xs2 = (const float2*)&xstate[g * 512];   // [t][c/2]
        float facc[WOUT], gacc[WOUT];
        #pragma unroll
        for (int t = 0; t < WOUT; ++t) { facc[t] = fb; gacc[t] = gb; }

        #pragma unroll 2
        for (int cp = 0; cp < 32; ++cp) {
            float2 xv[WIN];
            #pragma unroll
            for (int t = 0; t < WIN; ++t) xv[t] = xs2[t * 32 + cp];  // b64 broadcast
            float4 wA = pw4[(2 * cp) * 64 + o];
            float4 wB = pw4[(2 * cp + 1) * 64 + o];
            #pragma unroll
            for (int t = 0; t < WOUT; ++t) {
                facc[t] = fmaf(wA.x, xv[t].x, fmaf(wA.y, xv[t + D].x, facc[t]));
                gacc[t] = fmaf(wA.z, xv[t].x, fmaf(wA.w, xv[t + D].x, gacc[t]));
                facc[t] = fmaf(wB.x, xv[t].y, fmaf(wB.y, xv[t + D].y, facc[t]));
                gacc[t] = fmaf(wB.z, xv[t].y, fmaf(wB.w, xv[t + D].y, gacc[t]));
            }
        }
        float gated[WOUT];
        #pragma unroll
        for (int t = 0; t < WOUT; ++t)
            gated[t] = fast_tanh(facc[t]) * fast_sigmoid(gacc[t]);

        gbuf[g * 64 + o] = gated[WOUT - 1];
        asm volatile("" ::: "memory");
        float s = skb;
        const float2* gb2 = (const float2*)&gbuf[g * 64];
        #pragma unroll 8
        for (int cp = 0; cp < 32; ++cp) {
            float2 gq = gb2[cp];                 // b64 broadcast
            float2 sw = sl2[cp * 64 + o];        // b64 lane-stride
            s = fmaf(sw.x, gq.x, fmaf(sw.y, gq.y, s));
        }
        sacc[gi] += s;

        float xo[WOUT];
        #pragma unroll
        for (int t = 0; t < WOUT; ++t) xo[t] = xstate[g * 512 + (t + D) * 64 + o];
        #pragma unroll
        for (int t = 0; t < WOUT; ++t)
            xstate[g * 512 + t * 64 + o] = fmaf(gated[t] + xo[t], bscale, bshift);
        asm volatile("" ::: "memory");
    }
    __syncthreads();
}

__global__ __launch_bounds__(1024) void temporal_kernel(
    const float* __restrict__ X,
    const float* __restrict__ start_w, const float* __restrict__ start_b,
    const float* __restrict__ pw, const float* __restrict__ sk2,
    const float* __restrict__ filt_b, const float* __restrict__ gate_b,
    const float* __restrict__ skip_b,
    const float* __restrict__ bn_g, const float* __restrict__ bn_b,
    float* __restrict__ S, unsigned short* __restrict__ St)
{
    extern __shared__ float smem[];
    float* xstate = smem;           // 16384 floats [32][8][64]
    float* gbuf   = smem + 16384;   // 2048
    float* pwlds  = smem + 18432;   // 16384
    float* slds   = smem + 34816;   // 4096
    float* xstage = pwlds;

    int tid = threadIdx.x;
    int wave = tid >> 6, o = tid & 63;
    int item0 = blockIdx.x * 32;

    for (int idx = tid; idx < 32 * 128; idx += 1024) {
        int g = idx >> 7, rem = idx & 127;
        int ig = item0 + g;
        int b = ig / NN, n = ig - b * NN;
        int t = rem >> 4, f = rem & 15;
        xstage[idx] = X[((b * TT + t) * NN + n) * NF + f];
    }
    __syncthreads();

    {
        float sb = start_b[o];
        #pragma unroll
        for (int gi = 0; gi < TK_GI; ++gi) {
            int g = wave * TK_GI + gi;
            const float* xr = &xstage[g * 128];
            #pragma unroll
            for (int t = 0; t < 8; ++t) {
                float acc = sb;
                #pragma unroll
                for (int f = 0; f < 16; ++f)
                    acc = fmaf(start_w[o * 16 + f], xr[t * 16 + f], acc);
                xstate[g * 512 + t * 64 + o] = acc;
            }
        }
    }
    __syncthreads();

    float sacc[TK_GI] = {0, 0};
    do_layer<0, 1, 8, 7>(xstate, gbuf, pwlds, slds, pw, sk2, filt_b, gate_b,
                         skip_b, bn_g, bn_b, sacc);
    do_layer<1, 2, 7, 5>(xstate, gbuf, pwlds, slds, pw, sk2, filt_b, gate_b,
                         skip_b, bn_g, bn_b, sacc);
    do_layer<2, 4, 5, 1>(xstate, gbuf, pwlds, slds, pw, sk2, filt_b, gate_b,
                         skip_b, bn_g, bn_b, sacc);

    // write skip_final: S fp32 [n][bc] (head) + St bf16 [bc][n-swz] (GEMM1 B operand)
    #pragma unroll
    for (int gi = 0; gi < TK_GI; ++gi) {
        int ig = item0 + wave * TK_GI + gi;
        int b = ig / NN, n = ig - b * NN;
        int bc = b * 64 + o;
        S[(size_t)n * BCD + bc] = sacc[gi];
        St[(size_t)bc * NPAD + SWZK(n, o)] = f2bf(sacc[gi]);
    }
}

// ---------------- K3: bf16 MFMA GEMM, C[m][n] = sum_k A[m][k]*B[n][k] ----------------
// A: [NPAD][NPAD] bf16 k-swizzled; B: [BCD][NPAD] bf16 k-swizzled.
// Cf (fp32 [m][n]) and/or Ct (bf16 [n][m-swz]) outputs.
__global__ __launch_bounds__(256) void gemm_mfma(
    const unsigned short* __restrict__ A, const unsigned short* __restrict__ B,
    float* __restrict__ Cf, unsigned short* __restrict__ Ct)
{
    __shared__ unsigned short As[128 * 64];
    __shared__ unsigned short Bs[128 * 64];
    int tid = threadIdx.x;
    int wave = tid >> 6, lane = tid & 63;
    int lk = lane >> 4, lr = lane & 15;
    int n0 = blockIdx.x * 128, m0 = blockIdx.y * 128;
    int wm = wave >> 1, wn = wave & 1;

    f32x4 acc[4][4];
    #pragma unroll
    for (int i = 0; i < 4; ++i)
        #pragma unroll
        for (int j = 0; j < 4; ++j)
            acc[i][j] = (f32x4){0.f, 0.f, 0.f, 0.f};

    for (int k0 = 0; k0 < NPAD; k0 += 64) {
        // stage 16KB per tile via direct global->LDS DMA (linear dest, pre-swz src)
        #pragma unroll
        for (int i = 0; i < 4; ++i) {
            int chunk = wave * 4 + i;             // 0..15, 8 rows each
            int row = chunk * 8 + (lane >> 3);
            int koff = (lane & 7) * 8;            // ushort units
            __builtin_amdgcn_global_load_lds(
                (gas_t)(A + (size_t)(m0 + row) * NPAD + k0 + koff),
                (las_t)(&As[chunk * 512]), 16, 0, 0);
            __builtin_amdgcn_global_load_lds(
                (gas_t)(B + (size_t)(n0 + row) * NPAD + k0 + koff),
                (las_t)(&Bs[chunk * 512]), 16, 0, 0);
        }
        __syncthreads();
        #pragma unroll
        for (int s = 0; s < 2; ++s) {
            short8 av[4], bv[4];
            #pragma unroll
            for (int f = 0; f < 4; ++f) {
                int m = wm * 64 + f * 16 + lr;
                int ca = ((s * 4 + lk) ^ (m & 7));
                av[f] = *(const short8*)&As[m * 64 + ca * 8];
                int n = wn * 64 + f * 16 + lr;
                int cb = ((s * 4 + lk) ^ (n & 7));
                bv[f] = *(const short8*)&Bs[n * 64 + cb * 8];
            }
            #pragma unroll
            for (int fi = 0; fi < 4; ++fi)
                #pragma unroll
                for (int fj = 0; fj < 4; ++fj)
                    acc[fi][fj] = __builtin_amdgcn_mfma_f32_16x16x32_bf16(
                        av[fi], bv[fj], acc[fi][fj], 0, 0, 0);
        }
        __syncthreads();
    }

    #pragma unroll
    for (int fi = 0; fi < 4; ++fi) {
        #pragma unroll
        for (int fj = 0; fj < 4; ++fj) {
            int m = m0 + wm * 64 + fi * 16 + lk * 4;
            int n = n0 + wn * 64 + fj * 16 + lr;
            f32x4 v = acc[fi][fj];
            if (Cf) {
                Cf[(size_t)(m + 0) * BCD + n] = v[0];
                Cf[(size_t)(m + 1) * BCD + n] = v[1];
                Cf[(size_t)(m + 2) * BCD + n] = v[2];
                Cf[(size_t)(m + 3) * BCD + n] = v[3];
            }
            if (Ct) {
                ushort4 p;
                p.x = f2bf(v[0]); p.y = f2bf(v[1]);
                p.z = f2bf(v[2]); p.w = f2bf(v[3]);
                *(ushort4*)&Ct[(size_t)n * NPAD + SWZK(m, n)] = p;
            }
        }
    }
}

// ---------------- K4: gcn 1x1 + heads + outputs + partial reductions ----------------
__global__ __launch_bounds__(256) void head_kernel(
    const float* __restrict__ S, const unsigned short* __restrict__ x1t,
    const float* __restrict__ x2,
    const float* __restrict__ wgcnT, const float* __restrict__ gcn_b,
    const float* __restrict__ c01, const float* __restrict__ w1tT,
    const float* __restrict__ h0_w2, const float* __restrict__ h0_b2,
    const float* __restrict__ h1_w2, const float* __restrict__ h1_b2,
    const int* __restrict__ Ct, const float* __restrict__ Yf,
    float* __restrict__ out, float* __restrict__ partials)
{
    __shared__ float hl[4][4][192];
    __shared__ float gxl[4][4][64];
    int tid = threadIdx.x;
    int wave = tid >> 6, o = tid & 63;
    int wid = blockIdx.x * 4 + wave;
    float w2a = h0_w2[o], w2b = h1_w2[o];
    float b20 = h0_b2[0], b21 = h1_b2[0];
    float cb = gcn_b[o], c0a = c01[o], c0b = c01[64 + o];

    float accT = 0.f, accC = 0.f, bce = 0.f, cT = 0.f, cC = 0.f;

    for (int base = wid * 4; base < ITEMS; base += 2048 * 4) {
        #pragma unroll
        for (int it = 0; it < 4; ++it) {
            int item = base + it;
            int b = item / NN, n = item - b * NN;
            int bc = b * 64 + o;
            hl[wave][it][o]       = S[(size_t)n * BCD + bc];
            hl[wave][it][64 + o]  = bf2f(x1t[(size_t)bc * NPAD + SWZK(n, o)]);
            hl[wave][it][128 + o] = x2[(size_t)n * BCD + bc];
        }
        float a0 = cb, a1 = cb, a2 = cb, a3 = cb;
        for (int j = 0; j < 192; ++j) {
            float w = wgcnT[j * 64 + o];
            a0 = fmaf(w, hl[wave][0][j], a0);
            a1 = fmaf(w, hl[wave][1][j], a1);
            a2 = fmaf(w, hl[wave][2][j], a2);
            a3 = fmaf(w, hl[wave][3][j], a3);
        }
        float gxv[4] = {fmaxf(a0, 0.f), fmaxf(a1, 0.f), fmaxf(a2, 0.f), fmaxf(a3, 0.f)};
        #pragma unroll
        for (int it = 0; it < 4; ++it) gxl[wave][it][o] = gxv[it];

        float p0[4], p1[4];
        #pragma unroll
        for (int it = 0; it < 4; ++it) { p0[it] = c0a; p1[it] = c0b; }
        for (int c = 0; c < 64; ++c) {
            float w0 = w1tT[c * 64 + o];
            float w1 = w1tT[4096 + c * 64 + o];
            float g0 = gxl[wave][0][c], g1 = gxl[wave][1][c];
            float g2 = gxl[wave][2][c], g3 = gxl[wave][3][c];
            p0[0] = fmaf(w0, g0, p0[0]); p0[1] = fmaf(w0, g1, p0[1]);
            p0[2] = fmaf(w0, g2, p0[2]); p0[3] = fmaf(w0, g3, p0[3]);
            p1[0] = fmaf(w1, g0, p1[0]); p1[1] = fmaf(w1, g1, p1[1]);
            p1[2] = fmaf(w1, g2, p1[2]); p1[3] = fmaf(w1, g3, p1[3]);
        }
        #pragma unroll
        for (int it = 0; it < 4; ++it) {
            float r0 = w2a * fmaxf(p0[it], 0.f);
            float r1 = w2b * fmaxf(p1[it], 0.f);
            #pragma unroll
            for (int off = 32; off; off >>= 1) {
                r0 += __shfl_down(r0, off, 64);
                r1 += __shfl_down(r1, off, 64);
            }
            int item = base + it;
            int tt = Ct[item];
            if (o == 0) {
                float y0 = 1.f / (1.f + expf(-(r0 + b20)));
                float y1 = 1.f / (1.f + expf(-(r1 + b21)));
                float y = (tt > 0) ? y1 : y0;
                out[1 + item] = y;
                out[1 + ITEMS + item] = y0;
                out[1 + 2 * ITEMS + item] = y1;
                float yc = fminf(fmaxf(y, 1e-7f), 1.f - 1e-7f);
                float Yv = Yf[item];
                bce -= Yv * logf(yc) + (1.f - Yv) * logf(1.f - yc);
                if (tt > 0) cT += 1.f; else cC += 1.f;
            }
            if (tt > 0) accT += gxv[it]; else accC += gxv[it];
        }
    }
    partials[wid * 132 + o] = accT;
    partials[wid * 132 + 64 + o] = accC;
    if (o == 0) {
        partials[wid * 132 + 128] = bce;
        partials[wid * 132 + 129] = cT;
        partials[wid * 132 + 130] = cC;
    }
}

// ---------------- K5: final loss ----------------
__global__ void finalize_kernel(const float* __restrict__ partials,
                                const float* __restrict__ task_emb,
                                float* __restrict__ out)
{
    __shared__ float red[131];
    int tid = threadIdx.x; // 128
    for (int slot = tid; slot < 131; slot += 128) {
        float s = 0.f;
        for (int w = 0; w < 2048; ++w) s += partials[w * 132 + slot];
        red[slot] = s;
    }
    __syncthreads();
    if (tid < 64) {
        float cT = red[129], cC = red[130];
        float iT = 1.f / fmaxf(cT, 1.f), iC = 1.f / fmaxf(cC, 1.f);
        float d1 = task_emb[tid] * (cT * iT) - task_emb[tid] * (cC * iC);
        float d2 = red[tid] * iT - red[64 + tid] * iC;
        float p = d1 * d1 + d2 * d2;
        #pragma unroll
        for (int off = 32; off; off >>= 1) p += __shfl_down(p, off, 64);
        if (tid == 0) out[0] = red[128] * (1.f / (float)ITEMS) + p;
    }
}

// ---------------- launch ----------------
extern "C" void kernel_launch(void* const* d_in, const int* in_sizes, int n_in,
                              void* d_out, int out_size, void* d_ws, size_t ws_size,
                              hipStream_t stream)
{
    const float* X       = (const float*)d_in[0];
    const int*   Ct      = (const int*)d_in[2];
    const float* Yf      = (const float*)d_in[3];
    const float* start_w = (const float*)d_in[5];
    const float* start_b = (const float*)d_in[6];
    const float* filt_w  = (const float*)d_in[7];
    const float* filt_b  = (const float*)d_in[8];
    const float* gate_w  = (const float*)d_in[9];
    const float* gate_b  = (const float*)d_in[10];
    const float* skip_w  = (const float*)d_in[11];
    const float* skip_b  = (const float*)d_in[12];
    const float* bn_g    = (const float*)d_in[13];
    const float* bn_b    = (const float*)d_in[14];
    const float* nv1     = (const float*)d_in[15];
    const float* nv2     = (const float*)d_in[16];
    const float* task    = (const float*)d_in[17];
    const float* gcn_w   = (const float*)d_in[18];
    const float* gcn_b   = (const float*)d_in[19];
    const float* h0_w1   = (const float*)d_in[20];
    const float* h0_b1   = (const float*)d_in[21];
    const float* h0_w2   = (const float*)d_in[22];
    const float* h0_b2   = (const float*)d_in[23];
    const float* h1_w1   = (const float*)d_in[24];
    const float* h1_b1   = (const float*)d_in[25];
    const float* h1_w2   = (const float*)d_in[26];
    const float* h1_b2   = (const float*)d_in[27];

    float* ws    = (float*)d_ws;
    unsigned short* adpT = (unsigned short*)(ws + OFF_ADPT);
    float* S     = ws + OFF_S;
    unsigned short* St   = (unsigned short*)(ws + OFF_ST);
    unsigned short* x1t  = (unsigned short*)(ws + OFF_X1T);
    float* x2    = ws + OFF_X2;
    float* c01   = ws + OFF_C01;
    float* wgcnT = ws + OFF_WGCNT;
    float* w1tT  = ws + OFF_W1TT;
    float* part  = ws + OFF_PART;
    float* pw    = ws + OFF_PW;
    float* sk2   = ws + OFF_SK2;
    float* outp  = (float*)d_out;

    // zero bf16 operand buffers so padded rows/cols contribute exactly 0
    hipMemsetAsync(adpT, 0, (size_t)NPAD * NPAD * sizeof(unsigned short), stream);
    hipMemsetAsync(St,   0, (size_t)BCD * NPAD * sizeof(unsigned short), stream);

    prep_kernel<<<1, 256, 0, stream>>>(gcn_w, h0_w1, h0_b1, h1_w1, h1_b1, task,
                                       filt_w, gate_w, skip_w,
                                       c01, wgcnT, w1tT, pw, sk2);
    adp_kernel<<<NN, 256, 0, stream>>>(nv1, nv2, adpT);

    const int K2_LDS = 38912 * 4; // 152 KiB dynamic LDS
    hipFuncSetAttribute(reinterpret_cast<const void*>(temporal_kernel),
                        hipFuncAttributeMaxDynamicSharedMemorySize, K2_LDS);
    temporal_kernel<<<ITEMS / 32, 1024, K2_LDS, stream>>>(
        X, start_w, start_b, pw, sk2, filt_b, gate_b,
        skip_b, bn_g, bn_b, S, St);

    dim3 gg(BCD / 128, NPAD / 128);
    gemm_mfma<<<gg, 256, 0, stream>>>(adpT, St, nullptr, x1t);  // x1t = (adp^T·S)^T
    gemm_mfma<<<gg, 256, 0, stream>>>(adpT, x1t, x2, nullptr);  // x2  = adp^T·x1

    head_kernel<<<512, 256, 0, stream>>>(S, x1t, x2, wgcnT, gcn_b, c01, w1tT,
                                         h0_w2, h0_b2, h1_w2, h1_b2,
                                         Ct, Yf, outp, part);
    finalize_kernel<<<1, 128, 0, stream>>>(part, task, outp);
}

// Round 7
// 750.172 us; speedup vs baseline: 62.3409x; 2.9440x over previous
//
#include <hip/hip_runtime.h>
#include <cstdint>

// ---------------- problem constants ----------------
#define NB 64        // batch
#define TT 8         // timesteps
#define NN 2000      // nodes
#define NF 16        // in features
#define NCH 64       // channels
#define NPAD 2048    // padded node dim
#define BCD 4096     // NB*NCH
#define ITEMS 128000 // NB*NN

// ws offsets (floats)
#define OFF_ADPT  0                         // adpT bf16 [2048][2048]
#define OFF_S     2097152                   // S fp32 [2048][4096]
#define OFF_ST    (OFF_S + 8388608)         // St bf16 [4096][2048]
#define OFF_X1T   (OFF_ST + 4194304)        // x1t bf16 [4096][2048]
#define OFF_X2    (OFF_X1T + 4194304)       // x2 fp32 [2048][4096]
#define OFF_C01   (OFF_X2 + 8388608)        // 128
#define OFF_WGCNT (OFF_C01 + 128)           // 12288
#define OFF_W1TT  (OFF_WGCNT + 12288)       // 8192
#define OFF_PART  (OFF_W1TT + 8192)         // 270336
#define OFF_WAW   (OFF_PART + 270336)       // [3][128][128] bf16 pre-swz = 24576 floats
#define OFF_SWW   (OFF_WAW + 24576)         // [3][64][64] bf16 pre-swz = 6144
#define OFF_WSTW  (OFF_SWW + 6144)          // [64][128] bf16 pre-swz (K=32 + zero) = 4096

// chunk-XOR swizzle on the k dimension (8-bf16 chunks within 64-k tiles) for GEMM ops
#define SWZK(k, x) (((k) & ~63) | (((((k) >> 3) & 7) ^ ((x) & 7)) << 3) | ((k) & 7))
// gbuf row swizzle (8 chunks/row): mixes g and t bits so skip-reads don't collide
#define GSWZ(n) ((((n) >> 3) ^ (n)) & 7)

typedef __attribute__((ext_vector_type(8))) short short8;
typedef __attribute__((ext_vector_type(4))) float f32x4;
typedef const __attribute__((address_space(1))) uint32_t* gas_t;
typedef __attribute__((address_space(3))) uint32_t* las_t;

__device__ __forceinline__ float fast_rcp(float x) { return __builtin_amdgcn_rcpf(x); }
__device__ __forceinline__ float fast_tanh(float x) {
    x = fminf(fmaxf(x, -10.f), 10.f);
    float e = __expf(2.f * x);
    return (e - 1.f) * fast_rcp(e + 1.f);
}
__device__ __forceinline__ float fast_sigmoid(float x) {
    return fast_rcp(1.f + __expf(-x));
}
__device__ __forceinline__ unsigned short f2bf(float f) {
    uint32_t u = __float_as_uint(f);
    u += 0x7fff + ((u >> 16) & 1);       // RNE
    return (unsigned short)(u >> 16);
}
__device__ __forceinline__ float bf2f(unsigned short b) {
    return __uint_as_float(((uint32_t)b) << 16);
}

// ---------------- K0: precompute (transposes + swizzled bf16 weights + task-dot) ----------------
__global__ void prep_kernel(const float* __restrict__ gcn_w,
                            const float* __restrict__ h0_w1, const float* __restrict__ h0_b1,
                            const float* __restrict__ h1_w1, const float* __restrict__ h1_b1,
                            const float* __restrict__ task_emb,
                            const float* __restrict__ filt_w, const float* __restrict__ gate_w,
                            const float* __restrict__ skip_w, const float* __restrict__ start_w,
                            float* __restrict__ c01, float* __restrict__ wgcnT,
                            float* __restrict__ w1tT,
                            unsigned short* __restrict__ waw,
                            unsigned short* __restrict__ sww,
                            unsigned short* __restrict__ wstw)
{
    int tid = threadIdx.x;
    for (int idx = tid; idx < 64 * 192; idx += 256) {
        int o = idx / 192, j = idx % 192;
        wgcnT[j * 64 + o] = gcn_w[idx];
    }
    for (int idx = tid; idx < 4096; idx += 256) {
        int o = idx >> 6, c = idx & 63;
        w1tT[c * 64 + o]        = h0_w1[o * 128 + 64 + c];
        w1tT[4096 + c * 64 + o] = h1_w1[o * 128 + 64 + c];
    }
    // WA[L][r][k]: r<64 = filt ch r, r>=64 = gate ch r-64; k = tap*64 + c. Chunk-swizzled.
    for (int job = tid; job < 3 * 128 * 16; job += 256) {
        int L = job / 2048, rem = job % 2048;
        int r = rem >> 4, chp = rem & 15;
        int cho = chp ^ (r & 15);
        #pragma unroll
        for (int i = 0; i < 8; ++i) {
            int k = cho * 8 + i, tap = k >> 6, c = k & 63;
            float v = (r < 64) ? filt_w[L * 8192 + r * 128 + c * 2 + tap]
                               : gate_w[L * 8192 + (r - 64) * 128 + c * 2 + tap];
            waw[((L * 128 + r) * 16 + chp) * 8 + i] = f2bf(v);
        }
    }
    // SW[L][o][c] chunk-swizzled (8 chunks/row)
    for (int job = tid; job < 3 * 64 * 8; job += 256) {
        int L = job / 512, rem = job % 512;
        int o = rem >> 3, chp = rem & 7;
        int cho = chp ^ (o & 7);
        #pragma unroll
        for (int i = 0; i < 8; ++i)
            sww[((L * 64 + o) * 8 + chp) * 8 + i] = f2bf(skip_w[L * 4096 + o * 64 + cho * 8 + i]);
    }
    // Wstart[o][k] K=32 (k<16 data, else 0), 16 chunks/row swizzled
    for (int job = tid; job < 64 * 16; job += 256) {
        int o = job >> 4, chp = job & 15;
        int cho = chp ^ (o & 15);
        #pragma unroll
        for (int i = 0; i < 8; ++i) {
            int k = cho * 8 + i;
            wstw[(o * 16 + chp) * 8 + i] = (k < 16) ? f2bf(start_w[o * 16 + k]) : (unsigned short)0;
        }
    }
    if (tid < 128) {
        int head = tid >> 6, o = tid & 63;
        const float* w1 = head ? h1_w1 : h0_w1;
        const float* b1 = head ? h1_b1 : h0_b1;
        float a = b1[o];
        for (int k = 0; k < 64; ++k) a = fmaf(w1[o * 128 + k], task_emb[k], a);
        c01[tid] = a;
    }
}

// ---------------- K1: adpT = softmax(relu(nv1@nv2),axis=1)^T, bf16, k-swizzled ----------------
__global__ __launch_bounds__(256) void adp_kernel(const float* __restrict__ nv1,
                                                  const float* __restrict__ nv2,
                                                  unsigned short* __restrict__ adpT)
{
    __shared__ float nv1s[10];
    __shared__ float rbuf[4];
    int tid = threadIdx.x;
    int r = blockIdx.x;
    if (tid < 10) nv1s[tid] = nv1[r * 10 + tid];
    __syncthreads();

    float val[8];
    float vmax = -3.4e38f;
    #pragma unroll
    for (int s = 0; s < 8; ++s) {
        int j = tid + s * 256;
        if (j < NN) {
            float v = 0.f;
            #pragma unroll
            for (int k = 0; k < 10; ++k) v = fmaf(nv1s[k], nv2[k * NN + j], v);
            v = fmaxf(v, 0.f);
            val[s] = v;
            vmax = fmaxf(vmax, v);
        } else val[s] = -3.4e38f;
    }
    for (int off = 32; off; off >>= 1) vmax = fmaxf(vmax, __shfl_down(vmax, off, 64));
    if ((tid & 63) == 0) rbuf[tid >> 6] = vmax;
    __syncthreads();
    vmax = fmaxf(fmaxf(rbuf[0], rbuf[1]), fmaxf(rbuf[2], rbuf[3]));
    __syncthreads();
    float sum = 0.f;
    #pragma unroll
    for (int s = 0; s < 8; ++s) {
        int j = tid + s * 256;
        if (j < NN) { val[s] = expf(val[s] - vmax); sum += val[s]; }
    }
    for (int off = 32; off; off >>= 1) sum += __shfl_down(sum, off, 64);
    if ((tid & 63) == 0) rbuf[tid >> 6] = sum;
    __syncthreads();
    sum = rbuf[0] + rbuf[1] + rbuf[2] + rbuf[3];
    float inv = 1.f / sum;
    #pragma unroll
    for (int s = 0; s < 8; ++s) {
        int j = tid + s * 256;
        if (j < NN)
            adpT[(size_t)j * NPAD + SWZK(r, j)] = f2bf(val[s] * inv);
    }
}

// ---------------- K2: fused temporal stack (v7: MFMA) ----------------
// 1024 thr = 16 waves; 32 items/block. LDS:
//   xb  : B-operand bf16, 256 rows (n=g*8+t) x 128 k (tap,c), 16 chunks swz ^(n&15)  [64KB]
//   gbuf: gated bf16, 256 rows x 64 ch, 8 chunks swz ^GSWZ(n)                         [32KB]
//   WA  : A-operand bf16 128x128 (per-layer restaged, pre-swz in ws)                  [32KB]
//   SW  : skip A-operand bf16 [3][64][64]                                             [24KB]
//   biasAll f32 [3][128]                                                              [1.5KB]
// Residual/BN state in f32 registers xreg[2][8]; skip acc in waves 0,1 (MFMA).

__device__ __forceinline__ void mfma_phaseB(int L,
    const unsigned short* __restrict__ xb, unsigned short* __restrict__ gbuf,
    const unsigned short* __restrict__ WA, const float* __restrict__ biasAll,
    int wave, int lr, int lk)
{
    int n = wave * 16 + lr;
    f32x4 aF[4], aG[4];
    #pragma unroll
    for (int mt = 0; mt < 4; ++mt) {
        aF[mt] = (f32x4){0.f, 0.f, 0.f, 0.f};
        aG[mt] = (f32x4){0.f, 0.f, 0.f, 0.f};
    }
    #pragma unroll
    for (int ks = 0; ks < 4; ++ks) {
        short8 bv = *(const short8*)&xb[(n * 16 + ((ks * 4 + lk) ^ (n & 15))) * 8];
        #pragma unroll
        for (int mt = 0; mt < 4; ++mt) {
            int r = mt * 16 + lr;
            short8 av = *(const short8*)&WA[(r * 16 + ((ks * 4 + lk) ^ (r & 15))) * 8];
            aF[mt] = __builtin_amdgcn_mfma_f32_16x16x32_bf16(av, bv, aF[mt], 0, 0, 0);
        }
        #pragma unroll
        for (int mt = 0; mt < 4; ++mt) {
            int r = (mt + 4) * 16 + lr;
            short8 av = *(const short8*)&WA[(r * 16 + ((ks * 4 + lk) ^ (r & 15))) * 8];
            aG[mt] = __builtin_amdgcn_mfma_f32_16x16x32_bf16(av, bv, aG[mt], 0, 0, 0);
        }
    }
    int gs = GSWZ(n);
    #pragma unroll
    for (int mt = 0; mt < 4; ++mt) {
        int ob = mt * 16 + lk * 4;
        ushort4 p;
        p.x = f2bf(fast_tanh(aF[mt][0] + biasAll[L * 128 + ob + 0]) * fast_sigmoid(aG[mt][0] + biasAll[L * 128 + 64 + ob + 0]));
        p.y = f2bf(fast_tanh(aF[mt][1] + biasAll[L * 128 + ob + 1]) * fast_sigmoid(aG[mt][1] + biasAll[L * 128 + 64 + ob + 1]));
        p.z = f2bf(fast_tanh(aF[mt][2] + biasAll[L * 128 + ob + 2]) * fast_sigmoid(aG[mt][2] + biasAll[L * 128 + 64 + ob + 2]));
        p.w = f2bf(fast_tanh(aF[mt][3] + biasAll[L * 128 + ob + 3]) * fast_sigmoid(aG[mt][3] + biasAll[L * 128 + 64 + ob + 3]));
        *(ushort4*)&gbuf[((n * 8) + ((mt * 2 + (lk >> 1)) ^ gs)) * 8 + (lk & 1) * 4] = p;
    }
}

template<int L, int D, int WOUT, int DN>
__device__ __forceinline__ void phaseC_conv(unsigned short* __restrict__ xb,
    const unsigned short* __restrict__ gbuf,
    const float* __restrict__ bn_g, const float* __restrict__ bn_b,
    float xreg[2][8], int wave, int o)
{
    float bsc = bn_g[L * 64 + o] * rsqrtf(1.0f + 1e-5f);
    float bsh = bn_b[L * 64 + o];
    #pragma unroll
    for (int gi = 0; gi < 2; ++gi) {
        int g = wave * 2 + gi;
        #pragma unroll
        for (int t = 0; t < WOUT; ++t) {
            int n = g * 8 + t;
            float gv = bf2f(gbuf[(n * 8 + ((o >> 3) ^ GSWZ(n))) * 8 + (o & 7)]);
            float nx = (gv + xreg[gi][t + D]) * bsc + bsh;
            xreg[gi][t] = nx;
            if (DN > 0) {
                unsigned short bfv = f2bf(nx);
                xb[(n * 16 + ((o >> 3) ^ (n & 15))) * 8 + (o & 7)] = bfv;
                if (t >= DN) {
                    int n1 = n - DN;
                    xb[(n1 * 16 + (((o >> 3) + 8) ^ (n1 & 15))) * 8 + (o & 7)] = bfv;
                }
            }
        }
    }
}

__device__ __forceinline__ void phaseC_skip(int L, int LASTT,
    const unsigned short* __restrict__ gbuf, const unsigned short* __restrict__ SW,
    f32x4 skacc[4], int wave, int lr, int lk)
{
    if (wave >= 2) return;
    int g = wave * 16 + lr;
    int n = g * 8 + LASTT;
    int gs = GSWZ(n);
    #pragma unroll
    for (int ks = 0; ks < 2; ++ks) {
        short8 bv = *(const short8*)&gbuf[(n * 8 + ((ks * 4 + lk) ^ gs)) * 8];
        #pragma unroll
        for (int mt = 0; mt < 4; ++mt) {
            int r = mt * 16 + lr;
            short8 av = *(const short8*)&SW[((L * 64 + r) * 8 + ((ks * 4 + lk) ^ (r & 7))) * 8];
            skacc[mt] = __builtin_amdgcn_mfma_f32_16x16x32_bf16(av, bv, skacc[mt], 0, 0, 0);
        }
    }
}

__global__ __launch_bounds__(1024) void temporal_kernel(
    const float* __restrict__ X,
    const float* __restrict__ start_b,
    const unsigned short* __restrict__ waw,
    const unsigned short* __restrict__ sww,
    const unsigned short* __restrict__ wstw,
    const float* __restrict__ filt_b, const float* __restrict__ gate_b,
    const float* __restrict__ skip_b,
    const float* __restrict__ bn_g, const float* __restrict__ bn_b,
    float* __restrict__ S, unsigned short* __restrict__ St)
{
    extern __shared__ float smem[];
    unsigned short* xb   = (unsigned short*)smem;              // 32768 ush
    unsigned short* gbuf = (unsigned short*)(smem + 16384);    // 16384 ush
    unsigned short* WA   = (unsigned short*)(smem + 24576);    // 16384 ush
    unsigned short* SW   = (unsigned short*)(smem + 32768);    // 12288 ush
    float* biasAll       = smem + 38912;                       // 384 f32

    int tid = threadIdx.x;
    int wave = tid >> 6, lane = tid & 63;
    int lr = lane & 15, lk = lane >> 4;
    int o = lane;
    int item0 = blockIdx.x * 32;

    // ---- init staging ----
    __builtin_amdgcn_global_load_lds((gas_t)(wstw + tid * 8), (las_t)(WA + tid * 8), 16, 0, 0);
    for (int idx = tid; idx < 1536; idx += 1024)
        __builtin_amdgcn_global_load_lds((gas_t)(sww + idx * 8), (las_t)(SW + idx * 8), 16, 0, 0);
    if (tid < 384) {
        int L = tid >> 7, oo = tid & 127;
        biasAll[tid] = (oo < 64) ? filt_b[L * 64 + oo] : gate_b[L * 64 + oo - 64];
    }
    {   // X -> xb (rows n=g*8+t, k=f 0..15 in chunks {0,1}^swz, zeros in {2,3}^swz)
        int n = tid >> 2, c = tid & 3;
        int g = n >> 3, t = n & 7;
        int ig = item0 + g, b = ig / NN, nn = ig - b * NN;
        short8 v = {0, 0, 0, 0, 0, 0, 0, 0};
        if (c < 2) {
            const float* src = &X[((size_t)(b * TT + t) * NN + nn) * NF + c * 8];
            float4 f0 = *(const float4*)src;
            float4 f1 = *(const float4*)(src + 4);
            v[0] = (short)f2bf(f0.x); v[1] = (short)f2bf(f0.y);
            v[2] = (short)f2bf(f0.z); v[3] = (short)f2bf(f0.w);
            v[4] = (short)f2bf(f1.x); v[5] = (short)f2bf(f1.y);
            v[6] = (short)f2bf(f1.z); v[7] = (short)f2bf(f1.w);
        }
        *(short8*)&xb[(n * 16 + (c ^ (n & 15))) * 8] = v;
    }
    __syncthreads();

    // ---- start conv MFMA (K=32, M=64) ----
    {
        f32x4 aS[4];
        #pragma unroll
        for (int mt = 0; mt < 4; ++mt) aS[mt] = (f32x4){0.f, 0.f, 0.f, 0.f};
        int n = wave * 16 + lr;
        short8 bv = *(const short8*)&xb[(n * 16 + (lk ^ (n & 15))) * 8];
        #pragma unroll
        for (int mt = 0; mt < 4; ++mt) {
            int r = mt * 16 + lr;
            short8 av = *(const short8*)&WA[(r * 16 + (lk ^ (r & 15))) * 8];
            aS[mt] = __builtin_amdgcn_mfma_f32_16x16x32_bf16(av, bv, aS[mt], 0, 0, 0);
        }
        int gs = GSWZ(n);
        #pragma unroll
        for (int mt = 0; mt < 4; ++mt) {
            ushort4 p;
            p.x = f2bf(aS[mt][0]); p.y = f2bf(aS[mt][1]);
            p.z = f2bf(aS[mt][2]); p.w = f2bf(aS[mt][3]);
            *(ushort4*)&gbuf[((n * 8) + ((mt * 2 + (lk >> 1)) ^ gs)) * 8 + (lk & 1) * 4] = p;
        }
    }
    __syncthreads();

    float xreg[2][8];
    f32x4 skacc[4];
    #pragma unroll
    for (int mt = 0; mt < 4; ++mt) skacc[mt] = (f32x4){0.f, 0.f, 0.f, 0.f};

    // ---- C0: x = start_out + start_b; write taps for layer0 (D=1); stage WA_L0 ----
    {
        __builtin_amdgcn_global_load_lds((gas_t)(waw + (size_t)tid * 8),
                                         (las_t)(WA + tid * 8), 16, 0, 0);
        __builtin_amdgcn_global_load_lds((gas_t)(waw + (size_t)(tid + 1024) * 8),
                                         (las_t)(WA + (tid + 1024) * 8), 16, 0, 0);
        float sb = start_b[o];
        #pragma unroll
        for (int gi = 0; gi < 2; ++gi) {
            int g = wave * 2 + gi;
            #pragma unroll
            for (int t = 0; t < 8; ++t) {
                int n = g * 8 + t;
                float gv = bf2f(gbuf[(n * 8 + ((o >> 3) ^ GSWZ(n))) * 8 + (o & 7)]) + sb;
                xreg[gi][t] = gv;
                unsigned short bfv = f2bf(gv);
                xb[(n * 16 + ((o >> 3) ^ (n & 15))) * 8 + (o & 7)] = bfv;
                if (t >= 1) {
                    int n1 = n - 1;
                    xb[(n1 * 16 + (((o >> 3) + 8) ^ (n1 & 15))) * 8 + (o & 7)] = bfv;
                }
            }
        }
    }
    __syncthreads();

    // ---- layer 0 ----
    mfma_phaseB(0, xb, gbuf, WA, biasAll, wave, lr, lk);
    __syncthreads();
    phaseC_skip(0, 6, gbuf, SW, skacc, wave, lr, lk);
    phaseC_conv<0, 1, 7, 2>(xb, gbuf, bn_g, bn_b, xreg, wave, o);
    __builtin_amdgcn_global_load_lds((gas_t)(waw + (size_t)(2048 + tid) * 8),
                                     (las_t)(WA + tid * 8), 16, 0, 0);
    __builtin_amdgcn_global_load_lds((gas_t)(waw + (size_t)(2048 + tid + 1024) * 8),
                                     (las_t)(WA + (tid + 1024) * 8), 16, 0, 0);
    __syncthreads();

    // ---- layer 1 ----
    mfma_phaseB(1, xb, gbuf, WA, biasAll, wave, lr, lk);
    __syncthreads();
    phaseC_skip(1, 4, gbuf, SW, skacc, wave, lr, lk);
    phaseC_conv<1, 2, 5, 4>(xb, gbuf, bn_g, bn_b, xreg, wave, o);
    __builtin_amdgcn_global_load_lds((gas_t)(waw + (size_t)(4096 + tid) * 8),
                                     (las_t)(WA + tid * 8), 16, 0, 0);
    __builtin_amdgcn_global_load_lds((gas_t)(waw + (size_t)(4096 + tid + 1024) * 8),
                                     (las_t)(WA + (tid + 1024) * 8), 16, 0, 0);
    __syncthreads();

    // ---- layer 2 (x after this layer is dead; only skip matters) ----
    mfma_phaseB(2, xb, gbuf, WA, biasAll, wave, lr, lk);
    __syncthreads();
    phaseC_skip(2, 0, gbuf, SW, skacc, wave, lr, lk);

    // ---- final skip writes (waves 0,1 hold skip[o][g]) ----
    if (wave < 2) {
        int g = wave * 16 + lr;
        int ig = item0 + g, b = ig / NN, nn = ig - b * NN;
        #pragma unroll
        for (int mt = 0; mt < 4; ++mt) {
            #pragma unroll
            for (int j = 0; j < 4; ++j) {
                int oo = mt * 16 + lk * 4 + j;
                float v = skacc[mt][j] + skip_b[oo] + skip_b[64 + oo] + skip_b[128 + oo];
                int bc = b * 64 + oo;
                S[(size_t)nn * BCD + bc] = v;
                St[(size_t)bc * NPAD + SWZK(nn, oo)] = f2bf(v);
            }
        }
    }
}

// ---------------- K3: bf16 MFMA GEMM, C[m][n] = sum_k A[m][k]*B[n][k] ----------------
__global__ __launch_bounds__(256) void gemm_mfma(
    const unsigned short* __restrict__ A, const unsigned short* __restrict__ B,
    float* __restrict__ Cf, unsigned short* __restrict__ Ct)
{
    __shared__ unsigned short As[128 * 64];
    __shared__ unsigned short Bs[128 * 64];
    int tid = threadIdx.x;
    int wave = tid >> 6, lane = tid & 63;
    int lk = lane >> 4, lr = lane & 15;
    int n0 = blockIdx.x * 128, m0 = blockIdx.y * 128;
    int wm = wave >> 1, wn = wave & 1;

    f32x4 acc[4][4];
    #pragma unroll
    for (int i = 0; i < 4; ++i)
        #pragma unroll
        for (int j = 0; j < 4; ++j)
            acc[i][j] = (f32x4){0.f, 0.f, 0.f, 0.f};

    for (int k0 = 0; k0 < NPAD; k0 += 64) {
        #pragma unroll
        for (int i = 0; i < 4; ++i) {
            int chunk = wave * 4 + i;
            int row = chunk * 8 + (lane >> 3);
            int koff = (lane & 7) * 8;
            __builtin_amdgcn_global_load_lds(
                (gas_t)(A + (size_t)(m0 + row) * NPAD + k0 + koff),
                (las_t)(&As[chunk * 512]), 16, 0, 0);
            __builtin_amdgcn_global_load_lds(
                (gas_t)(B + (size_t)(n0 + row) * NPAD + k0 + koff),
                (las_t)(&Bs[chunk * 512]), 16, 0, 0);
        }
        __syncthreads();
        #pragma unroll
        for (int s = 0; s < 2; ++s) {
            short8 av[4], bv[4];
            #pragma unroll
            for (int f = 0; f < 4; ++f) {
                int m = wm * 64 + f * 16 + lr;
                int ca = ((s * 4 + lk) ^ (m & 7));
                av[f] = *(const short8*)&As[m * 64 + ca * 8];
                int n = wn * 64 + f * 16 + lr;
                int cb = ((s * 4 + lk) ^ (n & 7));
                bv[f] = *(const short8*)&Bs[n * 64 + cb * 8];
            }
            #pragma unroll
            for (int fi = 0; fi < 4; ++fi)
                #pragma unroll
                for (int fj = 0; fj < 4; ++fj)
                    acc[fi][fj] = __builtin_amdgcn_mfma_f32_16x16x32_bf16(
                        av[fi], bv[fj], acc[fi][fj], 0, 0, 0);
        }
        __syncthreads();
    }

    #pragma unroll
    for (int fi = 0; fi < 4; ++fi) {
        #pragma unroll
        for (int fj = 0; fj < 4; ++fj) {
            int m = m0 + wm * 64 + fi * 16 + lk * 4;
            int n = n0 + wn * 64 + fj * 16 + lr;
            f32x4 v = acc[fi][fj];
            if (Cf) {
                Cf[(size_t)(m + 0) * BCD + n] = v[0];
                Cf[(size_t)(m + 1) * BCD + n] = v[1];
                Cf[(size_t)(m + 2) * BCD + n] = v[2];
                Cf[(size_t)(m + 3) * BCD + n] = v[3];
            }
            if (Ct) {
                ushort4 p;
                p.x = f2bf(v[0]); p.y = f2bf(v[1]);
                p.z = f2bf(v[2]); p.w = f2bf(v[3]);
                *(ushort4*)&Ct[(size_t)n * NPAD + SWZK(m, n)] = p;
            }
        }
    }
}

// ---------------- K4: gcn 1x1 + heads + outputs + partial reductions ----------------
__global__ __launch_bounds__(256) void head_kernel(
    const float* __restrict__ S, const unsigned short* __restrict__ x1t,
    const float* __restrict__ x2,
    const float* __restrict__ wgcnT, const float* __restrict__ gcn_b,
    const float* __restrict__ c01, const float* __restrict__ w1tT,
    const float* __restrict__ h0_w2, const float* __restrict__ h0_b2,
    const float* __restrict__ h1_w2, const float* __restrict__ h1_b2,
    const int* __restrict__ Ct, const float* __restrict__ Yf,
    float* __restrict__ out, float* __restrict__ partials)
{
    __shared__ float hl[4][4][192];
    __shared__ float gxl[4][4][64];
    int tid = threadIdx.x;
    int wave = tid >> 6, o = tid & 63;
    int wid = blockIdx.x * 4 + wave;
    float w2a = h0_w2[o], w2b = h1_w2[o];
    float b20 = h0_b2[0], b21 = h1_b2[0];
    float cb = gcn_b[o], c0a = c01[o], c0b = c01[64 + o];

    float accT = 0.f, accC = 0.f, bce = 0.f, cT = 0.f, cC = 0.f;

    for (int base = wid * 4; base < ITEMS; base += 2048 * 4) {
        #pragma unroll
        for (int it = 0; it < 4; ++it) {
            int item = base + it;
            int b = item / NN, n = item - b * NN;
            int bc = b * 64 + o;
            hl[wave][it][o]       = S[(size_t)n * BCD + bc];
            hl[wave][it][64 + o]  = bf2f(x1t[(size_t)bc * NPAD + SWZK(n, o)]);
            hl[wave][it][128 + o] = x2[(size_t)n * BCD + bc];
        }
        float a0 = cb, a1 = cb, a2 = cb, a3 = cb;
        for (int j = 0; j < 192; ++j) {
            float w = wgcnT[j * 64 + o];
            a0 = fmaf(w, hl[wave][0][j], a0);
            a1 = fmaf(w, hl[wave][1][j], a1);
            a2 = fmaf(w, hl[wave][2][j], a2);
            a3 = fmaf(w, hl[wave][3][j], a3);
        }
        float gxv[4] = {fmaxf(a0, 0.f), fmaxf(a1, 0.f), fmaxf(a2, 0.f), fmaxf(a3, 0.f)};
        #pragma unroll
        for (int it = 0; it < 4; ++it) gxl[wave][it][o] = gxv[it];

        float p0[4], p1[4];
        #pragma unroll
        for (int it = 0; it < 4; ++it) { p0[it] = c0a; p1[it] = c0b; }
        for (int c = 0; c < 64; ++c) {
            float w0 = w1tT[c * 64 + o];
            float w1 = w1tT[4096 + c * 64 + o];
            float g0 = gxl[wave][0][c], g1 = gxl[wave][1][c];
            float g2 = gxl[wave][2][c], g3 = gxl[wave][3][c];
            p0[0] = fmaf(w0, g0, p0[0]); p0[1] = fmaf(w0, g1, p0[1]);
            p0[2] = fmaf(w0, g2, p0[2]); p0[3] = fmaf(w0, g3, p0[3]);
            p1[0] = fmaf(w1, g0, p1[0]); p1[1] = fmaf(w1, g1, p1[1]);
            p1[2] = fmaf(w1, g2, p1[2]); p1[3] = fmaf(w1, g3, p1[3]);
        }
        #pragma unroll
        for (int it = 0; it < 4; ++it) {
            float r0 = w2a * fmaxf(p0[it], 0.f);
            float r1 = w2b * fmaxf(p1[it], 0.f);
            #pragma unroll
            for (int off = 32; off; off >>= 1) {
                r0 += __shfl_down(r0, off, 64);
                r1 += __shfl_down(r1, off, 64);
            }
            int item = base + it;
            int tt = Ct[item];
            if (o == 0) {
                float y0 = 1.f / (1.f + expf(-(r0 + b20)));
                float y1 = 1.f / (1.f + expf(-(r1 + b21)));
                float y = (tt > 0) ? y1 : y0;
                out[1 + item] = y;
                out[1 + ITEMS + item] = y0;
                out[1 + 2 * ITEMS + item] = y1;
                float yc = fminf(fmaxf(y, 1e-7f), 1.f - 1e-7f);
                float Yv = Yf[item];
                bce -= Yv * logf(yc) + (1.f - Yv) * logf(1.f - yc);
                if (tt > 0) cT += 1.f; else cC += 1.f;
            }
            if (tt > 0) accT += gxv[it]; else accC += gxv[it];
        }
    }
    partials[wid * 132 + o] = accT;
    partials[wid * 132 + 64 + o] = accC;
    if (o == 0) {
        partials[wid * 132 + 128] = bce;
        partials[wid * 132 + 129] = cT;
        partials[wid * 132 + 130] = cC;
    }
}

// ---------------- K5: final loss ----------------
__global__ void finalize_kernel(const float* __restrict__ partials,
                                const float* __restrict__ task_emb,
                                float* __restrict__ out)
{
    __shared__ float red[131];
    int tid = threadIdx.x; // 128
    for (int slot = tid; slot < 131; slot += 128) {
        float s = 0.f;
        for (int w = 0; w < 2048; ++w) s += partials[w * 132 + slot];
        red[slot] = s;
    }
    __syncthreads();
    if (tid < 64) {
        float cT = red[129], cC = red[130];
        float iT = 1.f / fmaxf(cT, 1.f), iC = 1.f / fmaxf(cC, 1.f);
        float d1 = task_emb[tid] * (cT * iT) - task_emb[tid] * (cC * iC);
        float d2 = red[tid] * iT - red[64 + tid] * iC;
        float p = d1 * d1 + d2 * d2;
        #pragma unroll
        for (int off = 32; off; off >>= 1) p += __shfl_down(p, off, 64);
        if (tid == 0) out[0] = red[128] * (1.f / (float)ITEMS) + p;
    }
}

// ---------------- launch ----------------
extern "C" void kernel_launch(void* const* d_in, const int* in_sizes, int n_in,
                              void* d_out, int out_size, void* d_ws, size_t ws_size,
                              hipStream_t stream)
{
    const float* X       = (const float*)d_in[0];
    const int*   Ct      = (const int*)d_in[2];
    const float* Yf      = (const float*)d_in[3];
    const float* start_w = (const float*)d_in[5];
    const float* start_b = (const float*)d_in[6];
    const float* filt_w  = (const float*)d_in[7];
    const float* filt_b  = (const float*)d_in[8];
    const float* gate_w  = (const float*)d_in[9];
    const float* gate_b  = (const float*)d_in[10];
    const float* skip_w  = (const float*)d_in[11];
    const float* skip_b  = (const float*)d_in[12];
    const float* bn_g    = (const float*)d_in[13];
    const float* bn_b    = (const float*)d_in[14];
    const float* nv1     = (const float*)d_in[15];
    const float* nv2     = (const float*)d_in[16];
    const float* task    = (const float*)d_in[17];
    const float* gcn_w   = (const float*)d_in[18];
    const float* gcn_b   = (const float*)d_in[19];
    const float* h0_w1   = (const float*)d_in[20];
    const float* h0_b1   = (const float*)d_in[21];
    const float* h0_w2   = (const float*)d_in[22];
    const float* h0_b2   = (const float*)d_in[23];
    const float* h1_w1   = (const float*)d_in[24];
    const float* h1_b1   = (const float*)d_in[25];
    const float* h1_w2   = (const float*)d_in[26];
    const float* h1_b2   = (const float*)d_in[27];

    float* ws    = (float*)d_ws;
    unsigned short* adpT = (unsigned short*)(ws + OFF_ADPT);
    float* S     = ws + OFF_S;
    unsigned short* St   = (unsigned short*)(ws + OFF_ST);
    unsigned short* x1t  = (unsigned short*)(ws + OFF_X1T);
    float* x2    = ws + OFF_X2;
    float* c01   = ws + OFF_C01;
    float* wgcnT = ws + OFF_WGCNT;
    float* w1tT  = ws + OFF_W1TT;
    float* part  = ws + OFF_PART;
    unsigned short* waw  = (unsigned short*)(ws + OFF_WAW);
    unsigned short* sww  = (unsigned short*)(ws + OFF_SWW);
    unsigned short* wstw = (unsigned short*)(ws + OFF_WSTW);
    float* outp  = (float*)d_out;

    hipMemsetAsync(adpT, 0, (size_t)NPAD * NPAD * sizeof(unsigned short), stream);
    hipMemsetAsync(St,   0, (size_t)BCD * NPAD * sizeof(unsigned short), stream);

    prep_kernel<<<1, 256, 0, stream>>>(gcn_w, h0_w1, h0_b1, h1_w1, h1_b1, task,
                                       filt_w, gate_w, skip_w, start_w,
                                       c01, wgcnT, w1tT, waw, sww, wstw);
    adp_kernel<<<NN, 256, 0, stream>>>(nv1, nv2, adpT);

    const int K2_LDS = 39296 * 4; // ~153.5 KiB dynamic LDS
    hipFuncSetAttribute(reinterpret_cast<const void*>(temporal_kernel),
                        hipFuncAttributeMaxDynamicSharedMemorySize, K2_LDS);
    temporal_kernel<<<ITEMS / 32, 1024, K2_LDS, stream>>>(
        X, start_b, waw, sww, wstw, filt_b, gate_b,
        skip_b, bn_g, bn_b, S, St);

    dim3 gg(BCD / 128, NPAD / 128);
    gemm_mfma<<<gg, 256, 0, stream>>>(adpT, St, nullptr, x1t);  // x1t = (adp^T·S)^T
    gemm_mfma<<<gg, 256, 0, stream>>>(adpT, x1t, x2, nullptr);  // x2  = adp^T·x1

    head_kernel<<<512, 256, 0, stream>>>(S, x1t, x2, wgcnT, gcn_b, c01, w1tT,
                                         h0_w2, h0_b2, h1_w2, h1_b2,
                                         Ct, Yf, outp, part);
    finalize_kernel<<<1, 128, 0, stream>>>(part, task, outp);
}

// Round 9
// 612.753 us; speedup vs baseline: 76.3218x; 1.2243x over previous
//
#include <hip/hip_runtime.h>
#include <cstdint>

// ---------------- problem constants ----------------
#define NB 64        // batch
#define TT 8         // timesteps
#define NN 2000      // nodes
#define NF 16        // in features
#define NCH 64       // channels
#define NPAD 2048    // padded node dim
#define BCD 4096     // NB*NCH
#define ITEMS 128000 // NB*NN

// ws offsets (floats). x2 aliases [adpF|St] (both dead before GEMM2 writes x2).
#define OFF_ADPF  0                         // fp32 adp [2048][2048] = 4194304
#define OFF_ST    4194304                   // bf16 St [4096][2048]  = 4194304 floats
#define OFF_X2    0                         // fp32 x2 [2048][4096]  = 8388608 (alias)
#define OFF_ADPT  8388608                   // bf16 adpT [2048][2048] = 2097152 floats
#define OFF_S     10485760                  // fp32 S [2048][4096]   = 8388608
#define OFF_X1F   18874368                  // fp32 x1 [2048][4096]  = 8388608
#define OFF_X1T   27262976                  // bf16 x1t [4096][2048] = 4194304 floats
#define OFF_C01   31457280                  // 128
#define OFF_WGCNT (OFF_C01 + 128)           // 12288
#define OFF_W1TT  (OFF_WGCNT + 12288)       // 8192
#define OFF_PART  (OFF_W1TT + 8192)         // 270336
#define OFF_RED   (OFF_PART + 270336)       // 136
#define OFF_WAW   (OFF_RED + 136)           // 24576
#define OFF_SWW   (OFF_WAW + 24576)         // 6144
#define OFF_WSTW  (OFF_SWW + 6144)          // 4096

// chunk-XOR swizzle on the k dimension (8-bf16 chunks within 64-k tiles)
#define SWZK(k, x) (((k) & ~63) | (((((k) >> 3) & 7) ^ ((x) & 7)) << 3) | ((k) & 7))
// gbuf row swizzle (8 chunks/row)
#define GSWZ(n) ((((n) >> 3) ^ (n)) & 7)

typedef __attribute__((ext_vector_type(8))) short short8;
typedef __attribute__((ext_vector_type(4))) float f32x4;
typedef const __attribute__((address_space(1))) uint32_t* gas_t;
typedef __attribute__((address_space(3))) uint32_t* las_t;

__device__ __forceinline__ float fast_rcp(float x) { return __builtin_amdgcn_rcpf(x); }
__device__ __forceinline__ float fast_tanh(float x) {
    x = fminf(fmaxf(x, -10.f), 10.f);
    float e = __expf(2.f * x);
    return (e - 1.f) * fast_rcp(e + 1.f);
}
__device__ __forceinline__ float fast_sigmoid(float x) {
    return fast_rcp(1.f + __expf(-x));
}
// RNE f32->bf16 (proven bit-path from rounds 5-7; do NOT use v_cvt_pk_bf16_f32,
// it regressed absmax 3.9e-3 -> 5.1e-2 in round 8: rounding mode mismatch)
__device__ __forceinline__ unsigned short f2bf(float f) {
    uint32_t u = __float_as_uint(f);
    u += 0x7fff + ((u >> 16) & 1);
    return (unsigned short)(u >> 16);
}
__device__ __forceinline__ float bf2f(unsigned short b) {
    return __uint_as_float(((uint32_t)b) << 16);
}

// ---------------- K0: precompute (parallelized over 64 blocks) ----------------
__global__ __launch_bounds__(256) void prep_kernel(const float* __restrict__ gcn_w,
                            const float* __restrict__ h0_w1, const float* __restrict__ h0_b1,
                            const float* __restrict__ h1_w1, const float* __restrict__ h1_b1,
                            const float* __restrict__ task_emb,
                            const float* __restrict__ filt_w, const float* __restrict__ gate_w,
                            const float* __restrict__ skip_w, const float* __restrict__ start_w,
                            float* __restrict__ c01, float* __restrict__ wgcnT,
                            float* __restrict__ w1tT,
                            unsigned short* __restrict__ waw,
                            unsigned short* __restrict__ sww,
                            unsigned short* __restrict__ wstw)
{
    const int GS = 64 * 256;
    int gt = blockIdx.x * 256 + threadIdx.x;
    for (int idx = gt; idx < 64 * 192; idx += GS) {
        int o = idx / 192, j = idx % 192;
        wgcnT[j * 64 + o] = gcn_w[idx];
    }
    for (int idx = gt; idx < 4096; idx += GS) {
        int o = idx >> 6, c = idx & 63;
        w1tT[c * 64 + o]        = h0_w1[o * 128 + 64 + c];
        w1tT[4096 + c * 64 + o] = h1_w1[o * 128 + 64 + c];
    }
    for (int job = gt; job < 3 * 128 * 16; job += GS) {
        int L = job / 2048, rem = job % 2048;
        int r = rem >> 4, chp = rem & 15;
        int cho = chp ^ (r & 15);
        #pragma unroll
        for (int i = 0; i < 8; ++i) {
            int k = cho * 8 + i, tap = k >> 6, c = k & 63;
            float v = (r < 64) ? filt_w[L * 8192 + r * 128 + c * 2 + tap]
                               : gate_w[L * 8192 + (r - 64) * 128 + c * 2 + tap];
            waw[((L * 128 + r) * 16 + chp) * 8 + i] = f2bf(v);
        }
    }
    for (int job = gt; job < 3 * 64 * 8; job += GS) {
        int L = job / 512, rem = job % 512;
        int o = rem >> 3, chp = rem & 7;
        int cho = chp ^ (o & 7);
        #pragma unroll
        for (int i = 0; i < 8; ++i)
            sww[((L * 64 + o) * 8 + chp) * 8 + i] = f2bf(skip_w[L * 4096 + o * 64 + cho * 8 + i]);
    }
    for (int job = gt; job < 64 * 16; job += GS) {
        int o = job >> 4, chp = job & 15;
        int cho = chp ^ (o & 15);
        #pragma unroll
        for (int i = 0; i < 8; ++i) {
            int k = cho * 8 + i;
            wstw[(o * 16 + chp) * 8 + i] = (k < 16) ? f2bf(start_w[o * 16 + k]) : (unsigned short)0;
        }
    }
    if (gt < 128) {
        int head = gt >> 6, o = gt & 63;
        const float* w1 = head ? h1_w1 : h0_w1;
        const float* b1 = head ? h1_b1 : h0_b1;
        float a = b1[o];
        for (int k = 0; k < 64; ++k) a = fmaf(w1[o * 128 + k], task_emb[k], a);
        c01[gt] = a;
    }
}

// ---------------- K1: adpF = softmax(relu(nv1@nv2), axis=1), fp32, coalesced ----------------
__global__ __launch_bounds__(256) void adp_kernel(const float* __restrict__ nv1,
                                                  const float* __restrict__ nv2,
                                                  float* __restrict__ adpF)
{
    __shared__ float nv1s[10];
    __shared__ float rbuf[4];
    int tid = threadIdx.x;
    int r = blockIdx.x;
    if (tid < 10) nv1s[tid] = nv1[r * 10 + tid];
    __syncthreads();

    float val[8];
    float vmax = -3.4e38f;
    #pragma unroll
    for (int s = 0; s < 8; ++s) {
        int j = tid + s * 256;
        if (j < NN) {
            float v = 0.f;
            #pragma unroll
            for (int k = 0; k < 10; ++k) v = fmaf(nv1s[k], nv2[k * NN + j], v);
            v = fmaxf(v, 0.f);
            val[s] = v;
            vmax = fmaxf(vmax, v);
        } else val[s] = -3.4e38f;
    }
    for (int off = 32; off; off >>= 1) vmax = fmaxf(vmax, __shfl_down(vmax, off, 64));
    if ((tid & 63) == 0) rbuf[tid >> 6] = vmax;
    __syncthreads();
    vmax = fmaxf(fmaxf(rbuf[0], rbuf[1]), fmaxf(rbuf[2], rbuf[3]));
    __syncthreads();
    float sum = 0.f;
    #pragma unroll
    for (int s = 0; s < 8; ++s) {
        int j = tid + s * 256;
        if (j < NN) { val[s] = expf(val[s] - vmax); sum += val[s]; }
    }
    for (int off = 32; off; off >>= 1) sum += __shfl_down(sum, off, 64);
    if ((tid & 63) == 0) rbuf[tid >> 6] = sum;
    __syncthreads();
    sum = rbuf[0] + rbuf[1] + rbuf[2] + rbuf[3];
    float inv = 1.f / sum;
    #pragma unroll
    for (int s = 0; s < 8; ++s) {
        int j = tid + s * 256;
        if (j < NN) adpF[(size_t)r * NPAD + j] = val[s] * inv;
    }
}

// ---------------- K1b: adpT = transpose(adpF) -> bf16, k-swizzled, zero-padded ----------------
__global__ __launch_bounds__(256) void transpose_adp(const float* __restrict__ adpF,
                                                     unsigned short* __restrict__ adpT)
{
    __shared__ float tile[64][65];
    int tid = threadIdx.x;
    int r0 = blockIdx.x * 64;   // source row of adp = k dim of adpT
    int j0 = blockIdx.y * 64;   // adpT row dim
    #pragma unroll
    for (int s = 0; s < 16; ++s) {
        int idx = s * 256 + tid;
        int i = idx >> 6, jj = idx & 63;
        int r = r0 + i, j = j0 + jj;
        tile[i][jj] = (r < NN && j < NN) ? adpF[(size_t)r * NPAD + j] : 0.f;
    }
    __syncthreads();
    #pragma unroll
    for (int s = 0; s < 2; ++s) {
        int slot = s * 256 + tid;
        int j = slot >> 3, ch = slot & 7;
        short8 v;
        #pragma unroll
        for (int e = 0; e < 8; ++e) v[e] = (short)f2bf(tile[ch * 8 + e][j]);
        *(short8*)&adpT[(size_t)(j0 + j) * NPAD + r0 + ((ch ^ (j & 7)) << 3)] = v;
    }
}

// ---------------- K2: fused temporal stack (MFMA) ----------------
__device__ __forceinline__ void mfma_phaseB(int L,
    const unsigned short* __restrict__ xb, unsigned short* __restrict__ gbuf,
    const unsigned short* __restrict__ WA, const float* __restrict__ biasAll,
    int wave, int lr, int lk)
{
    int n = wave * 16 + lr;
    f32x4 aF[4], aG[4];
    #pragma unroll
    for (int mt = 0; mt < 4; ++mt) {
        aF[mt] = (f32x4){0.f, 0.f, 0.f, 0.f};
        aG[mt] = (f32x4){0.f, 0.f, 0.f, 0.f};
    }
    #pragma unroll
    for (int ks = 0; ks < 4; ++ks) {
        short8 bv = *(const short8*)&xb[(n * 16 + ((ks * 4 + lk) ^ (n & 15))) * 8];
        #pragma unroll
        for (int mt = 0; mt < 4; ++mt) {
            int r = mt * 16 + lr;
            short8 av = *(const short8*)&WA[(r * 16 + ((ks * 4 + lk) ^ (r & 15))) * 8];
            aF[mt] = __builtin_amdgcn_mfma_f32_16x16x32_bf16(av, bv, aF[mt], 0, 0, 0);
        }
        #pragma unroll
        for (int mt = 0; mt < 4; ++mt) {
            int r = (mt + 4) * 16 + lr;
            short8 av = *(const short8*)&WA[(r * 16 + ((ks * 4 + lk) ^ (r & 15))) * 8];
            aG[mt] = __builtin_amdgcn_mfma_f32_16x16x32_bf16(av, bv, aG[mt], 0, 0, 0);
        }
    }
    int gs = GSWZ(n);
    #pragma unroll
    for (int mt = 0; mt < 4; ++mt) {
        int ob = mt * 16 + lk * 4;
        ushort4 p;
        p.x = f2bf(fast_tanh(aF[mt][0] + biasAll[L * 128 + ob + 0]) * fast_sigmoid(aG[mt][0] + biasAll[L * 128 + 64 + ob + 0]));
        p.y = f2bf(fast_tanh(aF[mt][1] + biasAll[L * 128 + ob + 1]) * fast_sigmoid(aG[mt][1] + biasAll[L * 128 + 64 + ob + 1]));
        p.z = f2bf(fast_tanh(aF[mt][2] + biasAll[L * 128 + ob + 2]) * fast_sigmoid(aG[mt][2] + biasAll[L * 128 + 64 + ob + 2]));
        p.w = f2bf(fast_tanh(aF[mt][3] + biasAll[L * 128 + ob + 3]) * fast_sigmoid(aG[mt][3] + biasAll[L * 128 + 64 + ob + 3]));
        *(ushort4*)&gbuf[((n * 8) + ((mt * 2 + (lk >> 1)) ^ gs)) * 8 + (lk & 1) * 4] = p;
    }
}

template<int L, int D, int WOUT, int DN>
__device__ __forceinline__ void phaseC_conv(unsigned short* __restrict__ xb,
    const unsigned short* __restrict__ gbuf,
    const float* __restrict__ bn_g, const float* __restrict__ bn_b,
    float xreg[2][8], int wave, int o)
{
    float bsc = bn_g[L * 64 + o] * rsqrtf(1.0f + 1e-5f);
    float bsh = bn_b[L * 64 + o];
    #pragma unroll
    for (int gi = 0; gi < 2; ++gi) {
        int g = wave * 2 + gi;
        #pragma unroll
        for (int t = 0; t < WOUT; ++t) {
            int n = g * 8 + t;
            float gv = bf2f(gbuf[(n * 8 + ((o >> 3) ^ GSWZ(n))) * 8 + (o & 7)]);
            float nx = (gv + xreg[gi][t + D]) * bsc + bsh;
            xreg[gi][t] = nx;
            if (DN > 0) {
                unsigned short bfv = f2bf(nx);
                xb[(n * 16 + ((o >> 3) ^ (n & 15))) * 8 + (o & 7)] = bfv;
                if (t >= DN) {
                    int n1 = n - DN;
                    xb[(n1 * 16 + (((o >> 3) + 8) ^ (n1 & 15))) * 8 + (o & 7)] = bfv;
                }
            }
        }
    }
}

__device__ __forceinline__ void phaseC_skip(int L, int LASTT,
    const unsigned short* __restrict__ gbuf, const unsigned short* __restrict__ SW,
    f32x4 skacc[4], int wave, int lr, int lk)
{
    if (wave >= 2) return;
    int g = wave * 16 + lr;
    int n = g * 8 + LASTT;
    int gs = GSWZ(n);
    #pragma unroll
    for (int ks = 0; ks < 2; ++ks) {
        short8 bv = *(const short8*)&gbuf[(n * 8 + ((ks * 4 + lk) ^ gs)) * 8];
        #pragma unroll
        for (int mt = 0; mt < 4; ++mt) {
            int r = mt * 16 + lr;
            short8 av = *(const short8*)&SW[((L * 64 + r) * 8 + ((ks * 4 + lk) ^ (r & 7))) * 8];
            skacc[mt] = __builtin_amdgcn_mfma_f32_16x16x32_bf16(av, bv, skacc[mt], 0, 0, 0);
        }
    }
}

__global__ __launch_bounds__(1024) void temporal_kernel(
    const float* __restrict__ X,
    const float* __restrict__ start_b,
    const unsigned short* __restrict__ waw,
    const unsigned short* __restrict__ sww,
    const unsigned short* __restrict__ wstw,
    const float* __restrict__ filt_b, const float* __restrict__ gate_b,
    const float* __restrict__ skip_b,
    const float* __restrict__ bn_g, const float* __restrict__ bn_b,
    float* __restrict__ S, unsigned short* __restrict__ St)
{
    extern __shared__ float smem[];
    unsigned short* xb   = (unsigned short*)smem;              // 32768 ush
    unsigned short* gbuf = (unsigned short*)(smem + 16384);    // 16384 ush
    unsigned short* WA   = (unsigned short*)(smem + 24576);    // 16384 ush
    unsigned short* SW   = (unsigned short*)(smem + 32768);    // 12288 ush
    float* biasAll       = smem + 38912;                       // 384 f32

    int tid = threadIdx.x;
    int wave = tid >> 6, lane = tid & 63;
    int lr = lane & 15, lk = lane >> 4;
    int o = lane;
    int item0 = blockIdx.x * 32;

    // ---- init staging ----
    __builtin_amdgcn_global_load_lds((gas_t)(wstw + tid * 8), (las_t)(WA + tid * 8), 16, 0, 0);
    for (int idx = tid; idx < 1536; idx += 1024)
        __builtin_amdgcn_global_load_lds((gas_t)(sww + idx * 8), (las_t)(SW + idx * 8), 16, 0, 0);
    if (tid < 384) {
        int L = tid >> 7, oo = tid & 127;
        biasAll[tid] = (oo < 64) ? filt_b[L * 64 + oo] : gate_b[L * 64 + oo - 64];
    }
    {   // X -> xb
        int n = tid >> 2, c = tid & 3;
        int g = n >> 3, t = n & 7;
        int ig = item0 + g, b = ig / NN, nn = ig - b * NN;
        short8 v = {0, 0, 0, 0, 0, 0, 0, 0};
        if (c < 2) {
            const float* src = &X[((size_t)(b * TT + t) * NN + nn) * NF + c * 8];
            float4 f0 = *(const float4*)src;
            float4 f1 = *(const float4*)(src + 4);
            v[0] = (short)f2bf(f0.x); v[1] = (short)f2bf(f0.y);
            v[2] = (short)f2bf(f0.z); v[3] = (short)f2bf(f0.w);
            v[4] = (short)f2bf(f1.x); v[5] = (short)f2bf(f1.y);
            v[6] = (short)f2bf(f1.z); v[7] = (short)f2bf(f1.w);
        }
        *(short8*)&xb[(n * 16 + (c ^ (n & 15))) * 8] = v;
    }
    __syncthreads();

    // ---- start conv MFMA (K=32, M=64) ----
    {
        f32x4 aS[4];
        #pragma unroll
        for (int mt = 0; mt < 4; ++mt) aS[mt] = (f32x4){0.f, 0.f, 0.f, 0.f};
        int n = wave * 16 + lr;
        short8 bv = *(const short8*)&xb[(n * 16 + (lk ^ (n & 15))) * 8];
        #pragma unroll
        for (int mt = 0; mt < 4; ++mt) {
            int r = mt * 16 + lr;
            short8 av = *(const short8*)&WA[(r * 16 + (lk ^ (r & 15))) * 8];
            aS[mt] = __builtin_amdgcn_mfma_f32_16x16x32_bf16(av, bv, aS[mt], 0, 0, 0);
        }
        int gs = GSWZ(n);
        #pragma unroll
        for (int mt = 0; mt < 4; ++mt) {
            ushort4 p;
            p.x = f2bf(aS[mt][0]); p.y = f2bf(aS[mt][1]);
            p.z = f2bf(aS[mt][2]); p.w = f2bf(aS[mt][3]);
            *(ushort4*)&gbuf[((n * 8) + ((mt * 2 + (lk >> 1)) ^ gs)) * 8 + (lk & 1) * 4] = p;
        }
    }
    __syncthreads();

    float xreg[2][8];
    f32x4 skacc[4];
    #pragma unroll
    for (int mt = 0; mt < 4; ++mt) skacc[mt] = (f32x4){0.f, 0.f, 0.f, 0.f};

    // ---- C0: x = start_out + start_b; write taps for layer0 (D=1); stage WA_L0 ----
    {
        __builtin_amdgcn_global_load_lds((gas_t)(waw + (size_t)tid * 8),
                                         (las_t)(WA + tid * 8), 16, 0, 0);
        __builtin_amdgcn_global_load_lds((gas_t)(waw + (size_t)(tid + 1024) * 8),
                                         (las_t)(WA + (tid + 1024) * 8), 16, 0, 0);
        float sb = start_b[o];
        #pragma unroll
        for (int gi = 0; gi < 2; ++gi) {
            int g = wave * 2 + gi;
            #pragma unroll
            for (int t = 0; t < 8; ++t) {
                int n = g * 8 + t;
                float gv = bf2f(gbuf[(n * 8 + ((o >> 3) ^ GSWZ(n))) * 8 + (o & 7)]) + sb;
                xreg[gi][t] = gv;
                unsigned short bfv = f2bf(gv);
                xb[(n * 16 + ((o >> 3) ^ (n & 15))) * 8 + (o & 7)] = bfv;
                if (t >= 1) {
                    int n1 = n - 1;
                    xb[(n1 * 16 + (((o >> 3) + 8) ^ (n1 & 15))) * 8 + (o & 7)] = bfv;
                }
            }
        }
    }
    __syncthreads();

    // ---- layer 0 ----
    mfma_phaseB(0, xb, gbuf, WA, biasAll, wave, lr, lk);
    __syncthreads();
    phaseC_skip(0, 6, gbuf, SW, skacc, wave, lr, lk);
    phaseC_conv<0, 1, 7, 2>(xb, gbuf, bn_g, bn_b, xreg, wave, o);
    __builtin_amdgcn_global_load_lds((gas_t)(waw + (size_t)(2048 + tid) * 8),
                                     (las_t)(WA + tid * 8), 16, 0, 0);
    __builtin_amdgcn_global_load_lds((gas_t)(waw + (size_t)(2048 + tid + 1024) * 8),
                                     (las_t)(WA + (tid + 1024) * 8), 16, 0, 0);
    __syncthreads();

    // ---- layer 1 ----
    mfma_phaseB(1, xb, gbuf, WA, biasAll, wave, lr, lk);
    __syncthreads();
    phaseC_skip(1, 4, gbuf, SW, skacc, wave, lr, lk);
    phaseC_conv<1, 2, 5, 4>(xb, gbuf, bn_g, bn_b, xreg, wave, o);
    __builtin_amdgcn_global_load_lds((gas_t)(waw + (size_t)(4096 + tid) * 8),
                                     (las_t)(WA + tid * 8), 16, 0, 0);
    __builtin_amdgcn_global_load_lds((gas_t)(waw + (size_t)(4096 + tid + 1024) * 8),
                                     (las_t)(WA + (tid + 1024) * 8), 16, 0, 0);
    __syncthreads();

    // ---- layer 2 ----
    mfma_phaseB(2, xb, gbuf, WA, biasAll, wave, lr, lk);
    __syncthreads();
    phaseC_skip(2, 0, gbuf, SW, skacc, wave, lr, lk);

    // ---- final skip writes ----
    if (wave < 2) {
        int g = wave * 16 + lr;
        int ig = item0 + g, b = ig / NN, nn = ig - b * NN;
        #pragma unroll
        for (int mt = 0; mt < 4; ++mt) {
            #pragma unroll
            for (int j = 0; j < 4; ++j) {
                int oo = mt * 16 + lk * 4 + j;
                float v = skacc[mt][j] + skip_b[oo] + skip_b[64 + oo] + skip_b[128 + oo];
                int bc = b * 64 + oo;
                S[(size_t)nn * BCD + bc] = v;
                St[(size_t)bc * NPAD + SWZK(nn, oo)] = f2bf(v);
            }
        }
    }
}

// ---------------- K3: bf16 MFMA GEMM, C[m][n] = sum_k A[m][k]*B[n][k] ----------------
__global__ __launch_bounds__(256) void gemm_mfma(
    const unsigned short* __restrict__ A, const unsigned short* __restrict__ B,
    float* __restrict__ Cf, unsigned short* __restrict__ Ct)
{
    __shared__ unsigned short As[128 * 64];
    __shared__ unsigned short Bs[128 * 64];
    int tid = threadIdx.x;
    int wave = tid >> 6, lane = tid & 63;
    int lk = lane >> 4, lr = lane & 15;
    int n0 = blockIdx.x * 128, m0 = blockIdx.y * 128;
    int wm = wave >> 1, wn = wave & 1;

    f32x4 acc[4][4];
    #pragma unroll
    for (int i = 0; i < 4; ++i)
        #pragma unroll
        for (int j = 0; j < 4; ++j)
            acc[i][j] = (f32x4){0.f, 0.f, 0.f, 0.f};

    for (int k0 = 0; k0 < NPAD; k0 += 64) {
        #pragma unroll
        for (int i = 0; i < 4; ++i) {
            int chunk = wave * 4 + i;
            int row = chunk * 8 + (lane >> 3);
            int koff = (lane & 7) * 8;
            __builtin_amdgcn_global_load_lds(
                (gas_t)(A + (size_t)(m0 + row) * NPAD + k0 + koff),
                (las_t)(&As[chunk * 512]), 16, 0, 0);
            __builtin_amdgcn_global_load_lds(
                (gas_t)(B + (size_t)(n0 + row) * NPAD + k0 + koff),
                (las_t)(&Bs[chunk * 512]), 16, 0, 0);
        }
        __syncthreads();
        #pragma unroll
        for (int s = 0; s < 2; ++s) {
            short8 av[4], bv[4];
            #pragma unroll
            for (int f = 0; f < 4; ++f) {
                int m = wm * 64 + f * 16 + lr;
                int ca = ((s * 4 + lk) ^ (m & 7));
                av[f] = *(const short8*)&As[m * 64 + ca * 8];
                int n = wn * 64 + f * 16 + lr;
                int cb = ((s * 4 + lk) ^ (n & 7));
                bv[f] = *(const short8*)&Bs[n * 64 + cb * 8];
            }
            #pragma unroll
            for (int fi = 0; fi < 4; ++fi)
                #pragma unroll
                for (int fj = 0; fj < 4; ++fj)
                    acc[fi][fj] = __builtin_amdgcn_mfma_f32_16x16x32_bf16(
                        av[fi], bv[fj], acc[fi][fj], 0, 0, 0);
        }
        __syncthreads();
    }

    #pragma unroll
    for (int fi = 0; fi < 4; ++fi) {
        #pragma unroll
        for (int fj = 0; fj < 4; ++fj) {
            int m = m0 + wm * 64 + fi * 16 + lk * 4;
            int n = n0 + wn * 64 + fj * 16 + lr;
            f32x4 v = acc[fi][fj];
            if (Cf) {
                Cf[(size_t)(m + 0) * BCD + n] = v[0];
                Cf[(size_t)(m + 1) * BCD + n] = v[1];
                Cf[(size_t)(m + 2) * BCD + n] = v[2];
                Cf[(size_t)(m + 3) * BCD + n] = v[3];
            }
            if (Ct) {
                ushort4 p;
                p.x = f2bf(v[0]); p.y = f2bf(v[1]);
                p.z = f2bf(v[2]); p.w = f2bf(v[3]);
                *(ushort4*)&Ct[(size_t)n * NPAD + SWZK(m, n)] = p;
            }
        }
    }
}

// ---------------- K4: gcn 1x1 + heads + outputs + partial reductions ----------------
__global__ __launch_bounds__(256) void head_kernel(
    const float* __restrict__ S, const float* __restrict__ x1f,
    const float* __restrict__ x2,
    const float* __restrict__ wgcnT, const float* __restrict__ gcn_b,
    const float* __restrict__ c01, const float* __restrict__ w1tT,
    const float* __restrict__ h0_w2, const float* __restrict__ h0_b2,
    const float* __restrict__ h1_w2, const float* __restrict__ h1_b2,
    const int* __restrict__ Ct, const float* __restrict__ Yf,
    float* __restrict__ out, float* __restrict__ partials)
{
    __shared__ float hl[4][4][192];
    __shared__ float gxl[4][4][64];
    int tid = threadIdx.x;
    int wave = tid >> 6, o = tid & 63;
    int wid = blockIdx.x * 4 + wave;
    float w2a = h0_w2[o], w2b = h1_w2[o];
    float b20 = h0_b2[0], b21 = h1_b2[0];
    float cb = gcn_b[o], c0a = c01[o], c0b = c01[64 + o];

    float accT = 0.f, accC = 0.f, bce = 0.f, cT = 0.f, cC = 0.f;

    for (int base = wid * 4; base < ITEMS; base += 2048 * 4) {
        #pragma unroll
        for (int it = 0; it < 4; ++it) {
            int item = base + it;
            int b = item / NN, n = item - b * NN;
            int bc = b * 64 + o;
            hl[wave][it][o]       = S[(size_t)n * BCD + bc];
            hl[wave][it][64 + o]  = x1f[(size_t)n * BCD + bc];
            hl[wave][it][128 + o] = x2[(size_t)n * BCD + bc];
        }
        float a0 = cb, a1 = cb, a2 = cb, a3 = cb;
        for (int j = 0; j < 192; ++j) {
            float w = wgcnT[j * 64 + o];
            a0 = fmaf(w, hl[wave][0][j], a0);
            a1 = fmaf(w, hl[wave][1][j], a1);
            a2 = fmaf(w, hl[wave][2][j], a2);
            a3 = fmaf(w, hl[wave][3][j], a3);
        }
        float gxv[4] = {fmaxf(a0, 0.f), fmaxf(a1, 0.f), fmaxf(a2, 0.f), fmaxf(a3, 0.f)};
        #pragma unroll
        for (int it = 0; it < 4; ++it) gxl[wave][it][o] = gxv[it];

        float p0[4], p1[4];
        #pragma unroll
        for (int it = 0; it < 4; ++it) { p0[it] = c0a; p1[it] = c0b; }
        for (int c = 0; c < 64; ++c) {
            float w0 = w1tT[c * 64 + o];
            float w1 = w1tT[4096 + c * 64 + o];
            float g0 = gxl[wave][0][c], g1 = gxl[wave][1][c];
            float g2 = gxl[wave][2][c], g3 = gxl[wave][3][c];
            p0[0] = fmaf(w0, g0, p0[0]); p0[1] = fmaf(w0, g1, p0[1]);
            p0[2] = fmaf(w0, g2, p0[2]); p0[3] = fmaf(w0, g3, p0[3]);
            p1[0] = fmaf(w1, g0, p1[0]); p1[1] = fmaf(w1, g1, p1[1]);
            p1[2] = fmaf(w1, g2, p1[2]); p1[3] = fmaf(w1, g3, p1[3]);
        }
        #pragma unroll
        for (int it = 0; it < 4; ++it) {
            float r0 = w2a * fmaxf(p0[it], 0.f);
            float r1 = w2b * fmaxf(p1[it], 0.f);
            #pragma unroll
            for (int off = 32; off; off >>= 1) {
                r0 += __shfl_down(r0, off, 64);
                r1 += __shfl_down(r1, off, 64);
            }
            int item = base + it;
            int tt = Ct[item];
            if (o == 0) {
                float y0 = 1.f / (1.f + expf(-(r0 + b20)));
                float y1 = 1.f / (1.f + expf(-(r1 + b21)));
                float y = (tt > 0) ? y1 : y0;
                out[1 + item] = y;
                out[1 + ITEMS + item] = y0;
                out[1 + 2 * ITEMS + item] = y1;
                float yc = fminf(fmaxf(y, 1e-7f), 1.f - 1e-7f);
                float Yv = Yf[item];
                bce -= Yv * logf(yc) + (1.f - Yv) * logf(1.f - yc);
                if (tt > 0) cT += 1.f; else cC += 1.f;
            }
            if (tt > 0) accT += gxv[it]; else accC += gxv[it];
        }
    }
    partials[wid * 132 + o] = accT;
    partials[wid * 132 + 64 + o] = accC;
    if (o == 0) {
        partials[wid * 132 + 128] = bce;
        partials[wid * 132 + 129] = cT;
        partials[wid * 132 + 130] = cC;
    }
}

// ---------------- K5a: parallel slot reduce ----------------
__global__ __launch_bounds__(256) void reduce_kernel(const float* __restrict__ partials,
                                                     float* __restrict__ red)
{
    __shared__ float rb[4];
    int slot = blockIdx.x;
    int tid = threadIdx.x;
    float s = 0.f;
    for (int w = tid; w < 2048; w += 256) s += partials[w * 132 + slot];
    #pragma unroll
    for (int off = 32; off; off >>= 1) s += __shfl_down(s, off, 64);
    if ((tid & 63) == 0) rb[tid >> 6] = s;
    __syncthreads();
    if (tid == 0) red[slot] = rb[0] + rb[1] + rb[2] + rb[3];
}

// ---------------- K5b: final loss ----------------
__global__ void final_kernel(const float* __restrict__ red,
                             const float* __restrict__ task_emb,
                             float* __restrict__ out)
{
    int tid = threadIdx.x; // 64
    float cT = red[129], cC = red[130];
    float iT = 1.f / fmaxf(cT, 1.f), iC = 1.f / fmaxf(cC, 1.f);
    float d1 = task_emb[tid] * (cT * iT) - task_emb[tid] * (cC * iC);
    float d2 = red[tid] * iT - red[64 + tid] * iC;
    float p = d1 * d1 + d2 * d2;
    #pragma unroll
    for (int off = 32; off; off >>= 1) p += __shfl_down(p, off, 64);
    if (tid == 0) out[0] = red[128] * (1.f / (float)ITEMS) + p;
}

// ---------------- launch ----------------
extern "C" void kernel_launch(void* const* d_in, const int* in_sizes, int n_in,
                              void* d_out, int out_size, void* d_ws, size_t ws_size,
                              hipStream_t stream)
{
    const float* X       = (const float*)d_in[0];
    const int*   Ct      = (const int*)d_in[2];
    const float* Yf      = (const float*)d_in[3];
    const float* start_w = (const float*)d_in[5];
    const float* start_b = (const float*)d_in[6];
    const float* filt_w  = (const float*)d_in[7];
    const float* filt_b  = (const float*)d_in[8];
    const float* gate_w  = (const float*)d_in[9];
    const float* gate_b  = (const float*)d_in[10];
    const float* skip_w  = (const float*)d_in[11];
    const float* skip_b  = (const float*)d_in[12];
    const float* bn_g    = (const float*)d_in[13];
    const float* bn_b    = (const float*)d_in[14];
    const float* nv1     = (const float*)d_in[15];
    const float* nv2     = (const float*)d_in[16];
    const float* task    = (const float*)d_in[17];
    const float* gcn_w   = (const float*)d_in[18];
    const float* gcn_b   = (const float*)d_in[19];
    const float* h0_w1   = (const float*)d_in[20];
    const float* h0_b1   = (const float*)d_in[21];
    const float* h0_w2   = (const float*)d_in[22];
    const float* h0_b2   = (const float*)d_in[23];
    const float* h1_w1   = (const float*)d_in[24];
    const float* h1_b1   = (const float*)d_in[25];
    const float* h1_w2   = (const float*)d_in[26];
    const float* h1_b2   = (const float*)d_in[27];

    float* ws    = (float*)d_ws;
    float* adpF  = ws + OFF_ADPF;
    unsigned short* St   = (unsigned short*)(ws + OFF_ST);
    float* x2    = ws + OFF_X2;        // aliases [adpF|St], safe by schedule
    unsigned short* adpT = (unsigned short*)(ws + OFF_ADPT);
    float* S     = ws + OFF_S;
    float* x1f   = ws + OFF_X1F;
    unsigned short* x1t  = (unsigned short*)(ws + OFF_X1T);
    float* c01   = ws + OFF_C01;
    float* wgcnT = ws + OFF_WGCNT;
    float* w1tT  = ws + OFF_W1TT;
    float* part  = ws + OFF_PART;
    float* red   = ws + OFF_RED;
    unsigned short* waw  = (unsigned short*)(ws + OFF_WAW);
    unsigned short* sww  = (unsigned short*)(ws + OFF_SWW);
    unsigned short* wstw = (unsigned short*)(ws + OFF_WSTW);
    float* outp  = (float*)d_out;

    // zero St (pad rows n in [2000,2048) must contribute 0 to GEMM1)
    hipMemsetAsync(St, 0, (size_t)BCD * NPAD * sizeof(unsigned short), stream);

    prep_kernel<<<64, 256, 0, stream>>>(gcn_w, h0_w1, h0_b1, h1_w1, h1_b1, task,
                                        filt_w, gate_w, skip_w, start_w,
                                        c01, wgcnT, w1tT, waw, sww, wstw);
    adp_kernel<<<NN, 256, 0, stream>>>(nv1, nv2, adpF);
    dim3 tg(NPAD / 64, NPAD / 64);
    transpose_adp<<<tg, 256, 0, stream>>>(adpF, adpT);

    const int K2_LDS = 39296 * 4; // ~153.5 KiB dynamic LDS
    hipFuncSetAttribute(reinterpret_cast<const void*>(temporal_kernel),
                        hipFuncAttributeMaxDynamicSharedMemorySize, K2_LDS);
    temporal_kernel<<<ITEMS / 32, 1024, K2_LDS, stream>>>(
        X, start_b, waw, sww, wstw, filt_b, gate_b,
        skip_b, bn_g, bn_b, S, St);

    dim3 gg(BCD / 128, NPAD / 128);
    gemm_mfma<<<gg, 256, 0, stream>>>(adpT, St, x1f, x1t);      // x1 (both layouts)
    gemm_mfma<<<gg, 256, 0, stream>>>(adpT, x1t, x2, nullptr);  // x2 = adp^T·x1

    head_kernel<<<512, 256, 0, stream>>>(S, x1f, x2, wgcnT, gcn_b, c01, w1tT,
                                         h0_w2, h0_b2, h1_w2, h1_b2,
                                         Ct, Yf, outp, part);
    reduce_kernel<<<131, 256, 0, stream>>>(part, red);
    final_kernel<<<1, 64, 0, stream>>>(red, task, outp);
}

// Round 10
// 530.335 us; speedup vs baseline: 88.1827x; 1.1554x over previous
//
#include <hip/hip_runtime.h>
#include <cstdint>

// ---------------- problem constants ----------------
#define NB 64        // batch
#define TT 8         // timesteps
#define NN 2000      // nodes
#define NF 16        // in features
#define NCH 64       // channels
#define NPAD 2048    // padded node dim
#define BCD 4096     // NB*NCH
#define ITEMS 128000 // NB*NN

// ws offsets (floats). x2 aliases [adpF|St] (both dead before GEMM2 writes x2).
#define OFF_ADPF  0                         // fp32 adp [2048][2048] = 4194304
#define OFF_ST    4194304                   // bf16 St [4096][2048]  = 4194304 floats
#define OFF_X2    0                         // fp32 x2 [2048][4096]  = 8388608 (alias)
#define OFF_ADPT  8388608                   // bf16 adpT [2048][2048] = 2097152 floats
#define OFF_S     10485760                  // fp32 S [2048][4096]   = 8388608
#define OFF_X1F   18874368                  // fp32 x1 [2048][4096]  = 8388608
#define OFF_X1T   27262976                  // bf16 x1t [4096][2048] = 4194304 floats
#define OFF_C01   31457280                  // 128
#define OFF_WGCNT (OFF_C01 + 128)           // 12288
#define OFF_W1TT  (OFF_WGCNT + 12288)       // 8192
#define OFF_PART  (OFF_W1TT + 8192)         // 270336
#define OFF_RED   (OFF_PART + 270336)       // 136
#define OFF_WAW   (OFF_RED + 136)           // 24576
#define OFF_SWW   (OFF_WAW + 24576)         // 6144
#define OFF_WSTW  (OFF_SWW + 6144)          // 4096

// chunk-XOR swizzle on the k dimension (8-bf16 chunks within 64-k tiles)
#define SWZK(k, x) (((k) & ~63) | (((((k) >> 3) & 7) ^ ((x) & 7)) << 3) | ((k) & 7))
// gbuf row swizzle (8 chunks/row)
#define GSWZ(n) ((((n) >> 3) ^ (n)) & 7)

typedef __attribute__((ext_vector_type(8))) short short8;
typedef __attribute__((ext_vector_type(4))) float f32x4;
typedef const __attribute__((address_space(1))) uint32_t* gas_t;
typedef __attribute__((address_space(3))) uint32_t* las_t;

__device__ __forceinline__ float fast_rcp(float x) { return __builtin_amdgcn_rcpf(x); }
__device__ __forceinline__ float fast_tanh(float x) {
    x = fminf(fmaxf(x, -10.f), 10.f);
    float e = __expf(2.f * x);
    return (e - 1.f) * fast_rcp(e + 1.f);
}
__device__ __forceinline__ float fast_sigmoid(float x) {
    return fast_rcp(1.f + __expf(-x));
}
// RNE f32->bf16 (proven bit-path; v_cvt_pk_bf16_f32 regressed absmax 13x in r8)
__device__ __forceinline__ unsigned short f2bf(float f) {
    uint32_t u = __float_as_uint(f);
    u += 0x7fff + ((u >> 16) & 1);
    return (unsigned short)(u >> 16);
}
__device__ __forceinline__ float bf2f(unsigned short b) {
    return __uint_as_float(((uint32_t)b) << 16);
}

// ---------------- K0: precompute (parallelized over 64 blocks) ----------------
__global__ __launch_bounds__(256) void prep_kernel(const float* __restrict__ gcn_w,
                            const float* __restrict__ h0_w1, const float* __restrict__ h0_b1,
                            const float* __restrict__ h1_w1, const float* __restrict__ h1_b1,
                            const float* __restrict__ task_emb,
                            const float* __restrict__ filt_w, const float* __restrict__ gate_w,
                            const float* __restrict__ skip_w, const float* __restrict__ start_w,
                            float* __restrict__ c01, float* __restrict__ wgcnT,
                            float* __restrict__ w1tT,
                            unsigned short* __restrict__ waw,
                            unsigned short* __restrict__ sww,
                            unsigned short* __restrict__ wstw)
{
    const int GS = 64 * 256;
    int gt = blockIdx.x * 256 + threadIdx.x;
    for (int idx = gt; idx < 64 * 192; idx += GS) {
        int o = idx / 192, j = idx % 192;
        wgcnT[j * 64 + o] = gcn_w[idx];
    }
    for (int idx = gt; idx < 4096; idx += GS) {
        int o = idx >> 6, c = idx & 63;
        w1tT[c * 64 + o]        = h0_w1[o * 128 + 64 + c];
        w1tT[4096 + c * 64 + o] = h1_w1[o * 128 + 64 + c];
    }
    for (int job = gt; job < 3 * 128 * 16; job += GS) {
        int L = job / 2048, rem = job % 2048;
        int r = rem >> 4, chp = rem & 15;
        int cho = chp ^ (r & 15);
        #pragma unroll
        for (int i = 0; i < 8; ++i) {
            int k = cho * 8 + i, tap = k >> 6, c = k & 63;
            float v = (r < 64) ? filt_w[L * 8192 + r * 128 + c * 2 + tap]
                               : gate_w[L * 8192 + (r - 64) * 128 + c * 2 + tap];
            waw[((L * 128 + r) * 16 + chp) * 8 + i] = f2bf(v);
        }
    }
    for (int job = gt; job < 3 * 64 * 8; job += GS) {
        int L = job / 512, rem = job % 512;
        int o = rem >> 3, chp = rem & 7;
        int cho = chp ^ (o & 7);
        #pragma unroll
        for (int i = 0; i < 8; ++i)
            sww[((L * 64 + o) * 8 + chp) * 8 + i] = f2bf(skip_w[L * 4096 + o * 64 + cho * 8 + i]);
    }
    for (int job = gt; job < 64 * 16; job += GS) {
        int o = job >> 4, chp = job & 15;
        int cho = chp ^ (o & 15);
        #pragma unroll
        for (int i = 0; i < 8; ++i) {
            int k = cho * 8 + i;
            wstw[(o * 16 + chp) * 8 + i] = (k < 16) ? f2bf(start_w[o * 16 + k]) : (unsigned short)0;
        }
    }
    if (gt < 128) {
        int head = gt >> 6, o = gt & 63;
        const float* w1 = head ? h1_w1 : h0_w1;
        const float* b1 = head ? h1_b1 : h0_b1;
        float a = b1[o];
        for (int k = 0; k < 64; ++k) a = fmaf(w1[o * 128 + k], task_emb[k], a);
        c01[gt] = a;
    }
}

// ---------------- K1: adpF = softmax(relu(nv1@nv2), axis=1), fp32, coalesced ----------------
__global__ __launch_bounds__(256) void adp_kernel(const float* __restrict__ nv1,
                                                  const float* __restrict__ nv2,
                                                  float* __restrict__ adpF)
{
    __shared__ float nv1s[10];
    __shared__ float rbuf[4];
    int tid = threadIdx.x;
    int r = blockIdx.x;
    if (tid < 10) nv1s[tid] = nv1[r * 10 + tid];
    __syncthreads();

    float val[8];
    float vmax = -3.4e38f;
    #pragma unroll
    for (int s = 0; s < 8; ++s) {
        int j = tid + s * 256;
        if (j < NN) {
            float v = 0.f;
            #pragma unroll
            for (int k = 0; k < 10; ++k) v = fmaf(nv1s[k], nv2[k * NN + j], v);
            v = fmaxf(v, 0.f);
            val[s] = v;
            vmax = fmaxf(vmax, v);
        } else val[s] = -3.4e38f;
    }
    for (int off = 32; off; off >>= 1) vmax = fmaxf(vmax, __shfl_down(vmax, off, 64));
    if ((tid & 63) == 0) rbuf[tid >> 6] = vmax;
    __syncthreads();
    vmax = fmaxf(fmaxf(rbuf[0], rbuf[1]), fmaxf(rbuf[2], rbuf[3]));
    __syncthreads();
    float sum = 0.f;
    #pragma unroll
    for (int s = 0; s < 8; ++s) {
        int j = tid + s * 256;
        if (j < NN) { val[s] = expf(val[s] - vmax); sum += val[s]; }
    }
    for (int off = 32; off; off >>= 1) sum += __shfl_down(sum, off, 64);
    if ((tid & 63) == 0) rbuf[tid >> 6] = sum;
    __syncthreads();
    sum = rbuf[0] + rbuf[1] + rbuf[2] + rbuf[3];
    float inv = 1.f / sum;
    #pragma unroll
    for (int s = 0; s < 8; ++s) {
        int j = tid + s * 256;
        if (j < NN) adpF[(size_t)r * NPAD + j] = val[s] * inv;
    }
}

// ---------------- K1b: adpT = transpose(adpF) -> bf16, k-swizzled, zero-padded ----------------
__global__ __launch_bounds__(256) void transpose_adp(const float* __restrict__ adpF,
                                                     unsigned short* __restrict__ adpT)
{
    __shared__ float tile[64][65];
    int tid = threadIdx.x;
    int r0 = blockIdx.x * 64;   // source row of adp = k dim of adpT
    int j0 = blockIdx.y * 64;   // adpT row dim
    #pragma unroll
    for (int s = 0; s < 16; ++s) {
        int idx = s * 256 + tid;
        int i = idx >> 6, jj = idx & 63;
        int r = r0 + i, j = j0 + jj;
        tile[i][jj] = (r < NN && j < NN) ? adpF[(size_t)r * NPAD + j] : 0.f;
    }
    __syncthreads();
    #pragma unroll
    for (int s = 0; s < 2; ++s) {
        int slot = s * 256 + tid;
        int j = slot >> 3, ch = slot & 7;
        short8 v;
        #pragma unroll
        for (int e = 0; e < 8; ++e) v[e] = (short)f2bf(tile[ch * 8 + e][j]);
        *(short8*)&adpT[(size_t)(j0 + j) * NPAD + r0 + ((ch ^ (j & 7)) << 3)] = v;
    }
}

// ---------------- K2: fused temporal stack (MFMA, row-compacted phaseB) ----------------
// Live rows per layer: t < WOUT. NG = 32*WOUT/16 groups; wave w < NG handles
// rowmap(idx) = (idx/WOUT)*8 + idx%WOUT (per-lane MFMA addressing; rowmap n&15
// duplicates are <=2-way -> free bank aliasing). Idle waves donate their
// SIMD VALU/MFMA issue slots to busy waves (block is pipe-throughput-bound).
template<int NG, int WOUT>
__device__ __forceinline__ void mfma_phaseB(int L,
    const unsigned short* __restrict__ xb, unsigned short* __restrict__ gbuf,
    const unsigned short* __restrict__ WA, const float* __restrict__ biasAll,
    int wave, int lr, int lk)
{
    if (wave >= NG) return;
    int idx = wave * 16 + lr;
    int n = (idx / WOUT) * 8 + (idx % WOUT);   // compile-time divisor
    f32x4 aF[4], aG[4];
    #pragma unroll
    for (int mt = 0; mt < 4; ++mt) {
        aF[mt] = (f32x4){0.f, 0.f, 0.f, 0.f};
        aG[mt] = (f32x4){0.f, 0.f, 0.f, 0.f};
    }
    #pragma unroll
    for (int ks = 0; ks < 4; ++ks) {
        short8 bv = *(const short8*)&xb[(n * 16 + ((ks * 4 + lk) ^ (n & 15))) * 8];
        #pragma unroll
        for (int mt = 0; mt < 4; ++mt) {
            int r = mt * 16 + lr;
            short8 av = *(const short8*)&WA[(r * 16 + ((ks * 4 + lk) ^ (r & 15))) * 8];
            aF[mt] = __builtin_amdgcn_mfma_f32_16x16x32_bf16(av, bv, aF[mt], 0, 0, 0);
        }
        #pragma unroll
        for (int mt = 0; mt < 4; ++mt) {
            int r = (mt + 4) * 16 + lr;
            short8 av = *(const short8*)&WA[(r * 16 + ((ks * 4 + lk) ^ (r & 15))) * 8];
            aG[mt] = __builtin_amdgcn_mfma_f32_16x16x32_bf16(av, bv, aG[mt], 0, 0, 0);
        }
    }
    int gs = GSWZ(n);
    #pragma unroll
    for (int mt = 0; mt < 4; ++mt) {
        int ob = mt * 16 + lk * 4;
        ushort4 p;
        p.x = f2bf(fast_tanh(aF[mt][0] + biasAll[L * 128 + ob + 0]) * fast_sigmoid(aG[mt][0] + biasAll[L * 128 + 64 + ob + 0]));
        p.y = f2bf(fast_tanh(aF[mt][1] + biasAll[L * 128 + ob + 1]) * fast_sigmoid(aG[mt][1] + biasAll[L * 128 + 64 + ob + 1]));
        p.z = f2bf(fast_tanh(aF[mt][2] + biasAll[L * 128 + ob + 2]) * fast_sigmoid(aG[mt][2] + biasAll[L * 128 + 64 + ob + 2]));
        p.w = f2bf(fast_tanh(aF[mt][3] + biasAll[L * 128 + ob + 3]) * fast_sigmoid(aG[mt][3] + biasAll[L * 128 + 64 + ob + 3]));
        *(ushort4*)&gbuf[((n * 8) + ((mt * 2 + (lk >> 1)) ^ gs)) * 8 + (lk & 1) * 4] = p;
    }
}

// WOUT_NEXT = WOUT - DN: next layer only reads tap0 rows t < WOUT_NEXT.
template<int L, int D, int WOUT, int DN>
__device__ __forceinline__ void phaseC_conv(unsigned short* __restrict__ xb,
    const unsigned short* __restrict__ gbuf,
    const float* __restrict__ bn_g, const float* __restrict__ bn_b,
    float xreg[2][8], int wave, int o)
{
    const int WOUT_NEXT = WOUT - DN;
    float bsc = bn_g[L * 64 + o] * rsqrtf(1.0f + 1e-5f);
    float bsh = bn_b[L * 64 + o];
    #pragma unroll
    for (int gi = 0; gi < 2; ++gi) {
        int g = wave * 2 + gi;
        #pragma unroll
        for (int t = 0; t < WOUT; ++t) {
            int n = g * 8 + t;
            float gv = bf2f(gbuf[(n * 8 + ((o >> 3) ^ GSWZ(n))) * 8 + (o & 7)]);
            float nx = (gv + xreg[gi][t + D]) * bsc + bsh;
            xreg[gi][t] = nx;
            unsigned short bfv = f2bf(nx);
            if (t < WOUT_NEXT)
                xb[(n * 16 + ((o >> 3) ^ (n & 15))) * 8 + (o & 7)] = bfv;
            if (t >= DN) {
                int n1 = n - DN;
                xb[(n1 * 16 + (((o >> 3) + 8) ^ (n1 & 15))) * 8 + (o & 7)] = bfv;
            }
        }
    }
}

__device__ __forceinline__ void phaseC_skip(int L, int LASTT,
    const unsigned short* __restrict__ gbuf, const unsigned short* __restrict__ SW,
    f32x4 skacc[4], int wave, int lr, int lk)
{
    if (wave >= 2) return;
    int g = wave * 16 + lr;
    int n = g * 8 + LASTT;
    int gs = GSWZ(n);
    #pragma unroll
    for (int ks = 0; ks < 2; ++ks) {
        short8 bv = *(const short8*)&gbuf[(n * 8 + ((ks * 4 + lk) ^ gs)) * 8];
        #pragma unroll
        for (int mt = 0; mt < 4; ++mt) {
            int r = mt * 16 + lr;
            short8 av = *(const short8*)&SW[((L * 64 + r) * 8 + ((ks * 4 + lk) ^ (r & 7))) * 8];
            skacc[mt] = __builtin_amdgcn_mfma_f32_16x16x32_bf16(av, bv, skacc[mt], 0, 0, 0);
        }
    }
}

__global__ __launch_bounds__(1024) void temporal_kernel(
    const float* __restrict__ X,
    const float* __restrict__ start_b,
    const unsigned short* __restrict__ waw,
    const unsigned short* __restrict__ sww,
    const unsigned short* __restrict__ wstw,
    const float* __restrict__ filt_b, const float* __restrict__ gate_b,
    const float* __restrict__ skip_b,
    const float* __restrict__ bn_g, const float* __restrict__ bn_b,
    float* __restrict__ S, unsigned short* __restrict__ St)
{
    extern __shared__ float smem[];
    unsigned short* xb   = (unsigned short*)smem;              // 32768 ush
    unsigned short* gbuf = (unsigned short*)(smem + 16384);    // 16384 ush
    unsigned short* WA   = (unsigned short*)(smem + 24576);    // 16384 ush
    unsigned short* SW   = (unsigned short*)(smem + 32768);    // 12288 ush
    float* biasAll       = smem + 38912;                       // 384 f32

    int tid = threadIdx.x;
    int wave = tid >> 6, lane = tid & 63;
    int lr = lane & 15, lk = lane >> 4;
    int o = lane;
    int item0 = blockIdx.x * 32;

    // ---- init staging ----
    __builtin_amdgcn_global_load_lds((gas_t)(wstw + tid * 8), (las_t)(WA + tid * 8), 16, 0, 0);
    for (int idx = tid; idx < 1536; idx += 1024)
        __builtin_amdgcn_global_load_lds((gas_t)(sww + idx * 8), (las_t)(SW + idx * 8), 16, 0, 0);
    if (tid < 384) {
        int L = tid >> 7, oo = tid & 127;
        biasAll[tid] = (oo < 64) ? filt_b[L * 64 + oo] : gate_b[L * 64 + oo - 64];
    }
    {   // X -> xb
        int n = tid >> 2, c = tid & 3;
        int g = n >> 3, t = n & 7;
        int ig = item0 + g, b = ig / NN, nn = ig - b * NN;
        short8 v = {0, 0, 0, 0, 0, 0, 0, 0};
        if (c < 2) {
            const float* src = &X[((size_t)(b * TT + t) * NN + nn) * NF + c * 8];
            float4 f0 = *(const float4*)src;
            float4 f1 = *(const float4*)(src + 4);
            v[0] = (short)f2bf(f0.x); v[1] = (short)f2bf(f0.y);
            v[2] = (short)f2bf(f0.z); v[3] = (short)f2bf(f0.w);
            v[4] = (short)f2bf(f1.x); v[5] = (short)f2bf(f1.y);
            v[6] = (short)f2bf(f1.z); v[7] = (short)f2bf(f1.w);
        }
        *(short8*)&xb[(n * 16 + (c ^ (n & 15))) * 8] = v;
    }
    __syncthreads();

    // ---- start conv MFMA (K=32, M=64); all 8 t needed as layer-0 taps ----
    {
        f32x4 aS[4];
        #pragma unroll
        for (int mt = 0; mt < 4; ++mt) aS[mt] = (f32x4){0.f, 0.f, 0.f, 0.f};
        int n = wave * 16 + lr;
        short8 bv = *(const short8*)&xb[(n * 16 + (lk ^ (n & 15))) * 8];
        #pragma unroll
        for (int mt = 0; mt < 4; ++mt) {
            int r = mt * 16 + lr;
            short8 av = *(const short8*)&WA[(r * 16 + (lk ^ (r & 15))) * 8];
            aS[mt] = __builtin_amdgcn_mfma_f32_16x16x32_bf16(av, bv, aS[mt], 0, 0, 0);
        }
        int gs = GSWZ(n);
        #pragma unroll
        for (int mt = 0; mt < 4; ++mt) {
            ushort4 p;
            p.x = f2bf(aS[mt][0]); p.y = f2bf(aS[mt][1]);
            p.z = f2bf(aS[mt][2]); p.w = f2bf(aS[mt][3]);
            *(ushort4*)&gbuf[((n * 8) + ((mt * 2 + (lk >> 1)) ^ gs)) * 8 + (lk & 1) * 4] = p;
        }
    }
    __syncthreads();

    float xreg[2][8];
    f32x4 skacc[4];
    #pragma unroll
    for (int mt = 0; mt < 4; ++mt) skacc[mt] = (f32x4){0.f, 0.f, 0.f, 0.f};

    // ---- C0: x = start_out + start_b; taps for layer0 (D=1); stage WA_L0 ----
    {
        __builtin_amdgcn_global_load_lds((gas_t)(waw + (size_t)tid * 8),
                                         (las_t)(WA + tid * 8), 16, 0, 0);
        __builtin_amdgcn_global_load_lds((gas_t)(waw + (size_t)(tid + 1024) * 8),
                                         (las_t)(WA + (tid + 1024) * 8), 16, 0, 0);
        float sb = start_b[o];
        #pragma unroll
        for (int gi = 0; gi < 2; ++gi) {
            int g = wave * 2 + gi;
            #pragma unroll
            for (int t = 0; t < 8; ++t) {
                int n = g * 8 + t;
                float gv = bf2f(gbuf[(n * 8 + ((o >> 3) ^ GSWZ(n))) * 8 + (o & 7)]) + sb;
                xreg[gi][t] = gv;
                unsigned short bfv = f2bf(gv);
                if (t < 7)   // layer0 reads tap0 rows t<7 only
                    xb[(n * 16 + ((o >> 3) ^ (n & 15))) * 8 + (o & 7)] = bfv;
                if (t >= 1) {
                    int n1 = n - 1;
                    xb[(n1 * 16 + (((o >> 3) + 8) ^ (n1 & 15))) * 8 + (o & 7)] = bfv;
                }
            }
        }
    }
    __syncthreads();

    // ---- layer 0 (live rows t<7: 224 rows = 14 groups) ----
    mfma_phaseB<14, 7>(0, xb, gbuf, WA, biasAll, wave, lr, lk);
    __syncthreads();
    phaseC_skip(0, 6, gbuf, SW, skacc, wave, lr, lk);
    phaseC_conv<0, 1, 7, 2>(xb, gbuf, bn_g, bn_b, xreg, wave, o);
    __builtin_amdgcn_global_load_lds((gas_t)(waw + (size_t)(2048 + tid) * 8),
                                     (las_t)(WA + tid * 8), 16, 0, 0);
    __builtin_amdgcn_global_load_lds((gas_t)(waw + (size_t)(2048 + tid + 1024) * 8),
                                     (las_t)(WA + (tid + 1024) * 8), 16, 0, 0);
    __syncthreads();

    // ---- layer 1 (live rows t<5: 160 rows = 10 groups) ----
    mfma_phaseB<10, 5>(1, xb, gbuf, WA, biasAll, wave, lr, lk);
    __syncthreads();
    phaseC_skip(1, 4, gbuf, SW, skacc, wave, lr, lk);
    phaseC_conv<1, 2, 5, 4>(xb, gbuf, bn_g, bn_b, xreg, wave, o);
    __builtin_amdgcn_global_load_lds((gas_t)(waw + (size_t)(4096 + tid) * 8),
                                     (las_t)(WA + tid * 8), 16, 0, 0);
    __builtin_amdgcn_global_load_lds((gas_t)(waw + (size_t)(4096 + tid + 1024) * 8),
                                     (las_t)(WA + (tid + 1024) * 8), 16, 0, 0);
    __syncthreads();

    // ---- layer 2 (live rows t<1: 32 rows = 2 groups) ----
    mfma_phaseB<2, 1>(2, xb, gbuf, WA, biasAll, wave, lr, lk);
    __syncthreads();
    phaseC_skip(2, 0, gbuf, SW, skacc, wave, lr, lk);

    // ---- final skip writes ----
    if (wave < 2) {
        int g = wave * 16 + lr;
        int ig = item0 + g, b = ig / NN, nn = ig - b * NN;
        #pragma unroll
        for (int mt = 0; mt < 4; ++mt) {
            #pragma unroll
            for (int j = 0; j < 4; ++j) {
                int oo = mt * 16 + lk * 4 + j;
                float v = skacc[mt][j] + skip_b[oo] + skip_b[64 + oo] + skip_b[128 + oo];
                int bc = b * 64 + oo;
                S[(size_t)nn * BCD + bc] = v;
                St[(size_t)bc * NPAD + SWZK(nn, oo)] = f2bf(v);
            }
        }
    }
}

// ---------------- K3: bf16 MFMA GEMM, C[m][n] = sum_k A[m][k]*B[n][k] ----------------
__global__ __launch_bounds__(256) void gemm_mfma(
    const unsigned short* __restrict__ A, const unsigned short* __restrict__ B,
    float* __restrict__ Cf, unsigned short* __restrict__ Ct)
{
    __shared__ unsigned short As[128 * 64];
    __shared__ unsigned short Bs[128 * 64];
    int tid = threadIdx.x;
    int wave = tid >> 6, lane = tid & 63;
    int lk = lane >> 4, lr = lane & 15;
    int n0 = blockIdx.x * 128, m0 = blockIdx.y * 128;
    int wm = wave >> 1, wn = wave & 1;

    f32x4 acc[4][4];
    #pragma unroll
    for (int i = 0; i < 4; ++i)
        #pragma unroll
        for (int j = 0; j < 4; ++j)
            acc[i][j] = (f32x4){0.f, 0.f, 0.f, 0.f};

    for (int k0 = 0; k0 < NPAD; k0 += 64) {
        #pragma unroll
        for (int i = 0; i < 4; ++i) {
            int chunk = wave * 4 + i;
            int row = chunk * 8 + (lane >> 3);
            int koff = (lane & 7) * 8;
            __builtin_amdgcn_global_load_lds(
                (gas_t)(A + (size_t)(m0 + row) * NPAD + k0 + koff),
                (las_t)(&As[chunk * 512]), 16, 0, 0);
            __builtin_amdgcn_global_load_lds(
                (gas_t)(B + (size_t)(n0 + row) * NPAD + k0 + koff),
                (las_t)(&Bs[chunk * 512]), 16, 0, 0);
        }
        __syncthreads();
        #pragma unroll
        for (int s = 0; s < 2; ++s) {
            short8 av[4], bv[4];
            #pragma unroll
            for (int f = 0; f < 4; ++f) {
                int m = wm * 64 + f * 16 + lr;
                int ca = ((s * 4 + lk) ^ (m & 7));
                av[f] = *(const short8*)&As[m * 64 + ca * 8];
                int n = wn * 64 + f * 16 + lr;
                int cb = ((s * 4 + lk) ^ (n & 7));
                bv[f] = *(const short8*)&Bs[n * 64 + cb * 8];
            }
            #pragma unroll
            for (int fi = 0; fi < 4; ++fi)
                #pragma unroll
                for (int fj = 0; fj < 4; ++fj)
                    acc[fi][fj] = __builtin_amdgcn_mfma_f32_16x16x32_bf16(
                        av[fi], bv[fj], acc[fi][fj], 0, 0, 0);
        }
        __syncthreads();
    }

    #pragma unroll
    for (int fi = 0; fi < 4; ++fi) {
        #pragma unroll
        for (int fj = 0; fj < 4; ++fj) {
            int m = m0 + wm * 64 + fi * 16 + lk * 4;
            int n = n0 + wn * 64 + fj * 16 + lr;
            f32x4 v = acc[fi][fj];
            if (Cf) {
                Cf[(size_t)(m + 0) * BCD + n] = v[0];
                Cf[(size_t)(m + 1) * BCD + n] = v[1];
                Cf[(size_t)(m + 2) * BCD + n] = v[2];
                Cf[(size_t)(m + 3) * BCD + n] = v[3];
            }
            if (Ct) {
                ushort4 p;
                p.x = f2bf(v[0]); p.y = f2bf(v[1]);
                p.z = f2bf(v[2]); p.w = f2bf(v[3]);
                *(ushort4*)&Ct[(size_t)n * NPAD + SWZK(m, n)] = p;
            }
        }
    }
}

// ---------------- K4: gcn 1x1 + heads + outputs + partial reductions ----------------
__global__ __launch_bounds__(256) void head_kernel(
    const float* __restrict__ S, const float* __restrict__ x1f,
    const float* __restrict__ x2,
    const float* __restrict__ wgcnT, const float* __restrict__ gcn_b,
    const float* __restrict__ c01, const float* __restrict__ w1tT,
    const float* __restrict__ h0_w2, const float* __restrict__ h0_b2,
    const float* __restrict__ h1_w2, const float* __restrict__ h1_b2,
    const int* __restrict__ Ct, const float* __restrict__ Yf,
    float* __restrict__ out, float* __restrict__ partials)
{
    __shared__ float hl[4][4][192];
    __shared__ float gxl[4][4][64];
    int tid = threadIdx.x;
    int wave = tid >> 6, o = tid & 63;
    int wid = blockIdx.x * 4 + wave;
    float w2a = h0_w2[o], w2b = h1_w2[o];
    float b20 = h0_b2[0], b21 = h1_b2[0];
    float cb = gcn_b[o], c0a = c01[o], c0b = c01[64 + o];

    float accT = 0.f, accC = 0.f, bce = 0.f, cT = 0.f, cC = 0.f;

    for (int base = wid * 4; base < ITEMS; base += 2048 * 4) {
        #pragma unroll
        for (int it = 0; it < 4; ++it) {
            int item = base + it;
            int b = item / NN, n = item - b * NN;
            int bc = b * 64 + o;
            hl[wave][it][o]       = S[(size_t)n * BCD + bc];
            hl[wave][it][64 + o]  = x1f[(size_t)n * BCD + bc];
            hl[wave][it][128 + o] = x2[(size_t)n * BCD + bc];
        }
        float a0 = cb, a1 = cb, a2 = cb, a3 = cb;
        for (int j = 0; j < 192; ++j) {
            float w = wgcnT[j * 64 + o];
            a0 = fmaf(w, hl[wave][0][j], a0);
            a1 = fmaf(w, hl[wave][1][j], a1);
            a2 = fmaf(w, hl[wave][2][j], a2);
            a3 = fmaf(w, hl[wave][3][j], a3);
        }
        float gxv[4] = {fmaxf(a0, 0.f), fmaxf(a1, 0.f), fmaxf(a2, 0.f), fmaxf(a3, 0.f)};
        #pragma unroll
        for (int it = 0; it < 4; ++it) gxl[wave][it][o] = gxv[it];

        float p0[4], p1[4];
        #pragma unroll
        for (int it = 0; it < 4; ++it) { p0[it] = c0a; p1[it] = c0b; }
        for (int c = 0; c < 64; ++c) {
            float w0 = w1tT[c * 64 + o];
            float w1 = w1tT[4096 + c * 64 + o];
            float g0 = gxl[wave][0][c], g1 = gxl[wave][1][c];
            float g2 = gxl[wave][2][c], g3 = gxl[wave][3][c];
            p0[0] = fmaf(w0, g0, p0[0]); p0[1] = fmaf(w0, g1, p0[1]);
            p0[2] = fmaf(w0, g2, p0[2]); p0[3] = fmaf(w0, g3, p0[3]);
            p1[0] = fmaf(w1, g0, p1[0]); p1[1] = fmaf(w1, g1, p1[1]);
            p1[2] = fmaf(w1, g2, p1[2]); p1[3] = fmaf(w1, g3, p1[3]);
        }
        #pragma unroll
        for (int it = 0; it < 4; ++it) {
            float r0 = w2a * fmaxf(p0[it], 0.f);
            float r1 = w2b * fmaxf(p1[it], 0.f);
            #pragma unroll
            for (int off = 32; off; off >>= 1) {
                r0 += __shfl_down(r0, off, 64);
                r1 += __shfl_down(r1, off, 64);
            }
            int item = base + it;
            int tt = Ct[item];
            if (o == 0) {
                float y0 = 1.f / (1.f + expf(-(r0 + b20)));
                float y1 = 1.f / (1.f + expf(-(r1 + b21)));
                float y = (tt > 0) ? y1 : y0;
                out[1 + item] = y;
                out[1 + ITEMS + item] = y0;
                out[1 + 2 * ITEMS + item] = y1;
                float yc = fminf(fmaxf(y, 1e-7f), 1.f - 1e-7f);
                float Yv = Yf[item];
                bce -= Yv * logf(yc) + (1.f - Yv) * logf(1.f - yc);
                if (tt > 0) cT += 1.f; else cC += 1.f;
            }
            if (tt > 0) accT += gxv[it]; else accC += gxv[it];
        }
    }
    partials[wid * 132 + o] = accT;
    partials[wid * 132 + 64 + o] = accC;
    if (o == 0) {
        partials[wid * 132 + 128] = bce;
        partials[wid * 132 + 129] = cT;
        partials[wid * 132 + 130] = cC;
    }
}

// ---------------- K5a: parallel slot reduce ----------------
__global__ __launch_bounds__(256) void reduce_kernel(const float* __restrict__ partials,
                                                     float* __restrict__ red)
{
    __shared__ float rb[4];
    int slot = blockIdx.x;
    int tid = threadIdx.x;
    float s = 0.f;
    for (int w = tid; w < 2048; w += 256) s += partials[w * 132 + slot];
    #pragma unroll
    for (int off = 32; off; off >>= 1) s += __shfl_down(s, off, 64);
    if ((tid & 63) == 0) rb[tid >> 6] = s;
    __syncthreads();
    if (tid == 0) red[slot] = rb[0] + rb[1] + rb[2] + rb[3];
}

// ---------------- K5b: final loss ----------------
__global__ void final_kernel(const float* __restrict__ red,
                             const float* __restrict__ task_emb,
                             float* __restrict__ out)
{
    int tid = threadIdx.x; // 64
    float cT = red[129], cC = red[130];
    float iT = 1.f / fmaxf(cT, 1.f), iC = 1.f / fmaxf(cC, 1.f);
    float d1 = task_emb[tid] * (cT * iT) - task_emb[tid] * (cC * iC);
    float d2 = red[tid] * iT - red[64 + tid] * iC;
    float p = d1 * d1 + d2 * d2;
    #pragma unroll
    for (int off = 32; off; off >>= 1) p += __shfl_down(p, off, 64);
    if (tid == 0) out[0] = red[128] * (1.f / (float)ITEMS) + p;
}

// ---------------- launch ----------------
extern "C" void kernel_launch(void* const* d_in, const int* in_sizes, int n_in,
                              void* d_out, int out_size, void* d_ws, size_t ws_size,
                              hipStream_t stream)
{
    const float* X       = (const float*)d_in[0];
    const int*   Ct      = (const int*)d_in[2];
    const float* Yf      = (const float*)d_in[3];
    const float* start_w = (const float*)d_in[5];
    const float* start_b = (const float*)d_in[6];
    const float* filt_w  = (const float*)d_in[7];
    const float* filt_b  = (const float*)d_in[8];
    const float* gate_w  = (const float*)d_in[9];
    const float* gate_b  = (const float*)d_in[10];
    const float* skip_w  = (const float*)d_in[11];
    const float* skip_b  = (const float*)d_in[12];
    const float* bn_g    = (const float*)d_in[13];
    const float* bn_b    = (const float*)d_in[14];
    const float* nv1     = (const float*)d_in[15];
    const float* nv2     = (const float*)d_in[16];
    const float* task    = (const float*)d_in[17];
    const float* gcn_w   = (const float*)d_in[18];
    const float* gcn_b   = (const float*)d_in[19];
    const float* h0_w1   = (const float*)d_in[20];
    const float* h0_b1   = (const float*)d_in[21];
    const float* h0_w2   = (const float*)d_in[22];
    const float* h0_b2   = (const float*)d_in[23];
    const float* h1_w1   = (const float*)d_in[24];
    const float* h1_b1   = (const float*)d_in[25];
    const float* h1_w2   = (const float*)d_in[26];
    const float* h1_b2   = (const float*)d_in[27];

    float* ws    = (float*)d_ws;
    float* adpF  = ws + OFF_ADPF;
    unsigned short* St   = (unsigned short*)(ws + OFF_ST);
    float* x2    = ws + OFF_X2;        // aliases [adpF|St], safe by schedule
    unsigned short* adpT = (unsigned short*)(ws + OFF_ADPT);
    float* S     = ws + OFF_S;
    float* x1f   = ws + OFF_X1F;
    unsigned short* x1t  = (unsigned short*)(ws + OFF_X1T);
    float* c01   = ws + OFF_C01;
    float* wgcnT = ws + OFF_WGCNT;
    float* w1tT  = ws + OFF_W1TT;
    float* part  = ws + OFF_PART;
    float* red   = ws + OFF_RED;
    unsigned short* waw  = (unsigned short*)(ws + OFF_WAW);
    unsigned short* sww  = (unsigned short*)(ws + OFF_SWW);
    unsigned short* wstw = (unsigned short*)(ws + OFF_WSTW);
    float* outp  = (float*)d_out;

    // zero St (pad rows n in [2000,2048) must contribute 0 to GEMM1)
    hipMemsetAsync(St, 0, (size_t)BCD * NPAD * sizeof(unsigned short), stream);

    prep_kernel<<<64, 256, 0, stream>>>(gcn_w, h0_w1, h0_b1, h1_w1, h1_b1, task,
                                        filt_w, gate_w, skip_w, start_w,
                                        c01, wgcnT, w1tT, waw, sww, wstw);
    adp_kernel<<<NN, 256, 0, stream>>>(nv1, nv2, adpF);
    dim3 tg(NPAD / 64, NPAD / 64);
    transpose_adp<<<tg, 256, 0, stream>>>(adpF, adpT);

    const int K2_LDS = 39296 * 4; // ~153.5 KiB dynamic LDS
    hipFuncSetAttribute(reinterpret_cast<const void*>(temporal_kernel),
                        hipFuncAttributeMaxDynamicSharedMemorySize, K2_LDS);
    temporal_kernel<<<ITEMS / 32, 1024, K2_LDS, stream>>>(
        X, start_b, waw, sww, wstw, filt_b, gate_b,
        skip_b, bn_g, bn_b, S, St);

    dim3 gg(BCD / 128, NPAD / 128);
    gemm_mfma<<<gg, 256, 0, stream>>>(adpT, St, x1f, x1t);      // x1 (both layouts)
    gemm_mfma<<<gg, 256, 0, stream>>>(adpT, x1t, x2, nullptr);  // x2 = adp^T·x1

    head_kernel<<<512, 256, 0, stream>>>(S, x1f, x2, wgcnT, gcn_b, c01, w1tT,
                                         h0_w2, h0_b2, h1_w2, h1_b2,
                                         Ct, Yf, outp, part);
    reduce_kernel<<<131, 256, 0, stream>>>(part, red);
    final_kernel<<<1, 64, 0, stream>>>(red, task, outp);
}